// Round 15
// baseline (483.419 us; speedup 1.0000x reference)
//
#include <hip/hip_runtime.h>
#include <math.h>

// ---------------- types ----------------
typedef unsigned int   uint4v __attribute__((ext_vector_type(4)));
typedef float          f32x4  __attribute__((ext_vector_type(4)));
typedef __bf16         bf16x8 __attribute__((ext_vector_type(8)));
typedef unsigned short u16x8  __attribute__((ext_vector_type(8)));
typedef unsigned short u16x4  __attribute__((ext_vector_type(4)));

#define D_MODEL 512
#define SEQ     2048
#define BTOK    4096   // B * SEQ
#define HIDE    2048
#define NHEAD   8
#define HD      64

static __device__ __forceinline__ unsigned short f2bf(float f) {
  __bf16 b = (__bf16)f;
  return __builtin_bit_cast(unsigned short, b);
}
static __device__ __forceinline__ float bf2f(unsigned short b) {
  union { unsigned u; float f; } v; v.u = ((unsigned)b) << 16;
  return v.f;
}
static __device__ __forceinline__ bf16x8 ldb8(const unsigned short* p) {
  return __builtin_bit_cast(bf16x8, *(const uint4v*)p);
}
static __device__ __forceinline__ f32x4 mfma16(bf16x8 a, bf16x8 b, f32x4 c) {
  return __builtin_amdgcn_mfma_f32_16x16x32_bf16(a, b, c, 0, 0, 0);
}

typedef unsigned int u32_g __attribute__((address_space(1)));
typedef unsigned int u32_l __attribute__((address_space(3)));
static __device__ __forceinline__ void gload16(const unsigned short* g, unsigned short* l) {
  __builtin_amdgcn_global_load_lds((const u32_g*)(const void*)g,
                                   (u32_l*)(void*)l, 16, 0, 0);
}

#define SWZ(r, off) ((off) ^ (((r) & 7) << 4))
#define QSCALE 0.180336880f   // 0.125 * log2(e)

template<int N>
static __device__ __forceinline__ void waitcnt_vm() {
  asm volatile("s_waitcnt vmcnt(%0)" :: "i"(N) : "memory");
}

// ---------------- weight prep: LDS-tiled transpose f32 [K][N] -> bf16 [N][K] ----
__global__ __launch_bounds__(64) void prep_t(
    const float* __restrict__ qw, const float* __restrict__ kw,
    const float* __restrict__ vw, const float* __restrict__ ow,
    const float* __restrict__ w0, const float* __restrict__ w1,
    const float* __restrict__ w2,
    unsigned short* __restrict__ Wq, unsigned short* __restrict__ Wo,
    unsigned short* __restrict__ W01, unsigned short* __restrict__ W2)
{
  int bid = blockIdx.x;
  int l = bid >> 10;
  int r = bid & 1023;
  const float* src; unsigned short* dst;
  int tr, tc, srcN, dstK;
  if (r < 192) {
    int sel = r >> 6, tt = r & 63;
    tr = tt >> 3; tc = tt & 7;
    src = (sel == 0 ? qw : sel == 1 ? kw : vw) + (size_t)l * 262144;
    srcN = 512; dstK = 512;
    dst = Wq + (size_t)l * 786432 + (size_t)(sel * 512 + tc * 64) * 512 + tr * 64;
  } else if (r < 256) {
    int tt = r - 192; tr = tt >> 3; tc = tt & 7;
    src = ow + (size_t)l * 262144; srcN = 512; dstK = 512;
    dst = Wo + (size_t)l * 262144 + (size_t)(tc * 64) * 512 + tr * 64;
  } else if (r < 768) {
    int idx = r - 256; int sel = idx >> 8; int tt = idx & 255;
    tr = tt >> 5; tc = tt & 31;
    src = (sel ? w1 : w0) + (size_t)l * 1048576; srcN = 2048; dstK = 512;
    dst = W01 + (size_t)l * 2097152 + (size_t)sel * 1048576 + (size_t)(tc * 64) * 512 + tr * 64;
  } else {
    int tt = r - 768; tr = tt >> 3; tc = tt & 7;
    src = w2 + (size_t)l * 1048576; srcN = 512; dstK = 2048;
    dst = W2 + (size_t)l * 1048576 + (size_t)(tc * 64) * 2048 + tr * 64;
  }
  src += (size_t)(tr * 64) * srcN + tc * 64;
  __shared__ unsigned short T[64][68];
  int t = threadIdx.x;
  #pragma unroll
  for (int it = 0; it < 16; ++it) {
    int row = it * 4 + (t >> 4);
    int col = (t & 15) * 4;
    f32x4 v4 = *(const f32x4*)(src + (size_t)row * srcN + col);
    u16x4 o; o[0] = f2bf(v4.x); o[1] = f2bf(v4.y); o[2] = f2bf(v4.z); o[3] = f2bf(v4.w);
    *(u16x4*)&T[row][col] = o;
  }
  __syncthreads();
  unsigned short* orow = dst + (size_t)t * dstK;
  #pragma unroll
  for (int j0 = 0; j0 < 8; ++j0) {
    u16x8 o;
    #pragma unroll
    for (int j = 0; j < 8; ++j) o[j] = T[j0 * 8 + j][t];
    *(u16x8*)(orow + j0 * 8) = o;
  }
}

// ---------------- initrms: h = x; xn = rms(x)*w ----------------
__global__ __launch_bounds__(256) void initrms_k(const float* __restrict__ x,
                                                 const float* __restrict__ w,
                                                 float* __restrict__ h,
                                                 unsigned short* __restrict__ xn) {
  int row  = blockIdx.x * 4 + (threadIdx.x >> 6);
  int lane = threadIdx.x & 63;
  const float* xr = x + (size_t)row * D_MODEL + lane * 8;
  f32x4 v0 = *(const f32x4*)(xr);
  f32x4 v1 = *(const f32x4*)(xr + 4);
  *(f32x4*)(h + (size_t)row * D_MODEL + lane * 8)     = v0;
  *(f32x4*)(h + (size_t)row * D_MODEL + lane * 8 + 4) = v1;
  float ss = v0.x*v0.x + v0.y*v0.y + v0.z*v0.z + v0.w*v0.w
           + v1.x*v1.x + v1.y*v1.y + v1.z*v1.z + v1.w*v1.w;
  #pragma unroll
  for (int m = 1; m < 64; m <<= 1) ss += __shfl_xor(ss, m, 64);
  float inv = 1.0f / (sqrtf(ss * (1.0f / D_MODEL)) + 1e-6f);
  f32x4 w0 = *(const f32x4*)(w + lane * 8);
  f32x4 w1 = *(const f32x4*)(w + lane * 8 + 4);
  u16x8 o;
  o[0] = f2bf(v0.x * w0.x * inv); o[1] = f2bf(v0.y * w0.y * inv);
  o[2] = f2bf(v0.z * w0.z * inv); o[3] = f2bf(v0.w * w0.w * inv);
  o[4] = f2bf(v1.x * w1.x * inv); o[5] = f2bf(v1.y * w1.y * inv);
  o[6] = f2bf(v1.z * w1.z * inv); o[7] = f2bf(v1.w * w1.w * inv);
  *(u16x8*)(xn + (size_t)row * D_MODEL + lane * 8) = o;
}

// ---------------- addrms: h += y(bf16); xn = rms(h)*w ----------------
__global__ __launch_bounds__(256) void addrms_k(float* __restrict__ h,
                                                const unsigned short* __restrict__ y,
                                                const float* __restrict__ w,
                                                unsigned short* __restrict__ xn) {
  int row  = blockIdx.x * 4 + (threadIdx.x >> 6);
  int lane = threadIdx.x & 63;
  float* hr = h + (size_t)row * D_MODEL + lane * 8;
  f32x4 v0 = *(const f32x4*)(hr);
  f32x4 v1 = *(const f32x4*)(hr + 4);
  u16x8 yy = *(const u16x8*)(y + (size_t)row * D_MODEL + lane * 8);
  v0.x += bf2f(yy[0]); v0.y += bf2f(yy[1]); v0.z += bf2f(yy[2]); v0.w += bf2f(yy[3]);
  v1.x += bf2f(yy[4]); v1.y += bf2f(yy[5]); v1.z += bf2f(yy[6]); v1.w += bf2f(yy[7]);
  *(f32x4*)(hr)     = v0;
  *(f32x4*)(hr + 4) = v1;
  float ss = v0.x*v0.x + v0.y*v0.y + v0.z*v0.z + v0.w*v0.w
           + v1.x*v1.x + v1.y*v1.y + v1.z*v1.z + v1.w*v1.w;
  #pragma unroll
  for (int m = 1; m < 64; m <<= 1) ss += __shfl_xor(ss, m, 64);
  float inv = 1.0f / (sqrtf(ss * (1.0f / D_MODEL)) + 1e-6f);
  f32x4 w0 = *(const f32x4*)(w + lane * 8);
  f32x4 w1 = *(const f32x4*)(w + lane * 8 + 4);
  u16x8 o;
  o[0] = f2bf(v0.x * w0.x * inv); o[1] = f2bf(v0.y * w0.y * inv);
  o[2] = f2bf(v0.z * w0.z * inv); o[3] = f2bf(v0.w * w0.w * inv);
  o[4] = f2bf(v1.x * w1.x * inv); o[5] = f2bf(v1.y * w1.y * inv);
  o[6] = f2bf(v1.z * w1.z * inv); o[7] = f2bf(v1.w * w1.w * inv);
  *(u16x8*)(xn + (size_t)row * D_MODEL + lane * 8) = o;
}

// ---------------- addout: out = h + y (final layer, f32 out) --------------
__global__ __launch_bounds__(256) void addout_k(const float* __restrict__ h,
                                                const unsigned short* __restrict__ y,
                                                float* __restrict__ out) {
  int row  = blockIdx.x * 4 + (threadIdx.x >> 6);
  int lane = threadIdx.x & 63;
  const float* hr = h + (size_t)row * D_MODEL + lane * 8;
  f32x4 v0 = *(const f32x4*)(hr);
  f32x4 v1 = *(const f32x4*)(hr + 4);
  u16x8 yy = *(const u16x8*)(y + (size_t)row * D_MODEL + lane * 8);
  v0.x += bf2f(yy[0]); v0.y += bf2f(yy[1]); v0.z += bf2f(yy[2]); v0.w += bf2f(yy[3]);
  v1.x += bf2f(yy[4]); v1.y += bf2f(yy[5]); v1.z += bf2f(yy[6]); v1.w += bf2f(yy[7]);
  *(f32x4*)(out + (size_t)row * D_MODEL + lane * 8)     = v0;
  *(f32x4*)(out + (size_t)row * D_MODEL + lane * 8 + 4) = v1;
}

// ---------------- GEMM v7: counted-vmcnt pipeline + T2 swizzle ------------
#define EPI_QKV   0
#define EPI_PLAIN 1

template<int EPI, int BM, int BN>
__global__ __launch_bounds__(256) void gemm7_k(
    const unsigned short* __restrict__ A,
    const unsigned short* __restrict__ Bt,    // [N][K]
    const float* __restrict__ bias0,
    const float* __restrict__ bias1,
    const float* __restrict__ bias2,
    void* __restrict__ out0,
    void* __restrict__ out1,
    void* __restrict__ out2,                  // QKV: vt [bh][d][s]
    int M, int N, int K)
{
  constexpr int MF = BM / 32;
  constexpr int NF = BN / 32;
  constexpr int ALOADS = BM / 32;
  constexpr int BLOADS = BN / 32;
  constexpr int NL = ALOADS + BLOADS;

  __shared__ __attribute__((aligned(16))) unsigned short Al[2][BM * 64];
  __shared__ __attribute__((aligned(16))) unsigned short Bl[2][BN * 64];

  int nblk = gridDim.x;
  int orig = blockIdx.x;
  int qq = nblk >> 3, rr = nblk & 7, xcd = orig & 7, pos = orig >> 3;
  int lid = (xcd < rr ? xcd * (qq + 1) : rr * (qq + 1) + (xcd - rr) * qq) + pos;
  int numN = N / BN;
  int mt = lid / numN, nt = lid % numN;
  int m0 = mt * BM, n0 = nt * BN;

  int tid = threadIdx.x, lane = tid & 63, w = tid >> 6;
  int wm = w >> 1, wn = w & 1;
  int g = lane >> 4, c = lane & 15;
  int srow = lane >> 3, sslot = lane & 7;
  int sgc = (sslot ^ srow) * 8;

  const unsigned short* aG = A  + (size_t)(m0 + w * (BM / 4) + srow) * K + sgc;
  const unsigned short* bG = Bt + (size_t)(n0 + w * (BN / 4) + srow) * K + sgc;
  int aOff = (w * (BM / 4) + srow) * 64 + sslot * 8;
  int bOff = (w * (BN / 4) + srow) * 64 + sslot * 8;

  f32x4 acc[MF][NF] = {};
  int KT = K >> 6;
  int rk = c & 7;

  #pragma unroll
  for (int t = 0; t < ALOADS; ++t)
    gload16(aG + (size_t)(t * 8) * K, &Al[0][aOff + t * 8 * 64]);
  #pragma unroll
  for (int t = 0; t < BLOADS; ++t)
    gload16(bG + (size_t)(t * 8) * K, &Bl[0][bOff + t * 8 * 64]);

  for (int kt = 0; kt < KT; ++kt) {
    int cur = kt & 1;
    if (kt + 1 < KT) {
      int nb = cur ^ 1;
      const unsigned short* aGk = aG + (kt + 1) * 64;
      const unsigned short* bGk = bG + (kt + 1) * 64;
      #pragma unroll
      for (int t = 0; t < ALOADS; ++t)
        gload16(aGk + (size_t)(t * 8) * K, &Al[nb][aOff + t * 8 * 64]);
      #pragma unroll
      for (int t = 0; t < BLOADS; ++t)
        gload16(bGk + (size_t)(t * 8) * K, &Bl[nb][bOff + t * 8 * 64]);
      waitcnt_vm<NL>();
    } else {
      waitcnt_vm<0>();
    }
    __builtin_amdgcn_s_barrier();
    __builtin_amdgcn_sched_barrier(0);
    #pragma unroll
    for (int ks = 0; ks < 2; ++ks) {
      int slot = (ks * 4 + g) ^ rk;
      bf16x8 af[MF], bfr[NF];
      #pragma unroll
      for (int i = 0; i < MF; ++i)
        af[i] = ldb8(&Al[cur][(wm * (MF * 16) + i * 16 + c) * 64 + slot * 8]);
      #pragma unroll
      for (int j = 0; j < NF; ++j)
        bfr[j] = ldb8(&Bl[cur][(wn * (NF * 16) + j * 16 + c) * 64 + slot * 8]);
      #pragma unroll
      for (int i = 0; i < MF; ++i)
        #pragma unroll
        for (int j = 0; j < NF; ++j)
          acc[i][j] = mfma16(af[i], bfr[j], acc[i][j]);
    }
    __builtin_amdgcn_sched_barrier(0);
    __builtin_amdgcn_s_barrier();
  }

  if (EPI == EPI_QKV) {
    int sel  = n0 >> 9;
    if (sel < 2) {
      #pragma unroll
      for (int i = 0; i < MF; ++i) {
        int mrow = m0 + wm * (MF * 16) + i * 16 + g * 4;
        #pragma unroll
        for (int j = 0; j < NF; ++j) {
          int nloc = (n0 & 511) + wn * (NF * 16) + j * 16 + c;
          const float* bp = sel == 0 ? bias0 : bias1;
          unsigned short* o = (unsigned short*)(sel == 0 ? out0 : out1);
          float sc = (sel == 0) ? QSCALE : 1.0f;
          float bn = bp[nloc];
          #pragma unroll
          for (int ii = 0; ii < 4; ++ii)
            o[(size_t)(mrow + ii) * D_MODEL + nloc] = f2bf((acc[i][j][ii] + bn) * sc);
        }
      }
    } else {
      unsigned short* T = &Al[0][0];            // 64 x 136
      #pragma unroll
      for (int i = 0; i < MF; ++i) {
        int ml0 = wm * (MF * 16) + i * 16 + g * 4;
        #pragma unroll
        for (int j = 0; j < NF; ++j) {
          int nl = wn * (NF * 16) + j * 16 + c;
          float bn = bias2[(n0 & 511) + nl];
          u16x4 pk;
          #pragma unroll
          for (int ii = 0; ii < 4; ++ii) pk[ii] = f2bf(acc[i][j][ii] + bn);
          *(u16x4*)&T[nl * 136 + ml0] = pk;
        }
      }
      __syncthreads();
      int b  = m0 >> 11, s0 = m0 & 2047;
      int hh = (n0 & 511) >> 6;
      int r  = tid >> 2, c0 = (tid & 3) * 32;
      unsigned short* dst = (unsigned short*)out2 +
          ((size_t)(b * NHEAD + hh) * HD + r) * SEQ + s0 + c0;
      #pragma unroll
      for (int u = 0; u < 4; ++u)
        *(u16x8*)(dst + u * 8) = *(u16x8*)&T[r * 136 + c0 + u * 8];
    }
  } else {  // EPI_PLAIN
    #pragma unroll
    for (int i = 0; i < MF; ++i) {
      int mrow = m0 + wm * (MF * 16) + i * 16 + g * 4;
      #pragma unroll
      for (int j = 0; j < NF; ++j) {
        int n = n0 + wn * (NF * 16) + j * 16 + c;
        float bn = bias0[n];
        unsigned short* o = (unsigned short*)out0;
        #pragma unroll
        for (int ii = 0; ii < 4; ++ii)
          o[(size_t)(mrow + ii) * N + n] = f2bf(acc[i][j][ii] + bn);
      }
    }
  }
}

// ---------------- GEMM v10d: fused dual-B gated FFN-up (R10 best: single
// buffer, 2 barriers/K-step, 32KB LDS -> 4-5 blocks/CU, n-major chunking) ---
template<int BM, int BN>
__global__ __launch_bounds__(256) void gemm10d_k(
    const unsigned short* __restrict__ A,
    const unsigned short* __restrict__ B0t,   // [N][K]
    const unsigned short* __restrict__ B1t,   // [N][K]
    const float* __restrict__ bias0,
    const float* __restrict__ bias1,
    unsigned short* __restrict__ out,
    int M, int N, int K)
{
  constexpr int MF = BM / 32;
  constexpr int NF = BN / 32;
  constexpr int ALOADS = BM / 32;
  constexpr int BLOADS = BN / 32;

  __shared__ __attribute__((aligned(16))) unsigned short Al[BM * 64];
  __shared__ __attribute__((aligned(16))) unsigned short B0l[BN * 64];
  __shared__ __attribute__((aligned(16))) unsigned short B1l[BN * 64];

  int nblk = gridDim.x;
  int orig = blockIdx.x;
  int qq = nblk >> 3, rr = nblk & 7, xcd = orig & 7, pos = orig >> 3;
  int lid = (xcd < rr ? xcd * (qq + 1) : rr * (qq + 1) + (xcd - rr) * qq) + pos;
  int numM = M / BM;
  int nt = lid / numM, mt = lid % numM;   // n-major: XCD chunk shares B panel
  int m0 = mt * BM, n0 = nt * BN;

  int tid = threadIdx.x, lane = tid & 63, w = tid >> 6;
  int wm = w >> 1, wn = w & 1;
  int g = lane >> 4, c = lane & 15;
  int srow = lane >> 3, sslot = lane & 7;
  int sgc = (sslot ^ srow) * 8;

  const unsigned short* aG  = A   + (size_t)(m0 + w * (BM / 4) + srow) * K + sgc;
  const unsigned short* b0G = B0t + (size_t)(n0 + w * (BN / 4) + srow) * K + sgc;
  const unsigned short* b1G = B1t + (size_t)(n0 + w * (BN / 4) + srow) * K + sgc;
  unsigned short* aL  = &Al [(w * (BM / 4) + srow) * 64 + sslot * 8];
  unsigned short* b0L = &B0l[(w * (BN / 4) + srow) * 64 + sslot * 8];
  unsigned short* b1L = &B1l[(w * (BN / 4) + srow) * 64 + sslot * 8];

  f32x4 acc0[MF][NF] = {};
  f32x4 acc1[MF][NF] = {};
  int KT = K >> 6;
  int rk = c & 7;

  for (int kt = 0; kt < KT; ++kt) {
    if (kt) __syncthreads();
    #pragma unroll
    for (int t = 0; t < ALOADS; ++t)
      gload16(aG + (size_t)(t * 8) * K + kt * 64, aL + t * 8 * 64);
    #pragma unroll
    for (int t = 0; t < BLOADS; ++t) {
      gload16(b0G + (size_t)(t * 8) * K + kt * 64, b0L + t * 8 * 64);
      gload16(b1G + (size_t)(t * 8) * K + kt * 64, b1L + t * 8 * 64);
    }
    __syncthreads();
    #pragma unroll
    for (int ks = 0; ks < 2; ++ks) {
      int slot = (ks * 4 + g) ^ rk;
      bf16x8 af[MF], b0f[NF], b1f[NF];
      #pragma unroll
      for (int i = 0; i < MF; ++i)
        af[i] = ldb8(&Al[(wm * (MF * 16) + i * 16 + c) * 64 + slot * 8]);
      #pragma unroll
      for (int j = 0; j < NF; ++j) {
        b0f[j] = ldb8(&B0l[(wn * (NF * 16) + j * 16 + c) * 64 + slot * 8]);
        b1f[j] = ldb8(&B1l[(wn * (NF * 16) + j * 16 + c) * 64 + slot * 8]);
      }
      #pragma unroll
      for (int i = 0; i < MF; ++i)
        #pragma unroll
        for (int j = 0; j < NF; ++j) {
          acc0[i][j] = mfma16(af[i], b0f[j], acc0[i][j]);
          acc1[i][j] = mfma16(af[i], b1f[j], acc1[i][j]);
        }
    }
  }

  #pragma unroll
  for (int i = 0; i < MF; ++i) {
    int mrow = m0 + wm * (MF * 16) + i * 16 + g * 4;
    #pragma unroll
    for (int j = 0; j < NF; ++j) {
      int n = n0 + wn * (NF * 16) + j * 16 + c;
      float b0n = bias0[n], b1n = bias1[n];
      #pragma unroll
      for (int ii = 0; ii < 4; ++ii) {
        float a  = acc0[i][j][ii] + b0n;
        float gv = acc1[i][j][ii] + b1n;
        float s  = gv / (1.0f + __expf(-gv));
        out[(size_t)(mrow + ii) * N + n] = f2bf(a * s);
      }
    }
  }
}

// ---------------- attention v5: split-K flash, no-max softmax ------------
struct Stg { uint4v k0, k1, v0, v1; };

static __device__ __forceinline__ Stg stage_load(const unsigned short* Kp,
                                                 const unsigned short* Vp,
                                                 int kbase, int srow, int sslot) {
  Stg s;
  const unsigned short* kr = Kp + (size_t)(kbase + srow) * D_MODEL + sslot * 8;
  s.k0 = *(const uint4v*)kr;
  s.k1 = *(const uint4v*)(kr + 32);
  const unsigned short* vr = Vp + (size_t)srow * SEQ + kbase + sslot * 8;
  s.v0 = *(const uint4v*)vr;
  s.v1 = *(const uint4v*)(vr + 32);
  return s;
}
static __device__ __forceinline__ void stage_write(unsigned short* Klb, unsigned short* Vlb,
                                                   const Stg& s, int srow, int sslot) {
  char* kb = (char*)Klb;
  *(uint4v*)(kb + SWZ(srow, srow * 128 + sslot * 16))       = s.k0;
  *(uint4v*)(kb + SWZ(srow, srow * 128 + (sslot + 4) * 16)) = s.k1;
  char* vb = (char*)Vlb;
  *(uint4v*)(vb + SWZ(srow, srow * 128 + sslot * 16))       = s.v0;
  *(uint4v*)(vb + SWZ(srow, srow * 128 + (sslot + 4) * 16)) = s.v1;
}

template<bool MASKED>
static __device__ __forceinline__ void attn_tile(
    const unsigned short* Klb, const unsigned short* Vlb,
    bf16x8 qf0, bf16x8 qf1, f32x4* oacc, float& ps,
    int g, int c, int kbase, int qrow)
{
  f32x4 z[4];
  #pragma unroll
  for (int hh = 0; hh < 4; ++hh) {
    int r = hh * 16 + c;
    const char* base = (const char*)Klb;
    bf16x8 k0 = ldb8((const unsigned short*)(base + SWZ(r, r * 128 + g * 16)));
    bf16x8 k1 = ldb8((const unsigned short*)(base + SWZ(r, r * 128 + 64 + g * 16)));
    f32x4 t = {};
    t = mfma16(k0, qf0, t);
    t = mfma16(k1, qf1, t);
    z[hh] = t;
  }
  u16x8 pa0, pa1;
  #pragma unroll
  for (int hh = 0; hh < 4; ++hh) {
    #pragma unroll
    for (int i = 0; i < 4; ++i) {
      float p = exp2f(z[hh][i]);
      if (MASKED && (kbase + hh * 16 + g * 4 + i > qrow)) p = 0.0f;
      ps += p;
      unsigned short pb = f2bf(p);
      if (hh < 2) pa0[hh * 4 + i] = pb;
      else        pa1[(hh - 2) * 4 + i] = pb;
    }
  }
  bf16x8 af0 = __builtin_bit_cast(bf16x8, pa0);
  bf16x8 af1 = __builtin_bit_cast(bf16x8, pa1);
  #pragma unroll
  for (int db = 0; db < 4; ++db) {
    int r = db * 16 + c;
    const char* base = (const char*)Vlb;
    u16x4 v00 = *(const u16x4*)(base + SWZ(r, r * 128 + g * 8));
    u16x4 v01 = *(const u16x4*)(base + SWZ(r, r * 128 + 32 + g * 8));
    u16x4 v10 = *(const u16x4*)(base + SWZ(r, r * 128 + 64 + g * 8));
    u16x4 v11 = *(const u16x4*)(base + SWZ(r, r * 128 + 96 + g * 8));
    u16x8 vb0, vb1;
    #pragma unroll
    for (int j = 0; j < 4; ++j) {
      vb0[j] = v00[j]; vb0[4 + j] = v01[j];
      vb1[j] = v10[j]; vb1[4 + j] = v11[j];
    }
    oacc[db] = mfma16(af0, __builtin_bit_cast(bf16x8, vb0), oacc[db]);
    oacc[db] = mfma16(af1, __builtin_bit_cast(bf16x8, vb1), oacc[db]);
  }
}

static __device__ __forceinline__ int slot_base(int c) {
  if (c < 16) return (c - 8) * 2;
  if (c < 24) return 16 + (c - 16) * 3;
  return 40 + (c - 24) * 4;
}

__global__ __launch_bounds__(256) void attn5_k(const unsigned short* __restrict__ Q,
                                               const unsigned short* __restrict__ K,
                                               const unsigned short* __restrict__ VT,
                                               unsigned short* __restrict__ O,
                                               float* __restrict__ Oparts,
                                               float* __restrict__ Sparts)
{
  __shared__ __attribute__((aligned(16))) unsigned short Kl[2][64 * 64];
  __shared__ __attribute__((aligned(16))) unsigned short Vl[2][64 * 64];
  int tid = threadIdx.x, lane = tid & 63, w = tid >> 6;
  int g = lane >> 4, cl = lane & 15;

  int z = 79 - (int)blockIdx.x;
  int c, sp;
  if (z < 8)        { c = z;                    sp = 0; }
  else if (z < 24)  { int t2 = z - 8;  c = 8  + (t2 >> 1); sp = t2 & 1; }
  else if (z < 48)  { int t2 = z - 24; c = 16 + t2 / 3;    sp = t2 % 3; }
  else              { int t2 = z - 48; c = 24 + (t2 >> 2); sp = t2 & 3; }
  int kt0 = sp * 8;
  int kt1 = min(c + 1, kt0 + 8);
  bool lastsplit = (kt1 == c + 1);

  int bh = blockIdx.y, b = bh >> 3, h = bh & 7;
  int q0 = c * 64;
  const unsigned short* Qp = Q + (size_t)(b * SEQ) * D_MODEL + h * HD;
  const unsigned short* Kp = K + (size_t)(b * SEQ) * D_MODEL + h * HD;
  const unsigned short* Vp = VT + (size_t)bh * HD * SEQ;

  int qrow = q0 + w * 16 + cl;
  bf16x8 qf0 = ldb8(Qp + (size_t)qrow * D_MODEL + g * 8);
  bf16x8 qf1 = ldb8(Qp + (size_t)qrow * D_MODEL + 32 + g * 8);

  f32x4 oacc[4] = {};
  float ps = 0.0f;
  int srow = tid >> 2, sslot = tid & 3;

  Stg s0 = stage_load(Kp, Vp, kt0 * 64, srow, sslot);
  stage_write(&Kl[0][0], &Vl[0][0], s0, srow, sslot);
  __syncthreads();

  int buf = 0;
  for (int kt = kt0; kt < kt1 - 1; ++kt) {
    Stg sn = stage_load(Kp, Vp, (kt + 1) * 64, srow, sslot);
    attn_tile<false>(&Kl[buf][0], &Vl[buf][0], qf0, qf1, oacc, ps, g, cl, 0, 0);
    stage_write(&Kl[buf ^ 1][0], &Vl[buf ^ 1][0], sn, srow, sslot);
    __syncthreads();
    buf ^= 1;
  }
  if (lastsplit)
    attn_tile<true>(&Kl[buf][0], &Vl[buf][0], qf0, qf1, oacc, ps, g, cl,
                    (kt1 - 1) * 64, qrow);
  else
    attn_tile<false>(&Kl[buf][0], &Vl[buf][0], qf0, qf1, oacc, ps, g, cl, 0, 0);

  ps += __shfl_xor(ps, 16, 64);
  ps += __shfl_xor(ps, 32, 64);

  if (c < 8) {
    f32x4 inv;
    #pragma unroll
    for (int i = 0; i < 4; ++i) inv[i] = 1.0f / __shfl(ps, g * 4 + i, 64);
    #pragma unroll
    for (int db = 0; db < 4; ++db)
      #pragma unroll
      for (int i = 0; i < 4; ++i)
        O[(size_t)(b * SEQ + q0 + w * 16 + g * 4 + i) * D_MODEL + h * HD + db * 16 + cl] =
            f2bf(oacc[db][i] * inv[i]);
  } else {
    size_t slot = (size_t)bh * 72 + slot_base(c) + sp;
    float* Op = Oparts + slot * 4096;
    float* Sp = Sparts + slot * 64;
    #pragma unroll
    for (int db = 0; db < 4; ++db)
      #pragma unroll
      for (int i = 0; i < 4; ++i)
        Op[(w * 16 + g * 4 + i) * 64 + db * 16 + cl] = oacc[db][i];
    if (g == 0) Sp[w * 16 + cl] = ps;
  }
}

__global__ __launch_bounds__(256) void attn_comb_k(const float* __restrict__ Oparts,
                                                   const float* __restrict__ Sparts,
                                                   unsigned short* __restrict__ O) {
  int t  = threadIdx.x;
  int c  = 8 + (int)(blockIdx.x % 24);
  int bh = (int)(blockIdx.x / 24);
  int b = bh >> 3, h = bh & 7;
  int ns = (c + 8) >> 3;
  size_t slot = (size_t)bh * 72 + slot_base(c);
  const float* O0 = Oparts + slot * 4096;
  const float* S0 = Sparts + slot * 64;
  int r = t >> 2, d0 = (t & 3) * 16;
  f32x4 a0 = {}, a1 = {}, a2 = {}, a3 = {};
  float s = 0.0f;
  for (int si = 0; si < ns; ++si) {
    const float* o = O0 + si * 4096 + r * 64 + d0;
    a0 += *(const f32x4*)(o);
    a1 += *(const f32x4*)(o + 4);
    a2 += *(const f32x4*)(o + 8);
    a3 += *(const f32x4*)(o + 12);
    s  += S0[si * 64 + r];
  }
  float inv = 1.0f / s;
  u16x8 w0, w1;
  #pragma unroll
  for (int j = 0; j < 4; ++j) {
    w0[j]     = f2bf(a0[j] * inv); w0[4 + j] = f2bf(a1[j] * inv);
    w1[j]     = f2bf(a2[j] * inv); w1[4 + j] = f2bf(a3[j] * inv);
  }
  unsigned short* dst = O + (size_t)(b * SEQ + c * 64 + r) * D_MODEL + h * HD + d0;
  *(u16x8*)(dst)     = w0;
  *(u16x8*)(dst + 8) = w1;
}

// ---------------- launch ----------------
extern "C" void kernel_launch(void* const* d_in, const int* in_sizes, int n_in,
                              void* d_out, int out_size, void* d_ws, size_t ws_size,
                              hipStream_t stream) {
  (void)in_sizes; (void)n_in; (void)out_size; (void)ws_size;
  const float* x   = (const float*)d_in[0];
  const float* qw  = (const float*)d_in[1];
  const float* qb  = (const float*)d_in[2];
  const float* kw  = (const float*)d_in[3];
  const float* kbi = (const float*)d_in[4];
  const float* vw  = (const float*)d_in[5];
  const float* vb  = (const float*)d_in[6];
  const float* ow  = (const float*)d_in[7];
  const float* ob  = (const float*)d_in[8];
  const float* w0  = (const float*)d_in[9];
  const float* b0  = (const float*)d_in[10];
  const float* w1  = (const float*)d_in[11];
  const float* b1  = (const float*)d_in[12];
  const float* w2  = (const float*)d_in[13];
  const float* b2  = (const float*)d_in[14];
  const float* anw = (const float*)d_in[15];
  const float* fnw = (const float*)d_in[16];

  char* ws = (char*)d_ws;
  float*          h    = (float*)ws;                              // 0-8MB fp32 residual
  unsigned short* xn   = (unsigned short*)(ws + (8u  << 20));     // 8-12
  unsigned short* q    = (unsigned short*)(ws + (12u << 20));     // 12-16
  unsigned short* k    = (unsigned short*)(ws + (16u << 20));     // 16-20
  unsigned short* vt   = (unsigned short*)(ws + (24u << 20));     // 24-28
  unsigned short* ao   = (unsigned short*)(ws + (28u << 20));     // 28-32
  unsigned short* y    = (unsigned short*)(ws + (32u << 20));     // 32-36
  unsigned short* hbuf = (unsigned short*)(ws + (12u << 20));     // 12-28 (aliases q,k,vt)
  unsigned short* Wq   = (unsigned short*)(ws + (36u << 20));     // 36-42
  unsigned short* Wo   = (unsigned short*)(ws + (42u << 20));     // 42-44
  unsigned short* W01  = (unsigned short*)(ws + (44u << 20));     // 44-60
  unsigned short* W2   = (unsigned short*)(ws + (60u << 20));     // 60-68
  float*          Opar = (float*)(ws + (68u << 20));              // 68-86 (18MB)
  float*          Spar = (float*)(ws + (86u << 20));              // 86-86.3

  prep_t<<<4096, 64, 0, stream>>>(qw, kw, vw, ow, w0, w1, w2, Wq, Wo, W01, W2);
  initrms_k<<<BTOK / 4, 256, 0, stream>>>(x, anw, h, xn);

  for (int l = 0; l < 4; ++l) {
    size_t bo  = (size_t)l * D_MODEL;
    size_t bho = (size_t)l * HIDE;

    gemm7_k<EPI_QKV, 128, 64><<<768, 256, 0, stream>>>(
        xn, Wq + (size_t)l * 786432, qb + bo, kbi + bo, vb + bo,
        q, k, vt, BTOK, 3 * D_MODEL, D_MODEL);
    attn5_k<<<dim3(80, 16), 256, 0, stream>>>(q, k, vt, ao, Opar, Spar);
    attn_comb_k<<<384, 256, 0, stream>>>(Opar, Spar, ao);
    gemm7_k<EPI_PLAIN, 64, 64><<<512, 256, 0, stream>>>(
        ao, Wo + (size_t)l * 262144, ob + bo, nullptr, nullptr,
        y, nullptr, nullptr, BTOK, D_MODEL, D_MODEL);
    addrms_k<<<BTOK / 4, 256, 0, stream>>>(h, y, fnw + bo, xn);

    gemm10d_k<128, 64><<<1024, 256, 0, stream>>>(
        xn, W01 + (size_t)l * 2097152, W01 + (size_t)l * 2097152 + 1048576,
        b0 + bho, b1 + bho, hbuf, BTOK, HIDE, D_MODEL);
    gemm7_k<EPI_PLAIN, 128, 64><<<256, 256, 0, stream>>>(
        hbuf, W2 + (size_t)l * 1048576, b2 + bo, nullptr, nullptr,
        y, nullptr, nullptr, BTOK, D_MODEL, HIDE);
    if (l < 3)
      addrms_k<<<BTOK / 4, 256, 0, stream>>>(h, y, anw + bo + D_MODEL, xn);
    else
      addout_k<<<BTOK / 4, 256, 0, stream>>>(h, y, (float*)d_out);
  }
}

// Round 16
// 461.986 us; speedup vs baseline: 1.0464x; 1.0464x over previous
//
#include <hip/hip_runtime.h>
#include <math.h>

// ---------------- types ----------------
typedef unsigned int   uint4v __attribute__((ext_vector_type(4)));
typedef float          f32x4  __attribute__((ext_vector_type(4)));
typedef __bf16         bf16x8 __attribute__((ext_vector_type(8)));
typedef unsigned short u16x8  __attribute__((ext_vector_type(8)));
typedef unsigned short u16x4  __attribute__((ext_vector_type(4)));

#define D_MODEL 512
#define SEQ     2048
#define BTOK    4096   // B * SEQ
#define HIDE    2048
#define NHEAD   8
#define HD      64

static __device__ __forceinline__ unsigned short f2bf(float f) {
  __bf16 b = (__bf16)f;
  return __builtin_bit_cast(unsigned short, b);
}
static __device__ __forceinline__ float bf2f(unsigned short b) {
  union { unsigned u; float f; } v; v.u = ((unsigned)b) << 16;
  return v.f;
}
static __device__ __forceinline__ bf16x8 ldb8(const unsigned short* p) {
  return __builtin_bit_cast(bf16x8, *(const uint4v*)p);
}
static __device__ __forceinline__ f32x4 mfma16(bf16x8 a, bf16x8 b, f32x4 c) {
  return __builtin_amdgcn_mfma_f32_16x16x32_bf16(a, b, c, 0, 0, 0);
}

typedef unsigned int u32_g __attribute__((address_space(1)));
typedef unsigned int u32_l __attribute__((address_space(3)));
static __device__ __forceinline__ void gload16(const unsigned short* g, unsigned short* l) {
  __builtin_amdgcn_global_load_lds((const u32_g*)(const void*)g,
                                   (u32_l*)(void*)l, 16, 0, 0);
}

#define SWZ(r, off) ((off) ^ (((r) & 7) << 4))
#define QSCALE 0.180336880f   // 0.125 * log2(e)

template<int N>
static __device__ __forceinline__ void waitcnt_vm() {
  asm volatile("s_waitcnt vmcnt(%0)" :: "i"(N) : "memory");
}

// ---------------- weight prep: LDS-tiled transpose f32 [K][N] -> bf16 [N][K] ----
__global__ __launch_bounds__(64) void prep_t(
    const float* __restrict__ qw, const float* __restrict__ kw,
    const float* __restrict__ vw, const float* __restrict__ ow,
    const float* __restrict__ w0, const float* __restrict__ w1,
    const float* __restrict__ w2,
    unsigned short* __restrict__ Wq, unsigned short* __restrict__ Wo,
    unsigned short* __restrict__ W01, unsigned short* __restrict__ W2)
{
  int bid = blockIdx.x;
  int l = bid >> 10;
  int r = bid & 1023;
  const float* src; unsigned short* dst;
  int tr, tc, srcN, dstK;
  if (r < 192) {
    int sel = r >> 6, tt = r & 63;
    tr = tt >> 3; tc = tt & 7;
    src = (sel == 0 ? qw : sel == 1 ? kw : vw) + (size_t)l * 262144;
    srcN = 512; dstK = 512;
    dst = Wq + (size_t)l * 786432 + (size_t)(sel * 512 + tc * 64) * 512 + tr * 64;
  } else if (r < 256) {
    int tt = r - 192; tr = tt >> 3; tc = tt & 7;
    src = ow + (size_t)l * 262144; srcN = 512; dstK = 512;
    dst = Wo + (size_t)l * 262144 + (size_t)(tc * 64) * 512 + tr * 64;
  } else if (r < 768) {
    int idx = r - 256; int sel = idx >> 8; int tt = idx & 255;
    tr = tt >> 5; tc = tt & 31;
    src = (sel ? w1 : w0) + (size_t)l * 1048576; srcN = 2048; dstK = 512;
    dst = W01 + (size_t)l * 2097152 + (size_t)sel * 1048576 + (size_t)(tc * 64) * 512 + tr * 64;
  } else {
    int tt = r - 768; tr = tt >> 3; tc = tt & 7;
    src = w2 + (size_t)l * 1048576; srcN = 512; dstK = 2048;
    dst = W2 + (size_t)l * 1048576 + (size_t)(tc * 64) * 2048 + tr * 64;
  }
  src += (size_t)(tr * 64) * srcN + tc * 64;
  __shared__ unsigned short T[64][68];
  int t = threadIdx.x;
  #pragma unroll
  for (int it = 0; it < 16; ++it) {
    int row = it * 4 + (t >> 4);
    int col = (t & 15) * 4;
    f32x4 v4 = *(const f32x4*)(src + (size_t)row * srcN + col);
    u16x4 o; o[0] = f2bf(v4.x); o[1] = f2bf(v4.y); o[2] = f2bf(v4.z); o[3] = f2bf(v4.w);
    *(u16x4*)&T[row][col] = o;
  }
  __syncthreads();
  unsigned short* orow = dst + (size_t)t * dstK;
  #pragma unroll
  for (int j0 = 0; j0 < 8; ++j0) {
    u16x8 o;
    #pragma unroll
    for (int j = 0; j < 8; ++j) o[j] = T[j0 * 8 + j][t];
    *(u16x8*)(orow + j0 * 8) = o;
  }
}

// ---------------- initrms: h = x; xn = rms(x)*w ----------------
__global__ __launch_bounds__(256) void initrms_k(const float* __restrict__ x,
                                                 const float* __restrict__ w,
                                                 float* __restrict__ h,
                                                 unsigned short* __restrict__ xn) {
  int row  = blockIdx.x * 4 + (threadIdx.x >> 6);
  int lane = threadIdx.x & 63;
  const float* xr = x + (size_t)row * D_MODEL + lane * 8;
  f32x4 v0 = *(const f32x4*)(xr);
  f32x4 v1 = *(const f32x4*)(xr + 4);
  *(f32x4*)(h + (size_t)row * D_MODEL + lane * 8)     = v0;
  *(f32x4*)(h + (size_t)row * D_MODEL + lane * 8 + 4) = v1;
  float ss = v0.x*v0.x + v0.y*v0.y + v0.z*v0.z + v0.w*v0.w
           + v1.x*v1.x + v1.y*v1.y + v1.z*v1.z + v1.w*v1.w;
  #pragma unroll
  for (int m = 1; m < 64; m <<= 1) ss += __shfl_xor(ss, m, 64);
  float inv = 1.0f / (sqrtf(ss * (1.0f / D_MODEL)) + 1e-6f);
  f32x4 w0 = *(const f32x4*)(w + lane * 8);
  f32x4 w1 = *(const f32x4*)(w + lane * 8 + 4);
  u16x8 o;
  o[0] = f2bf(v0.x * w0.x * inv); o[1] = f2bf(v0.y * w0.y * inv);
  o[2] = f2bf(v0.z * w0.z * inv); o[3] = f2bf(v0.w * w0.w * inv);
  o[4] = f2bf(v1.x * w1.x * inv); o[5] = f2bf(v1.y * w1.y * inv);
  o[6] = f2bf(v1.z * w1.z * inv); o[7] = f2bf(v1.w * w1.w * inv);
  *(u16x8*)(xn + (size_t)row * D_MODEL + lane * 8) = o;
}

// ---------------- addrms: h += y(bf16); xn = rms(h)*w ----------------
__global__ __launch_bounds__(256) void addrms_k(float* __restrict__ h,
                                                const unsigned short* __restrict__ y,
                                                const float* __restrict__ w,
                                                unsigned short* __restrict__ xn) {
  int row  = blockIdx.x * 4 + (threadIdx.x >> 6);
  int lane = threadIdx.x & 63;
  float* hr = h + (size_t)row * D_MODEL + lane * 8;
  f32x4 v0 = *(const f32x4*)(hr);
  f32x4 v1 = *(const f32x4*)(hr + 4);
  u16x8 yy = *(const u16x8*)(y + (size_t)row * D_MODEL + lane * 8);
  v0.x += bf2f(yy[0]); v0.y += bf2f(yy[1]); v0.z += bf2f(yy[2]); v0.w += bf2f(yy[3]);
  v1.x += bf2f(yy[4]); v1.y += bf2f(yy[5]); v1.z += bf2f(yy[6]); v1.w += bf2f(yy[7]);
  *(f32x4*)(hr)     = v0;
  *(f32x4*)(hr + 4) = v1;
  float ss = v0.x*v0.x + v0.y*v0.y + v0.z*v0.z + v0.w*v0.w
           + v1.x*v1.x + v1.y*v1.y + v1.z*v1.z + v1.w*v1.w;
  #pragma unroll
  for (int m = 1; m < 64; m <<= 1) ss += __shfl_xor(ss, m, 64);
  float inv = 1.0f / (sqrtf(ss * (1.0f / D_MODEL)) + 1e-6f);
  f32x4 w0 = *(const f32x4*)(w + lane * 8);
  f32x4 w1 = *(const f32x4*)(w + lane * 8 + 4);
  u16x8 o;
  o[0] = f2bf(v0.x * w0.x * inv); o[1] = f2bf(v0.y * w0.y * inv);
  o[2] = f2bf(v0.z * w0.z * inv); o[3] = f2bf(v0.w * w0.w * inv);
  o[4] = f2bf(v1.x * w1.x * inv); o[5] = f2bf(v1.y * w1.y * inv);
  o[6] = f2bf(v1.z * w1.z * inv); o[7] = f2bf(v1.w * w1.w * inv);
  *(u16x8*)(xn + (size_t)row * D_MODEL + lane * 8) = o;
}

// ---------------- addout: out = h + y (final layer, f32 out) --------------
__global__ __launch_bounds__(256) void addout_k(const float* __restrict__ h,
                                                const unsigned short* __restrict__ y,
                                                float* __restrict__ out) {
  int row  = blockIdx.x * 4 + (threadIdx.x >> 6);
  int lane = threadIdx.x & 63;
  const float* hr = h + (size_t)row * D_MODEL + lane * 8;
  f32x4 v0 = *(const f32x4*)(hr);
  f32x4 v1 = *(const f32x4*)(hr + 4);
  u16x8 yy = *(const u16x8*)(y + (size_t)row * D_MODEL + lane * 8);
  v0.x += bf2f(yy[0]); v0.y += bf2f(yy[1]); v0.z += bf2f(yy[2]); v0.w += bf2f(yy[3]);
  v1.x += bf2f(yy[4]); v1.y += bf2f(yy[5]); v1.z += bf2f(yy[6]); v1.w += bf2f(yy[7]);
  *(f32x4*)(out + (size_t)row * D_MODEL + lane * 8)     = v0;
  *(f32x4*)(out + (size_t)row * D_MODEL + lane * 8 + 4) = v1;
}

// ---------------- GEMM v7: counted-vmcnt pipeline + T2 swizzle ------------
#define EPI_QKV   0
#define EPI_PLAIN 1

template<int EPI, int BM, int BN>
__global__ __launch_bounds__(256) void gemm7_k(
    const unsigned short* __restrict__ A,
    const unsigned short* __restrict__ Bt,    // [N][K]
    const float* __restrict__ bias0,
    const float* __restrict__ bias1,
    const float* __restrict__ bias2,
    void* __restrict__ out0,
    void* __restrict__ out1,
    void* __restrict__ out2,                  // QKV: vt [bh][d][s]
    int M, int N, int K)
{
  constexpr int MF = BM / 32;
  constexpr int NF = BN / 32;
  constexpr int ALOADS = BM / 32;
  constexpr int BLOADS = BN / 32;
  constexpr int NL = ALOADS + BLOADS;

  __shared__ __attribute__((aligned(16))) unsigned short Al[2][BM * 64];
  __shared__ __attribute__((aligned(16))) unsigned short Bl[2][BN * 64];

  int nblk = gridDim.x;
  int orig = blockIdx.x;
  int qq = nblk >> 3, rr = nblk & 7, xcd = orig & 7, pos = orig >> 3;
  int lid = (xcd < rr ? xcd * (qq + 1) : rr * (qq + 1) + (xcd - rr) * qq) + pos;
  int numN = N / BN;
  int mt = lid / numN, nt = lid % numN;
  int m0 = mt * BM, n0 = nt * BN;

  int tid = threadIdx.x, lane = tid & 63, w = tid >> 6;
  int wm = w >> 1, wn = w & 1;
  int g = lane >> 4, c = lane & 15;
  int srow = lane >> 3, sslot = lane & 7;
  int sgc = (sslot ^ srow) * 8;

  const unsigned short* aG = A  + (size_t)(m0 + w * (BM / 4) + srow) * K + sgc;
  const unsigned short* bG = Bt + (size_t)(n0 + w * (BN / 4) + srow) * K + sgc;
  int aOff = (w * (BM / 4) + srow) * 64 + sslot * 8;
  int bOff = (w * (BN / 4) + srow) * 64 + sslot * 8;

  f32x4 acc[MF][NF] = {};
  int KT = K >> 6;
  int rk = c & 7;

  #pragma unroll
  for (int t = 0; t < ALOADS; ++t)
    gload16(aG + (size_t)(t * 8) * K, &Al[0][aOff + t * 8 * 64]);
  #pragma unroll
  for (int t = 0; t < BLOADS; ++t)
    gload16(bG + (size_t)(t * 8) * K, &Bl[0][bOff + t * 8 * 64]);

  for (int kt = 0; kt < KT; ++kt) {
    int cur = kt & 1;
    if (kt + 1 < KT) {
      int nb = cur ^ 1;
      const unsigned short* aGk = aG + (kt + 1) * 64;
      const unsigned short* bGk = bG + (kt + 1) * 64;
      #pragma unroll
      for (int t = 0; t < ALOADS; ++t)
        gload16(aGk + (size_t)(t * 8) * K, &Al[nb][aOff + t * 8 * 64]);
      #pragma unroll
      for (int t = 0; t < BLOADS; ++t)
        gload16(bGk + (size_t)(t * 8) * K, &Bl[nb][bOff + t * 8 * 64]);
      waitcnt_vm<NL>();
    } else {
      waitcnt_vm<0>();
    }
    __builtin_amdgcn_s_barrier();
    __builtin_amdgcn_sched_barrier(0);
    #pragma unroll
    for (int ks = 0; ks < 2; ++ks) {
      int slot = (ks * 4 + g) ^ rk;
      bf16x8 af[MF], bfr[NF];
      #pragma unroll
      for (int i = 0; i < MF; ++i)
        af[i] = ldb8(&Al[cur][(wm * (MF * 16) + i * 16 + c) * 64 + slot * 8]);
      #pragma unroll
      for (int j = 0; j < NF; ++j)
        bfr[j] = ldb8(&Bl[cur][(wn * (NF * 16) + j * 16 + c) * 64 + slot * 8]);
      #pragma unroll
      for (int i = 0; i < MF; ++i)
        #pragma unroll
        for (int j = 0; j < NF; ++j)
          acc[i][j] = mfma16(af[i], bfr[j], acc[i][j]);
    }
    __builtin_amdgcn_sched_barrier(0);
    __builtin_amdgcn_s_barrier();
  }

  if (EPI == EPI_QKV) {
    int sel  = n0 >> 9;
    if (sel < 2) {
      #pragma unroll
      for (int i = 0; i < MF; ++i) {
        int mrow = m0 + wm * (MF * 16) + i * 16 + g * 4;
        #pragma unroll
        for (int j = 0; j < NF; ++j) {
          int nloc = (n0 & 511) + wn * (NF * 16) + j * 16 + c;
          const float* bp = sel == 0 ? bias0 : bias1;
          unsigned short* o = (unsigned short*)(sel == 0 ? out0 : out1);
          float sc = (sel == 0) ? QSCALE : 1.0f;
          float bn = bp[nloc];
          #pragma unroll
          for (int ii = 0; ii < 4; ++ii)
            o[(size_t)(mrow + ii) * D_MODEL + nloc] = f2bf((acc[i][j][ii] + bn) * sc);
        }
      }
    } else {
      unsigned short* T = &Al[0][0];            // 64 x 136
      #pragma unroll
      for (int i = 0; i < MF; ++i) {
        int ml0 = wm * (MF * 16) + i * 16 + g * 4;
        #pragma unroll
        for (int j = 0; j < NF; ++j) {
          int nl = wn * (NF * 16) + j * 16 + c;
          float bn = bias2[(n0 & 511) + nl];
          u16x4 pk;
          #pragma unroll
          for (int ii = 0; ii < 4; ++ii) pk[ii] = f2bf(acc[i][j][ii] + bn);
          *(u16x4*)&T[nl * 136 + ml0] = pk;
        }
      }
      __syncthreads();
      int b  = m0 >> 11, s0 = m0 & 2047;
      int hh = (n0 & 511) >> 6;
      int r  = tid >> 2, c0 = (tid & 3) * 32;
      unsigned short* dst = (unsigned short*)out2 +
          ((size_t)(b * NHEAD + hh) * HD + r) * SEQ + s0 + c0;
      #pragma unroll
      for (int u = 0; u < 4; ++u)
        *(u16x8*)(dst + u * 8) = *(u16x8*)&T[r * 136 + c0 + u * 8];
    }
  } else {  // EPI_PLAIN
    #pragma unroll
    for (int i = 0; i < MF; ++i) {
      int mrow = m0 + wm * (MF * 16) + i * 16 + g * 4;
      #pragma unroll
      for (int j = 0; j < NF; ++j) {
        int n = n0 + wn * (NF * 16) + j * 16 + c;
        float bn = bias0[n];
        unsigned short* o = (unsigned short*)out0;
        #pragma unroll
        for (int ii = 0; ii < 4; ++ii)
          o[(size_t)(mrow + ii) * N + n] = f2bf(acc[i][j][ii] + bn);
      }
    }
  }
}

// ---------------- GEMM v10d: fused dual-B gated FFN-up (single buffer,
// 2 barriers/K-step, 32KB LDS -> 4-5 blocks/CU, n-major chunking) ----------
template<int BM, int BN>
__global__ __launch_bounds__(256) void gemm10d_k(
    const unsigned short* __restrict__ A,
    const unsigned short* __restrict__ B0t,   // [N][K]
    const unsigned short* __restrict__ B1t,   // [N][K]
    const float* __restrict__ bias0,
    const float* __restrict__ bias1,
    unsigned short* __restrict__ out,
    int M, int N, int K)
{
  constexpr int MF = BM / 32;
  constexpr int NF = BN / 32;
  constexpr int ALOADS = BM / 32;
  constexpr int BLOADS = BN / 32;

  __shared__ __attribute__((aligned(16))) unsigned short Al[BM * 64];
  __shared__ __attribute__((aligned(16))) unsigned short B0l[BN * 64];
  __shared__ __attribute__((aligned(16))) unsigned short B1l[BN * 64];

  int nblk = gridDim.x;
  int orig = blockIdx.x;
  int qq = nblk >> 3, rr = nblk & 7, xcd = orig & 7, pos = orig >> 3;
  int lid = (xcd < rr ? xcd * (qq + 1) : rr * (qq + 1) + (xcd - rr) * qq) + pos;
  int numM = M / BM;
  int nt = lid / numM, mt = lid % numM;   // n-major: XCD chunk shares B panel
  int m0 = mt * BM, n0 = nt * BN;

  int tid = threadIdx.x, lane = tid & 63, w = tid >> 6;
  int wm = w >> 1, wn = w & 1;
  int g = lane >> 4, c = lane & 15;
  int srow = lane >> 3, sslot = lane & 7;
  int sgc = (sslot ^ srow) * 8;

  const unsigned short* aG  = A   + (size_t)(m0 + w * (BM / 4) + srow) * K + sgc;
  const unsigned short* b0G = B0t + (size_t)(n0 + w * (BN / 4) + srow) * K + sgc;
  const unsigned short* b1G = B1t + (size_t)(n0 + w * (BN / 4) + srow) * K + sgc;
  unsigned short* aL  = &Al [(w * (BM / 4) + srow) * 64 + sslot * 8];
  unsigned short* b0L = &B0l[(w * (BN / 4) + srow) * 64 + sslot * 8];
  unsigned short* b1L = &B1l[(w * (BN / 4) + srow) * 64 + sslot * 8];

  f32x4 acc0[MF][NF] = {};
  f32x4 acc1[MF][NF] = {};
  int KT = K >> 6;
  int rk = c & 7;

  for (int kt = 0; kt < KT; ++kt) {
    if (kt) __syncthreads();
    #pragma unroll
    for (int t = 0; t < ALOADS; ++t)
      gload16(aG + (size_t)(t * 8) * K + kt * 64, aL + t * 8 * 64);
    #pragma unroll
    for (int t = 0; t < BLOADS; ++t) {
      gload16(b0G + (size_t)(t * 8) * K + kt * 64, b0L + t * 8 * 64);
      gload16(b1G + (size_t)(t * 8) * K + kt * 64, b1L + t * 8 * 64);
    }
    __syncthreads();
    #pragma unroll
    for (int ks = 0; ks < 2; ++ks) {
      int slot = (ks * 4 + g) ^ rk;
      bf16x8 af[MF], b0f[NF], b1f[NF];
      #pragma unroll
      for (int i = 0; i < MF; ++i)
        af[i] = ldb8(&Al[(wm * (MF * 16) + i * 16 + c) * 64 + slot * 8]);
      #pragma unroll
      for (int j = 0; j < NF; ++j) {
        b0f[j] = ldb8(&B0l[(wn * (NF * 16) + j * 16 + c) * 64 + slot * 8]);
        b1f[j] = ldb8(&B1l[(wn * (NF * 16) + j * 16 + c) * 64 + slot * 8]);
      }
      #pragma unroll
      for (int i = 0; i < MF; ++i)
        #pragma unroll
        for (int j = 0; j < NF; ++j) {
          acc0[i][j] = mfma16(af[i], b0f[j], acc0[i][j]);
          acc1[i][j] = mfma16(af[i], b1f[j], acc1[i][j]);
        }
    }
  }

  #pragma unroll
  for (int i = 0; i < MF; ++i) {
    int mrow = m0 + wm * (MF * 16) + i * 16 + g * 4;
    #pragma unroll
    for (int j = 0; j < NF; ++j) {
      int n = n0 + wn * (NF * 16) + j * 16 + c;
      float b0n = bias0[n], b1n = bias1[n];
      #pragma unroll
      for (int ii = 0; ii < 4; ++ii) {
        float a  = acc0[i][j][ii] + b0n;
        float gv = acc1[i][j][ii] + b1n;
        float s  = gv / (1.0f + __expf(-gv));
        out[(size_t)(mrow + ii) * N + n] = f2bf(a * s);
      }
    }
  }
}

// ---------------- attention v5: split-K flash, no-max softmax ------------
struct Stg { uint4v k0, k1, v0, v1; };

static __device__ __forceinline__ Stg stage_load(const unsigned short* Kp,
                                                 const unsigned short* Vp,
                                                 int kbase, int srow, int sslot) {
  Stg s;
  const unsigned short* kr = Kp + (size_t)(kbase + srow) * D_MODEL + sslot * 8;
  s.k0 = *(const uint4v*)kr;
  s.k1 = *(const uint4v*)(kr + 32);
  const unsigned short* vr = Vp + (size_t)srow * SEQ + kbase + sslot * 8;
  s.v0 = *(const uint4v*)vr;
  s.v1 = *(const uint4v*)(vr + 32);
  return s;
}
static __device__ __forceinline__ void stage_write(unsigned short* Klb, unsigned short* Vlb,
                                                   const Stg& s, int srow, int sslot) {
  char* kb = (char*)Klb;
  *(uint4v*)(kb + SWZ(srow, srow * 128 + sslot * 16))       = s.k0;
  *(uint4v*)(kb + SWZ(srow, srow * 128 + (sslot + 4) * 16)) = s.k1;
  char* vb = (char*)Vlb;
  *(uint4v*)(vb + SWZ(srow, srow * 128 + sslot * 16))       = s.v0;
  *(uint4v*)(vb + SWZ(srow, srow * 128 + (sslot + 4) * 16)) = s.v1;
}

template<bool MASKED>
static __device__ __forceinline__ void attn_tile(
    const unsigned short* Klb, const unsigned short* Vlb,
    bf16x8 qf0, bf16x8 qf1, f32x4* oacc, float& ps,
    int g, int c, int kbase, int qrow)
{
  f32x4 z[4];
  #pragma unroll
  for (int hh = 0; hh < 4; ++hh) {
    int r = hh * 16 + c;
    const char* base = (const char*)Klb;
    bf16x8 k0 = ldb8((const unsigned short*)(base + SWZ(r, r * 128 + g * 16)));
    bf16x8 k1 = ldb8((const unsigned short*)(base + SWZ(r, r * 128 + 64 + g * 16)));
    f32x4 t = {};
    t = mfma16(k0, qf0, t);
    t = mfma16(k1, qf1, t);
    z[hh] = t;
  }
  u16x8 pa0, pa1;
  #pragma unroll
  for (int hh = 0; hh < 4; ++hh) {
    #pragma unroll
    for (int i = 0; i < 4; ++i) {
      float p = exp2f(z[hh][i]);
      if (MASKED && (kbase + hh * 16 + g * 4 + i > qrow)) p = 0.0f;
      ps += p;
      unsigned short pb = f2bf(p);
      if (hh < 2) pa0[hh * 4 + i] = pb;
      else        pa1[(hh - 2) * 4 + i] = pb;
    }
  }
  bf16x8 af0 = __builtin_bit_cast(bf16x8, pa0);
  bf16x8 af1 = __builtin_bit_cast(bf16x8, pa1);
  #pragma unroll
  for (int db = 0; db < 4; ++db) {
    int r = db * 16 + c;
    const char* base = (const char*)Vlb;
    u16x4 v00 = *(const u16x4*)(base + SWZ(r, r * 128 + g * 8));
    u16x4 v01 = *(const u16x4*)(base + SWZ(r, r * 128 + 32 + g * 8));
    u16x4 v10 = *(const u16x4*)(base + SWZ(r, r * 128 + 64 + g * 8));
    u16x4 v11 = *(const u16x4*)(base + SWZ(r, r * 128 + 96 + g * 8));
    u16x8 vb0, vb1;
    #pragma unroll
    for (int j = 0; j < 4; ++j) {
      vb0[j] = v00[j]; vb0[4 + j] = v01[j];
      vb1[j] = v10[j]; vb1[4 + j] = v11[j];
    }
    oacc[db] = mfma16(af0, __builtin_bit_cast(bf16x8, vb0), oacc[db]);
    oacc[db] = mfma16(af1, __builtin_bit_cast(bf16x8, vb1), oacc[db]);
  }
}

static __device__ __forceinline__ int slot_base(int c) {
  if (c < 16) return (c - 8) * 2;
  if (c < 24) return 16 + (c - 16) * 3;
  return 40 + (c - 24) * 4;
}

__global__ __launch_bounds__(256) void attn5_k(const unsigned short* __restrict__ Q,
                                               const unsigned short* __restrict__ K,
                                               const unsigned short* __restrict__ VT,
                                               unsigned short* __restrict__ O,
                                               float* __restrict__ Oparts,
                                               float* __restrict__ Sparts)
{
  __shared__ __attribute__((aligned(16))) unsigned short Kl[2][64 * 64];
  __shared__ __attribute__((aligned(16))) unsigned short Vl[2][64 * 64];
  int tid = threadIdx.x, lane = tid & 63, w = tid >> 6;
  int g = lane >> 4, cl = lane & 15;

  int z = 79 - (int)blockIdx.x;
  int c, sp;
  if (z < 8)        { c = z;                    sp = 0; }
  else if (z < 24)  { int t2 = z - 8;  c = 8  + (t2 >> 1); sp = t2 & 1; }
  else if (z < 48)  { int t2 = z - 24; c = 16 + t2 / 3;    sp = t2 % 3; }
  else              { int t2 = z - 48; c = 24 + (t2 >> 2); sp = t2 & 3; }
  int kt0 = sp * 8;
  int kt1 = min(c + 1, kt0 + 8);
  bool lastsplit = (kt1 == c + 1);

  int bh = blockIdx.y, b = bh >> 3, h = bh & 7;
  int q0 = c * 64;
  const unsigned short* Qp = Q + (size_t)(b * SEQ) * D_MODEL + h * HD;
  const unsigned short* Kp = K + (size_t)(b * SEQ) * D_MODEL + h * HD;
  const unsigned short* Vp = VT + (size_t)bh * HD * SEQ;

  int qrow = q0 + w * 16 + cl;
  bf16x8 qf0 = ldb8(Qp + (size_t)qrow * D_MODEL + g * 8);
  bf16x8 qf1 = ldb8(Qp + (size_t)qrow * D_MODEL + 32 + g * 8);

  f32x4 oacc[4] = {};
  float ps = 0.0f;
  int srow = tid >> 2, sslot = tid & 3;

  Stg s0 = stage_load(Kp, Vp, kt0 * 64, srow, sslot);
  stage_write(&Kl[0][0], &Vl[0][0], s0, srow, sslot);
  __syncthreads();

  int buf = 0;
  for (int kt = kt0; kt < kt1 - 1; ++kt) {
    Stg sn = stage_load(Kp, Vp, (kt + 1) * 64, srow, sslot);
    attn_tile<false>(&Kl[buf][0], &Vl[buf][0], qf0, qf1, oacc, ps, g, cl, 0, 0);
    stage_write(&Kl[buf ^ 1][0], &Vl[buf ^ 1][0], sn, srow, sslot);
    __syncthreads();
    buf ^= 1;
  }
  if (lastsplit)
    attn_tile<true>(&Kl[buf][0], &Vl[buf][0], qf0, qf1, oacc, ps, g, cl,
                    (kt1 - 1) * 64, qrow);
  else
    attn_tile<false>(&Kl[buf][0], &Vl[buf][0], qf0, qf1, oacc, ps, g, cl, 0, 0);

  ps += __shfl_xor(ps, 16, 64);
  ps += __shfl_xor(ps, 32, 64);

  if (c < 8) {
    f32x4 inv;
    #pragma unroll
    for (int i = 0; i < 4; ++i) inv[i] = 1.0f / __shfl(ps, g * 4 + i, 64);
    #pragma unroll
    for (int db = 0; db < 4; ++db)
      #pragma unroll
      for (int i = 0; i < 4; ++i)
        O[(size_t)(b * SEQ + q0 + w * 16 + g * 4 + i) * D_MODEL + h * HD + db * 16 + cl] =
            f2bf(oacc[db][i] * inv[i]);
  } else {
    size_t slot = (size_t)bh * 72 + slot_base(c) + sp;
    float* Op = Oparts + slot * 4096;
    float* Sp = Sparts + slot * 64;
    #pragma unroll
    for (int db = 0; db < 4; ++db)
      #pragma unroll
      for (int i = 0; i < 4; ++i)
        Op[(w * 16 + g * 4 + i) * 64 + db * 16 + cl] = oacc[db][i];
    if (g == 0) Sp[w * 16 + cl] = ps;
  }
}

__global__ __launch_bounds__(256) void attn_comb_k(const float* __restrict__ Oparts,
                                                   const float* __restrict__ Sparts,
                                                   unsigned short* __restrict__ O) {
  int t  = threadIdx.x;
  int c  = 8 + (int)(blockIdx.x % 24);
  int bh = (int)(blockIdx.x / 24);
  int b = bh >> 3, h = bh & 7;
  int ns = (c + 8) >> 3;
  size_t slot = (size_t)bh * 72 + slot_base(c);
  const float* O0 = Oparts + slot * 4096;
  const float* S0 = Sparts + slot * 64;
  int r = t >> 2, d0 = (t & 3) * 16;
  f32x4 a0 = {}, a1 = {}, a2 = {}, a3 = {};
  float s = 0.0f;
  for (int si = 0; si < ns; ++si) {
    const float* o = O0 + si * 4096 + r * 64 + d0;
    a0 += *(const f32x4*)(o);
    a1 += *(const f32x4*)(o + 4);
    a2 += *(const f32x4*)(o + 8);
    a3 += *(const f32x4*)(o + 12);
    s  += S0[si * 64 + r];
  }
  float inv = 1.0f / s;
  u16x8 w0, w1;
  #pragma unroll
  for (int j = 0; j < 4; ++j) {
    w0[j]     = f2bf(a0[j] * inv); w0[4 + j] = f2bf(a1[j] * inv);
    w1[j]     = f2bf(a2[j] * inv); w1[4 + j] = f2bf(a3[j] * inv);
  }
  unsigned short* dst = O + (size_t)(b * SEQ + c * 64 + r) * D_MODEL + h * HD + d0;
  *(u16x8*)(dst)     = w0;
  *(u16x8*)(dst + 8) = w1;
}

// ---------------- launch ----------------
extern "C" void kernel_launch(void* const* d_in, const int* in_sizes, int n_in,
                              void* d_out, int out_size, void* d_ws, size_t ws_size,
                              hipStream_t stream) {
  (void)in_sizes; (void)n_in; (void)out_size; (void)ws_size;
  const float* x   = (const float*)d_in[0];
  const float* qw  = (const float*)d_in[1];
  const float* qb  = (const float*)d_in[2];
  const float* kw  = (const float*)d_in[3];
  const float* kbi = (const float*)d_in[4];
  const float* vw  = (const float*)d_in[5];
  const float* vb  = (const float*)d_in[6];
  const float* ow  = (const float*)d_in[7];
  const float* ob  = (const float*)d_in[8];
  const float* w0  = (const float*)d_in[9];
  const float* b0  = (const float*)d_in[10];
  const float* w1  = (const float*)d_in[11];
  const float* b1  = (const float*)d_in[12];
  const float* w2  = (const float*)d_in[13];
  const float* b2  = (const float*)d_in[14];
  const float* anw = (const float*)d_in[15];
  const float* fnw = (const float*)d_in[16];

  char* ws = (char*)d_ws;
  float*          h    = (float*)ws;                              // 0-8MB fp32 residual
  unsigned short* xn   = (unsigned short*)(ws + (8u  << 20));     // 8-12
  unsigned short* q    = (unsigned short*)(ws + (12u << 20));     // 12-16
  unsigned short* k    = (unsigned short*)(ws + (16u << 20));     // 16-20
  unsigned short* vt   = (unsigned short*)(ws + (24u << 20));     // 24-28
  unsigned short* ao   = (unsigned short*)(ws + (28u << 20));     // 28-32
  unsigned short* y    = (unsigned short*)(ws + (32u << 20));     // 32-36
  unsigned short* hbuf = (unsigned short*)(ws + (12u << 20));     // 12-28 (aliases q,k,vt)
  unsigned short* Wq   = (unsigned short*)(ws + (36u << 20));     // 36-42
  unsigned short* Wo   = (unsigned short*)(ws + (42u << 20));     // 42-44
  unsigned short* W01  = (unsigned short*)(ws + (44u << 20));     // 44-60
  unsigned short* W2   = (unsigned short*)(ws + (60u << 20));     // 60-68
  float*          Opar = (float*)(ws + (68u << 20));              // 68-86 (18MB)
  float*          Spar = (float*)(ws + (86u << 20));              // 86-86.3

  prep_t<<<4096, 64, 0, stream>>>(qw, kw, vw, ow, w0, w1, w2, Wq, Wo, W01, W2);
  initrms_k<<<BTOK / 4, 256, 0, stream>>>(x, anw, h, xn);

  for (int l = 0; l < 4; ++l) {
    size_t bo  = (size_t)l * D_MODEL;
    size_t bho = (size_t)l * HIDE;

    gemm7_k<EPI_QKV, 128, 64><<<768, 256, 0, stream>>>(
        xn, Wq + (size_t)l * 786432, qb + bo, kbi + bo, vb + bo,
        q, k, vt, BTOK, 3 * D_MODEL, D_MODEL);
    attn5_k<<<dim3(80, 16), 256, 0, stream>>>(q, k, vt, ao, Opar, Spar);
    attn_comb_k<<<384, 256, 0, stream>>>(Opar, Spar, ao);
    gemm7_k<EPI_PLAIN, 64, 64><<<512, 256, 0, stream>>>(
        ao, Wo + (size_t)l * 262144, ob + bo, nullptr, nullptr,
        y, nullptr, nullptr, BTOK, D_MODEL, D_MODEL);
    addrms_k<<<BTOK / 4, 256, 0, stream>>>(h, y, fnw + bo, xn);

    gemm10d_k<128, 64><<<1024, 256, 0, stream>>>(
        xn, W01 + (size_t)l * 2097152, W01 + (size_t)l * 2097152 + 1048576,
        b0 + bho, b1 + bho, hbuf, BTOK, HIDE, D_MODEL);
    gemm7_k<EPI_PLAIN, 64, 64><<<512, 256, 0, stream>>>(
        hbuf, W2 + (size_t)l * 1048576, b2 + bo, nullptr, nullptr,
        y, nullptr, nullptr, BTOK, D_MODEL, HIDE);
    if (l < 3)
      addrms_k<<<BTOK / 4, 256, 0, stream>>>(h, y, anw + bo + D_MODEL, xn);
    else
      addout_k<<<BTOK / 4, 256, 0, stream>>>(h, y, (float*)d_out);
  }
}

// Round 17
// 455.858 us; speedup vs baseline: 1.0605x; 1.0134x over previous
//
#include <hip/hip_runtime.h>
#include <math.h>

// ---------------- types ----------------
typedef unsigned int   uint4v __attribute__((ext_vector_type(4)));
typedef float          f32x4  __attribute__((ext_vector_type(4)));
typedef __bf16         bf16x8 __attribute__((ext_vector_type(8)));
typedef unsigned short u16x8  __attribute__((ext_vector_type(8)));
typedef unsigned short u16x4  __attribute__((ext_vector_type(4)));

#define D_MODEL 512
#define SEQ     2048
#define BTOK    4096   // B * SEQ
#define HIDE    2048
#define NHEAD   8
#define HD      64

static __device__ __forceinline__ unsigned short f2bf(float f) {
  __bf16 b = (__bf16)f;
  return __builtin_bit_cast(unsigned short, b);
}
static __device__ __forceinline__ float bf2f(unsigned short b) {
  union { unsigned u; float f; } v; v.u = ((unsigned)b) << 16;
  return v.f;
}
static __device__ __forceinline__ bf16x8 ldb8(const unsigned short* p) {
  return __builtin_bit_cast(bf16x8, *(const uint4v*)p);
}
static __device__ __forceinline__ f32x4 mfma16(bf16x8 a, bf16x8 b, f32x4 c) {
  return __builtin_amdgcn_mfma_f32_16x16x32_bf16(a, b, c, 0, 0, 0);
}

typedef unsigned int u32_g __attribute__((address_space(1)));
typedef unsigned int u32_l __attribute__((address_space(3)));
static __device__ __forceinline__ void gload16(const unsigned short* g, unsigned short* l) {
  __builtin_amdgcn_global_load_lds((const u32_g*)(const void*)g,
                                   (u32_l*)(void*)l, 16, 0, 0);
}

#define SWZ(r, off) ((off) ^ (((r) & 7) << 4))
#define QSCALE 0.180336880f   // 0.125 * log2(e)

template<int N>
static __device__ __forceinline__ void waitcnt_vm() {
  asm volatile("s_waitcnt vmcnt(%0)" :: "i"(N) : "memory");
}

// ---------------- weight prep: LDS-tiled transpose f32 [K][N] -> bf16 [N][K] ----
__global__ __launch_bounds__(64) void prep_t(
    const float* __restrict__ qw, const float* __restrict__ kw,
    const float* __restrict__ vw, const float* __restrict__ ow,
    const float* __restrict__ w0, const float* __restrict__ w1,
    const float* __restrict__ w2,
    unsigned short* __restrict__ Wq, unsigned short* __restrict__ Wo,
    unsigned short* __restrict__ W01, unsigned short* __restrict__ W2)
{
  int bid = blockIdx.x;
  int l = bid >> 10;
  int r = bid & 1023;
  const float* src; unsigned short* dst;
  int tr, tc, srcN, dstK;
  if (r < 192) {
    int sel = r >> 6, tt = r & 63;
    tr = tt >> 3; tc = tt & 7;
    src = (sel == 0 ? qw : sel == 1 ? kw : vw) + (size_t)l * 262144;
    srcN = 512; dstK = 512;
    dst = Wq + (size_t)l * 786432 + (size_t)(sel * 512 + tc * 64) * 512 + tr * 64;
  } else if (r < 256) {
    int tt = r - 192; tr = tt >> 3; tc = tt & 7;
    src = ow + (size_t)l * 262144; srcN = 512; dstK = 512;
    dst = Wo + (size_t)l * 262144 + (size_t)(tc * 64) * 512 + tr * 64;
  } else if (r < 768) {
    int idx = r - 256; int sel = idx >> 8; int tt = idx & 255;
    tr = tt >> 5; tc = tt & 31;
    src = (sel ? w1 : w0) + (size_t)l * 1048576; srcN = 2048; dstK = 512;
    dst = W01 + (size_t)l * 2097152 + (size_t)sel * 1048576 + (size_t)(tc * 64) * 512 + tr * 64;
  } else {
    int tt = r - 768; tr = tt >> 3; tc = tt & 7;
    src = w2 + (size_t)l * 1048576; srcN = 512; dstK = 2048;
    dst = W2 + (size_t)l * 1048576 + (size_t)(tc * 64) * 2048 + tr * 64;
  }
  src += (size_t)(tr * 64) * srcN + tc * 64;
  __shared__ unsigned short T[64][68];
  int t = threadIdx.x;
  #pragma unroll
  for (int it = 0; it < 16; ++it) {
    int row = it * 4 + (t >> 4);
    int col = (t & 15) * 4;
    f32x4 v4 = *(const f32x4*)(src + (size_t)row * srcN + col);
    u16x4 o; o[0] = f2bf(v4.x); o[1] = f2bf(v4.y); o[2] = f2bf(v4.z); o[3] = f2bf(v4.w);
    *(u16x4*)&T[row][col] = o;
  }
  __syncthreads();
  unsigned short* orow = dst + (size_t)t * dstK;
  #pragma unroll
  for (int j0 = 0; j0 < 8; ++j0) {
    u16x8 o;
    #pragma unroll
    for (int j = 0; j < 8; ++j) o[j] = T[j0 * 8 + j][t];
    *(u16x8*)(orow + j0 * 8) = o;
  }
}

// ---------------- initrms: h = x; xn = rms(x)*w ----------------
__global__ __launch_bounds__(256) void initrms_k(const float* __restrict__ x,
                                                 const float* __restrict__ w,
                                                 float* __restrict__ h,
                                                 unsigned short* __restrict__ xn) {
  int row  = blockIdx.x * 4 + (threadIdx.x >> 6);
  int lane = threadIdx.x & 63;
  const float* xr = x + (size_t)row * D_MODEL + lane * 8;
  f32x4 v0 = *(const f32x4*)(xr);
  f32x4 v1 = *(const f32x4*)(xr + 4);
  *(f32x4*)(h + (size_t)row * D_MODEL + lane * 8)     = v0;
  *(f32x4*)(h + (size_t)row * D_MODEL + lane * 8 + 4) = v1;
  float ss = v0.x*v0.x + v0.y*v0.y + v0.z*v0.z + v0.w*v0.w
           + v1.x*v1.x + v1.y*v1.y + v1.z*v1.z + v1.w*v1.w;
  #pragma unroll
  for (int m = 1; m < 64; m <<= 1) ss += __shfl_xor(ss, m, 64);
  float inv = 1.0f / (sqrtf(ss * (1.0f / D_MODEL)) + 1e-6f);
  f32x4 w0 = *(const f32x4*)(w + lane * 8);
  f32x4 w1 = *(const f32x4*)(w + lane * 8 + 4);
  u16x8 o;
  o[0] = f2bf(v0.x * w0.x * inv); o[1] = f2bf(v0.y * w0.y * inv);
  o[2] = f2bf(v0.z * w0.z * inv); o[3] = f2bf(v0.w * w0.w * inv);
  o[4] = f2bf(v1.x * w1.x * inv); o[5] = f2bf(v1.y * w1.y * inv);
  o[6] = f2bf(v1.z * w1.z * inv); o[7] = f2bf(v1.w * w1.w * inv);
  *(u16x8*)(xn + (size_t)row * D_MODEL + lane * 8) = o;
}

// ---------------- addrms: h += y(bf16); xn = rms(h)*w ----------------
__global__ __launch_bounds__(256) void addrms_k(float* __restrict__ h,
                                                const unsigned short* __restrict__ y,
                                                const float* __restrict__ w,
                                                unsigned short* __restrict__ xn) {
  int row  = blockIdx.x * 4 + (threadIdx.x >> 6);
  int lane = threadIdx.x & 63;
  float* hr = h + (size_t)row * D_MODEL + lane * 8;
  f32x4 v0 = *(const f32x4*)(hr);
  f32x4 v1 = *(const f32x4*)(hr + 4);
  u16x8 yy = *(const u16x8*)(y + (size_t)row * D_MODEL + lane * 8);
  v0.x += bf2f(yy[0]); v0.y += bf2f(yy[1]); v0.z += bf2f(yy[2]); v0.w += bf2f(yy[3]);
  v1.x += bf2f(yy[4]); v1.y += bf2f(yy[5]); v1.z += bf2f(yy[6]); v1.w += bf2f(yy[7]);
  *(f32x4*)(hr)     = v0;
  *(f32x4*)(hr + 4) = v1;
  float ss = v0.x*v0.x + v0.y*v0.y + v0.z*v0.z + v0.w*v0.w
           + v1.x*v1.x + v1.y*v1.y + v1.z*v1.z + v1.w*v1.w;
  #pragma unroll
  for (int m = 1; m < 64; m <<= 1) ss += __shfl_xor(ss, m, 64);
  float inv = 1.0f / (sqrtf(ss * (1.0f / D_MODEL)) + 1e-6f);
  f32x4 w0 = *(const f32x4*)(w + lane * 8);
  f32x4 w1 = *(const f32x4*)(w + lane * 8 + 4);
  u16x8 o;
  o[0] = f2bf(v0.x * w0.x * inv); o[1] = f2bf(v0.y * w0.y * inv);
  o[2] = f2bf(v0.z * w0.z * inv); o[3] = f2bf(v0.w * w0.w * inv);
  o[4] = f2bf(v1.x * w1.x * inv); o[5] = f2bf(v1.y * w1.y * inv);
  o[6] = f2bf(v1.z * w1.z * inv); o[7] = f2bf(v1.w * w1.w * inv);
  *(u16x8*)(xn + (size_t)row * D_MODEL + lane * 8) = o;
}

// ---------------- addout: out = h + y (final layer, f32 out) --------------
__global__ __launch_bounds__(256) void addout_k(const float* __restrict__ h,
                                                const unsigned short* __restrict__ y,
                                                float* __restrict__ out) {
  int row  = blockIdx.x * 4 + (threadIdx.x >> 6);
  int lane = threadIdx.x & 63;
  const float* hr = h + (size_t)row * D_MODEL + lane * 8;
  f32x4 v0 = *(const f32x4*)(hr);
  f32x4 v1 = *(const f32x4*)(hr + 4);
  u16x8 yy = *(const u16x8*)(y + (size_t)row * D_MODEL + lane * 8);
  v0.x += bf2f(yy[0]); v0.y += bf2f(yy[1]); v0.z += bf2f(yy[2]); v0.w += bf2f(yy[3]);
  v1.x += bf2f(yy[4]); v1.y += bf2f(yy[5]); v1.z += bf2f(yy[6]); v1.w += bf2f(yy[7]);
  *(f32x4*)(out + (size_t)row * D_MODEL + lane * 8)     = v0;
  *(f32x4*)(out + (size_t)row * D_MODEL + lane * 8 + 4) = v1;
}

// ---------------- GEMM v7: counted-vmcnt pipeline + T2 swizzle ------------
#define EPI_QKV   0
#define EPI_PLAIN 1

template<int EPI, int BM, int BN>
__global__ __launch_bounds__(256) void gemm7_k(
    const unsigned short* __restrict__ A,
    const unsigned short* __restrict__ Bt,    // [N][K]
    const float* __restrict__ bias0,
    const float* __restrict__ bias1,
    const float* __restrict__ bias2,
    void* __restrict__ out0,
    void* __restrict__ out1,
    void* __restrict__ out2,                  // QKV: vt [bh][d][s]
    int M, int N, int K)
{
  constexpr int MF = BM / 32;
  constexpr int NF = BN / 32;
  constexpr int ALOADS = BM / 32;
  constexpr int BLOADS = BN / 32;
  constexpr int NL = ALOADS + BLOADS;

  __shared__ __attribute__((aligned(16))) unsigned short Al[2][BM * 64];
  __shared__ __attribute__((aligned(16))) unsigned short Bl[2][BN * 64];

  int nblk = gridDim.x;
  int orig = blockIdx.x;
  int qq = nblk >> 3, rr = nblk & 7, xcd = orig & 7, pos = orig >> 3;
  int lid = (xcd < rr ? xcd * (qq + 1) : rr * (qq + 1) + (xcd - rr) * qq) + pos;
  int numN = N / BN;
  int mt = lid / numN, nt = lid % numN;
  int m0 = mt * BM, n0 = nt * BN;

  int tid = threadIdx.x, lane = tid & 63, w = tid >> 6;
  int wm = w >> 1, wn = w & 1;
  int g = lane >> 4, c = lane & 15;
  int srow = lane >> 3, sslot = lane & 7;
  int sgc = (sslot ^ srow) * 8;

  const unsigned short* aG = A  + (size_t)(m0 + w * (BM / 4) + srow) * K + sgc;
  const unsigned short* bG = Bt + (size_t)(n0 + w * (BN / 4) + srow) * K + sgc;
  int aOff = (w * (BM / 4) + srow) * 64 + sslot * 8;
  int bOff = (w * (BN / 4) + srow) * 64 + sslot * 8;

  f32x4 acc[MF][NF] = {};
  int KT = K >> 6;
  int rk = c & 7;

  #pragma unroll
  for (int t = 0; t < ALOADS; ++t)
    gload16(aG + (size_t)(t * 8) * K, &Al[0][aOff + t * 8 * 64]);
  #pragma unroll
  for (int t = 0; t < BLOADS; ++t)
    gload16(bG + (size_t)(t * 8) * K, &Bl[0][bOff + t * 8 * 64]);

  for (int kt = 0; kt < KT; ++kt) {
    int cur = kt & 1;
    if (kt + 1 < KT) {
      int nb = cur ^ 1;
      const unsigned short* aGk = aG + (kt + 1) * 64;
      const unsigned short* bGk = bG + (kt + 1) * 64;
      #pragma unroll
      for (int t = 0; t < ALOADS; ++t)
        gload16(aGk + (size_t)(t * 8) * K, &Al[nb][aOff + t * 8 * 64]);
      #pragma unroll
      for (int t = 0; t < BLOADS; ++t)
        gload16(bGk + (size_t)(t * 8) * K, &Bl[nb][bOff + t * 8 * 64]);
      waitcnt_vm<NL>();
    } else {
      waitcnt_vm<0>();
    }
    __builtin_amdgcn_s_barrier();
    __builtin_amdgcn_sched_barrier(0);
    #pragma unroll
    for (int ks = 0; ks < 2; ++ks) {
      int slot = (ks * 4 + g) ^ rk;
      bf16x8 af[MF], bfr[NF];
      #pragma unroll
      for (int i = 0; i < MF; ++i)
        af[i] = ldb8(&Al[cur][(wm * (MF * 16) + i * 16 + c) * 64 + slot * 8]);
      #pragma unroll
      for (int j = 0; j < NF; ++j)
        bfr[j] = ldb8(&Bl[cur][(wn * (NF * 16) + j * 16 + c) * 64 + slot * 8]);
      #pragma unroll
      for (int i = 0; i < MF; ++i)
        #pragma unroll
        for (int j = 0; j < NF; ++j)
          acc[i][j] = mfma16(af[i], bfr[j], acc[i][j]);
    }
    __builtin_amdgcn_sched_barrier(0);
    __builtin_amdgcn_s_barrier();
  }

  if (EPI == EPI_QKV) {
    int sel  = n0 >> 9;
    if (sel < 2) {
      #pragma unroll
      for (int i = 0; i < MF; ++i) {
        int mrow = m0 + wm * (MF * 16) + i * 16 + g * 4;
        #pragma unroll
        for (int j = 0; j < NF; ++j) {
          int nloc = (n0 & 511) + wn * (NF * 16) + j * 16 + c;
          const float* bp = sel == 0 ? bias0 : bias1;
          unsigned short* o = (unsigned short*)(sel == 0 ? out0 : out1);
          float sc = (sel == 0) ? QSCALE : 1.0f;
          float bn = bp[nloc];
          #pragma unroll
          for (int ii = 0; ii < 4; ++ii)
            o[(size_t)(mrow + ii) * D_MODEL + nloc] = f2bf((acc[i][j][ii] + bn) * sc);
        }
      }
    } else {
      unsigned short* T = &Al[0][0];            // 64 x 136
      #pragma unroll
      for (int i = 0; i < MF; ++i) {
        int ml0 = wm * (MF * 16) + i * 16 + g * 4;
        #pragma unroll
        for (int j = 0; j < NF; ++j) {
          int nl = wn * (NF * 16) + j * 16 + c;
          float bn = bias2[(n0 & 511) + nl];
          u16x4 pk;
          #pragma unroll
          for (int ii = 0; ii < 4; ++ii) pk[ii] = f2bf(acc[i][j][ii] + bn);
          *(u16x4*)&T[nl * 136 + ml0] = pk;
        }
      }
      __syncthreads();
      int b  = m0 >> 11, s0 = m0 & 2047;
      int hh = (n0 & 511) >> 6;
      int r  = tid >> 2, c0 = (tid & 3) * 32;
      unsigned short* dst = (unsigned short*)out2 +
          ((size_t)(b * NHEAD + hh) * HD + r) * SEQ + s0 + c0;
      #pragma unroll
      for (int u = 0; u < 4; ++u)
        *(u16x8*)(dst + u * 8) = *(u16x8*)&T[r * 136 + c0 + u * 8];
    }
  } else {  // EPI_PLAIN
    #pragma unroll
    for (int i = 0; i < MF; ++i) {
      int mrow = m0 + wm * (MF * 16) + i * 16 + g * 4;
      #pragma unroll
      for (int j = 0; j < NF; ++j) {
        int n = n0 + wn * (NF * 16) + j * 16 + c;
        float bn = bias0[n];
        unsigned short* o = (unsigned short*)out0;
        #pragma unroll
        for (int ii = 0; ii < 4; ++ii)
          o[(size_t)(mrow + ii) * N + n] = f2bf(acc[i][j][ii] + bn);
      }
    }
  }
}

// ---------------- GEMM v11d: fused dual-B gated FFN-up (single buffer,
// m-major XCD chunking -> hbuf output is XCD-local for the w2 consumer) ----
template<int BM, int BN>
__global__ __launch_bounds__(256) void gemm11d_k(
    const unsigned short* __restrict__ A,
    const unsigned short* __restrict__ B0t,   // [N][K]
    const unsigned short* __restrict__ B1t,   // [N][K]
    const float* __restrict__ bias0,
    const float* __restrict__ bias1,
    unsigned short* __restrict__ out,
    int M, int N, int K)
{
  constexpr int MF = BM / 32;
  constexpr int NF = BN / 32;
  constexpr int ALOADS = BM / 32;
  constexpr int BLOADS = BN / 32;

  __shared__ __attribute__((aligned(16))) unsigned short Al[BM * 64];
  __shared__ __attribute__((aligned(16))) unsigned short B0l[BN * 64];
  __shared__ __attribute__((aligned(16))) unsigned short B1l[BN * 64];

  int nblk = gridDim.x;
  int orig = blockIdx.x;
  int qq = nblk >> 3, rr = nblk & 7, xcd = orig & 7, pos = orig >> 3;
  int lid = (xcd < rr ? xcd * (qq + 1) : rr * (qq + 1) + (xcd - rr) * qq) + pos;
  int numN = N / BN;
  int mt = lid / numN, nt = lid % numN;   // m-major: XCD chunk = contiguous m slab
  int m0 = mt * BM, n0 = nt * BN;

  int tid = threadIdx.x, lane = tid & 63, w = tid >> 6;
  int wm = w >> 1, wn = w & 1;
  int g = lane >> 4, c = lane & 15;
  int srow = lane >> 3, sslot = lane & 7;
  int sgc = (sslot ^ srow) * 8;

  const unsigned short* aG  = A   + (size_t)(m0 + w * (BM / 4) + srow) * K + sgc;
  const unsigned short* b0G = B0t + (size_t)(n0 + w * (BN / 4) + srow) * K + sgc;
  const unsigned short* b1G = B1t + (size_t)(n0 + w * (BN / 4) + srow) * K + sgc;
  unsigned short* aL  = &Al [(w * (BM / 4) + srow) * 64 + sslot * 8];
  unsigned short* b0L = &B0l[(w * (BN / 4) + srow) * 64 + sslot * 8];
  unsigned short* b1L = &B1l[(w * (BN / 4) + srow) * 64 + sslot * 8];

  f32x4 acc0[MF][NF] = {};
  f32x4 acc1[MF][NF] = {};
  int KT = K >> 6;
  int rk = c & 7;

  for (int kt = 0; kt < KT; ++kt) {
    if (kt) __syncthreads();
    #pragma unroll
    for (int t = 0; t < ALOADS; ++t)
      gload16(aG + (size_t)(t * 8) * K + kt * 64, aL + t * 8 * 64);
    #pragma unroll
    for (int t = 0; t < BLOADS; ++t) {
      gload16(b0G + (size_t)(t * 8) * K + kt * 64, b0L + t * 8 * 64);
      gload16(b1G + (size_t)(t * 8) * K + kt * 64, b1L + t * 8 * 64);
    }
    __syncthreads();
    #pragma unroll
    for (int ks = 0; ks < 2; ++ks) {
      int slot = (ks * 4 + g) ^ rk;
      bf16x8 af[MF], b0f[NF], b1f[NF];
      #pragma unroll
      for (int i = 0; i < MF; ++i)
        af[i] = ldb8(&Al[(wm * (MF * 16) + i * 16 + c) * 64 + slot * 8]);
      #pragma unroll
      for (int j = 0; j < NF; ++j) {
        b0f[j] = ldb8(&B0l[(wn * (NF * 16) + j * 16 + c) * 64 + slot * 8]);
        b1f[j] = ldb8(&B1l[(wn * (NF * 16) + j * 16 + c) * 64 + slot * 8]);
      }
      #pragma unroll
      for (int i = 0; i < MF; ++i)
        #pragma unroll
        for (int j = 0; j < NF; ++j) {
          acc0[i][j] = mfma16(af[i], b0f[j], acc0[i][j]);
          acc1[i][j] = mfma16(af[i], b1f[j], acc1[i][j]);
        }
    }
  }

  #pragma unroll
  for (int i = 0; i < MF; ++i) {
    int mrow = m0 + wm * (MF * 16) + i * 16 + g * 4;
    #pragma unroll
    for (int j = 0; j < NF; ++j) {
      int n = n0 + wn * (NF * 16) + j * 16 + c;
      float b0n = bias0[n], b1n = bias1[n];
      #pragma unroll
      for (int ii = 0; ii < 4; ++ii) {
        float a  = acc0[i][j][ii] + b0n;
        float gv = acc1[i][j][ii] + b1n;
        float s  = gv / (1.0f + __expf(-gv));
        out[(size_t)(mrow + ii) * N + n] = f2bf(a * s);
      }
    }
  }
}

// ---------------- attention v5: split-K flash, no-max softmax ------------
struct Stg { uint4v k0, k1, v0, v1; };

static __device__ __forceinline__ Stg stage_load(const unsigned short* Kp,
                                                 const unsigned short* Vp,
                                                 int kbase, int srow, int sslot) {
  Stg s;
  const unsigned short* kr = Kp + (size_t)(kbase + srow) * D_MODEL + sslot * 8;
  s.k0 = *(const uint4v*)kr;
  s.k1 = *(const uint4v*)(kr + 32);
  const unsigned short* vr = Vp + (size_t)srow * SEQ + kbase + sslot * 8;
  s.v0 = *(const uint4v*)vr;
  s.v1 = *(const uint4v*)(vr + 32);
  return s;
}
static __device__ __forceinline__ void stage_write(unsigned short* Klb, unsigned short* Vlb,
                                                   const Stg& s, int srow, int sslot) {
  char* kb = (char*)Klb;
  *(uint4v*)(kb + SWZ(srow, srow * 128 + sslot * 16))       = s.k0;
  *(uint4v*)(kb + SWZ(srow, srow * 128 + (sslot + 4) * 16)) = s.k1;
  char* vb = (char*)Vlb;
  *(uint4v*)(vb + SWZ(srow, srow * 128 + sslot * 16))       = s.v0;
  *(uint4v*)(vb + SWZ(srow, srow * 128 + (sslot + 4) * 16)) = s.v1;
}

template<bool MASKED>
static __device__ __forceinline__ void attn_tile(
    const unsigned short* Klb, const unsigned short* Vlb,
    bf16x8 qf0, bf16x8 qf1, f32x4* oacc, float& ps,
    int g, int c, int kbase, int qrow)
{
  f32x4 z[4];
  #pragma unroll
  for (int hh = 0; hh < 4; ++hh) {
    int r = hh * 16 + c;
    const char* base = (const char*)Klb;
    bf16x8 k0 = ldb8((const unsigned short*)(base + SWZ(r, r * 128 + g * 16)));
    bf16x8 k1 = ldb8((const unsigned short*)(base + SWZ(r, r * 128 + 64 + g * 16)));
    f32x4 t = {};
    t = mfma16(k0, qf0, t);
    t = mfma16(k1, qf1, t);
    z[hh] = t;
  }
  u16x8 pa0, pa1;
  #pragma unroll
  for (int hh = 0; hh < 4; ++hh) {
    #pragma unroll
    for (int i = 0; i < 4; ++i) {
      float p = exp2f(z[hh][i]);
      if (MASKED && (kbase + hh * 16 + g * 4 + i > qrow)) p = 0.0f;
      ps += p;
      unsigned short pb = f2bf(p);
      if (hh < 2) pa0[hh * 4 + i] = pb;
      else        pa1[(hh - 2) * 4 + i] = pb;
    }
  }
  bf16x8 af0 = __builtin_bit_cast(bf16x8, pa0);
  bf16x8 af1 = __builtin_bit_cast(bf16x8, pa1);
  #pragma unroll
  for (int db = 0; db < 4; ++db) {
    int r = db * 16 + c;
    const char* base = (const char*)Vlb;
    u16x4 v00 = *(const u16x4*)(base + SWZ(r, r * 128 + g * 8));
    u16x4 v01 = *(const u16x4*)(base + SWZ(r, r * 128 + 32 + g * 8));
    u16x4 v10 = *(const u16x4*)(base + SWZ(r, r * 128 + 64 + g * 8));
    u16x4 v11 = *(const u16x4*)(base + SWZ(r, r * 128 + 96 + g * 8));
    u16x8 vb0, vb1;
    #pragma unroll
    for (int j = 0; j < 4; ++j) {
      vb0[j] = v00[j]; vb0[4 + j] = v01[j];
      vb1[j] = v10[j]; vb1[4 + j] = v11[j];
    }
    oacc[db] = mfma16(af0, __builtin_bit_cast(bf16x8, vb0), oacc[db]);
    oacc[db] = mfma16(af1, __builtin_bit_cast(bf16x8, vb1), oacc[db]);
  }
}

static __device__ __forceinline__ int slot_base(int c) {
  if (c < 16) return (c - 8) * 2;
  if (c < 24) return 16 + (c - 16) * 3;
  return 40 + (c - 24) * 4;
}

__global__ __launch_bounds__(256) void attn5_k(const unsigned short* __restrict__ Q,
                                               const unsigned short* __restrict__ K,
                                               const unsigned short* __restrict__ VT,
                                               unsigned short* __restrict__ O,
                                               float* __restrict__ Oparts,
                                               float* __restrict__ Sparts)
{
  __shared__ __attribute__((aligned(16))) unsigned short Kl[2][64 * 64];
  __shared__ __attribute__((aligned(16))) unsigned short Vl[2][64 * 64];
  int tid = threadIdx.x, lane = tid & 63, w = tid >> 6;
  int g = lane >> 4, cl = lane & 15;

  int z = 79 - (int)blockIdx.x;
  int c, sp;
  if (z < 8)        { c = z;                    sp = 0; }
  else if (z < 24)  { int t2 = z - 8;  c = 8  + (t2 >> 1); sp = t2 & 1; }
  else if (z < 48)  { int t2 = z - 24; c = 16 + t2 / 3;    sp = t2 % 3; }
  else              { int t2 = z - 48; c = 24 + (t2 >> 2); sp = t2 & 3; }
  int kt0 = sp * 8;
  int kt1 = min(c + 1, kt0 + 8);
  bool lastsplit = (kt1 == c + 1);

  int bh = blockIdx.y, b = bh >> 3, h = bh & 7;
  int q0 = c * 64;
  const unsigned short* Qp = Q + (size_t)(b * SEQ) * D_MODEL + h * HD;
  const unsigned short* Kp = K + (size_t)(b * SEQ) * D_MODEL + h * HD;
  const unsigned short* Vp = VT + (size_t)bh * HD * SEQ;

  int qrow = q0 + w * 16 + cl;
  bf16x8 qf0 = ldb8(Qp + (size_t)qrow * D_MODEL + g * 8);
  bf16x8 qf1 = ldb8(Qp + (size_t)qrow * D_MODEL + 32 + g * 8);

  f32x4 oacc[4] = {};
  float ps = 0.0f;
  int srow = tid >> 2, sslot = tid & 3;

  Stg s0 = stage_load(Kp, Vp, kt0 * 64, srow, sslot);
  stage_write(&Kl[0][0], &Vl[0][0], s0, srow, sslot);
  __syncthreads();

  int buf = 0;
  for (int kt = kt0; kt < kt1 - 1; ++kt) {
    Stg sn = stage_load(Kp, Vp, (kt + 1) * 64, srow, sslot);
    attn_tile<false>(&Kl[buf][0], &Vl[buf][0], qf0, qf1, oacc, ps, g, cl, 0, 0);
    stage_write(&Kl[buf ^ 1][0], &Vl[buf ^ 1][0], sn, srow, sslot);
    __syncthreads();
    buf ^= 1;
  }
  if (lastsplit)
    attn_tile<true>(&Kl[buf][0], &Vl[buf][0], qf0, qf1, oacc, ps, g, cl,
                    (kt1 - 1) * 64, qrow);
  else
    attn_tile<false>(&Kl[buf][0], &Vl[buf][0], qf0, qf1, oacc, ps, g, cl, 0, 0);

  ps += __shfl_xor(ps, 16, 64);
  ps += __shfl_xor(ps, 32, 64);

  if (c < 8) {
    f32x4 inv;
    #pragma unroll
    for (int i = 0; i < 4; ++i) inv[i] = 1.0f / __shfl(ps, g * 4 + i, 64);
    #pragma unroll
    for (int db = 0; db < 4; ++db)
      #pragma unroll
      for (int i = 0; i < 4; ++i)
        O[(size_t)(b * SEQ + q0 + w * 16 + g * 4 + i) * D_MODEL + h * HD + db * 16 + cl] =
            f2bf(oacc[db][i] * inv[i]);
  } else {
    size_t slot = (size_t)bh * 72 + slot_base(c) + sp;
    float* Op = Oparts + slot * 4096;
    float* Sp = Sparts + slot * 64;
    #pragma unroll
    for (int db = 0; db < 4; ++db)
      #pragma unroll
      for (int i = 0; i < 4; ++i)
        Op[(w * 16 + g * 4 + i) * 64 + db * 16 + cl] = oacc[db][i];
    if (g == 0) Sp[w * 16 + cl] = ps;
  }
}

__global__ __launch_bounds__(256) void attn_comb_k(const float* __restrict__ Oparts,
                                                   const float* __restrict__ Sparts,
                                                   unsigned short* __restrict__ O) {
  int t  = threadIdx.x;
  int c  = 8 + (int)(blockIdx.x % 24);
  int bh = (int)(blockIdx.x / 24);
  int b = bh >> 3, h = bh & 7;
  int ns = (c + 8) >> 3;
  size_t slot = (size_t)bh * 72 + slot_base(c);
  const float* O0 = Oparts + slot * 4096;
  const float* S0 = Sparts + slot * 64;
  int r = t >> 2, d0 = (t & 3) * 16;
  f32x4 a0 = {}, a1 = {}, a2 = {}, a3 = {};
  float s = 0.0f;
  for (int si = 0; si < ns; ++si) {
    const float* o = O0 + si * 4096 + r * 64 + d0;
    a0 += *(const f32x4*)(o);
    a1 += *(const f32x4*)(o + 4);
    a2 += *(const f32x4*)(o + 8);
    a3 += *(const f32x4*)(o + 12);
    s  += S0[si * 64 + r];
  }
  float inv = 1.0f / s;
  u16x8 w0, w1;
  #pragma unroll
  for (int j = 0; j < 4; ++j) {
    w0[j]     = f2bf(a0[j] * inv); w0[4 + j] = f2bf(a1[j] * inv);
    w1[j]     = f2bf(a2[j] * inv); w1[4 + j] = f2bf(a3[j] * inv);
  }
  unsigned short* dst = O + (size_t)(b * SEQ + c * 64 + r) * D_MODEL + h * HD + d0;
  *(u16x8*)(dst)     = w0;
  *(u16x8*)(dst + 8) = w1;
}

// ---------------- launch ----------------
extern "C" void kernel_launch(void* const* d_in, const int* in_sizes, int n_in,
                              void* d_out, int out_size, void* d_ws, size_t ws_size,
                              hipStream_t stream) {
  (void)in_sizes; (void)n_in; (void)out_size; (void)ws_size;
  const float* x   = (const float*)d_in[0];
  const float* qw  = (const float*)d_in[1];
  const float* qb  = (const float*)d_in[2];
  const float* kw  = (const float*)d_in[3];
  const float* kbi = (const float*)d_in[4];
  const float* vw  = (const float*)d_in[5];
  const float* vb  = (const float*)d_in[6];
  const float* ow  = (const float*)d_in[7];
  const float* ob  = (const float*)d_in[8];
  const float* w0  = (const float*)d_in[9];
  const float* b0  = (const float*)d_in[10];
  const float* w1  = (const float*)d_in[11];
  const float* b1  = (const float*)d_in[12];
  const float* w2  = (const float*)d_in[13];
  const float* b2  = (const float*)d_in[14];
  const float* anw = (const float*)d_in[15];
  const float* fnw = (const float*)d_in[16];

  char* ws = (char*)d_ws;
  float*          h    = (float*)ws;                              // 0-8MB fp32 residual
  unsigned short* xn   = (unsigned short*)(ws + (8u  << 20));     // 8-12
  unsigned short* q    = (unsigned short*)(ws + (12u << 20));     // 12-16
  unsigned short* k    = (unsigned short*)(ws + (16u << 20));     // 16-20
  unsigned short* vt   = (unsigned short*)(ws + (24u << 20));     // 24-28
  unsigned short* ao   = (unsigned short*)(ws + (28u << 20));     // 28-32
  unsigned short* y    = (unsigned short*)(ws + (32u << 20));     // 32-36
  unsigned short* hbuf = (unsigned short*)(ws + (12u << 20));     // 12-28 (aliases q,k,vt)
  unsigned short* Wq   = (unsigned short*)(ws + (36u << 20));     // 36-42
  unsigned short* Wo   = (unsigned short*)(ws + (42u << 20));     // 42-44
  unsigned short* W01  = (unsigned short*)(ws + (44u << 20));     // 44-60
  unsigned short* W2   = (unsigned short*)(ws + (60u << 20));     // 60-68
  float*          Opar = (float*)(ws + (68u << 20));              // 68-86 (18MB)
  float*          Spar = (float*)(ws + (86u << 20));              // 86-86.3

  prep_t<<<4096, 64, 0, stream>>>(qw, kw, vw, ow, w0, w1, w2, Wq, Wo, W01, W2);
  initrms_k<<<BTOK / 4, 256, 0, stream>>>(x, anw, h, xn);

  for (int l = 0; l < 4; ++l) {
    size_t bo  = (size_t)l * D_MODEL;
    size_t bho = (size_t)l * HIDE;

    gemm7_k<EPI_QKV, 128, 64><<<768, 256, 0, stream>>>(
        xn, Wq + (size_t)l * 786432, qb + bo, kbi + bo, vb + bo,
        q, k, vt, BTOK, 3 * D_MODEL, D_MODEL);
    attn5_k<<<dim3(80, 16), 256, 0, stream>>>(q, k, vt, ao, Opar, Spar);
    attn_comb_k<<<384, 256, 0, stream>>>(Opar, Spar, ao);
    gemm7_k<EPI_PLAIN, 64, 64><<<512, 256, 0, stream>>>(
        ao, Wo + (size_t)l * 262144, ob + bo, nullptr, nullptr,
        y, nullptr, nullptr, BTOK, D_MODEL, D_MODEL);
    addrms_k<<<BTOK / 4, 256, 0, stream>>>(h, y, fnw + bo, xn);

    gemm11d_k<128, 64><<<1024, 256, 0, stream>>>(
        xn, W01 + (size_t)l * 2097152, W01 + (size_t)l * 2097152 + 1048576,
        b0 + bho, b1 + bho, hbuf, BTOK, HIDE, D_MODEL);
    gemm7_k<EPI_PLAIN, 64, 64><<<512, 256, 0, stream>>>(
        hbuf, W2 + (size_t)l * 1048576, b2 + bo, nullptr, nullptr,
        y, nullptr, nullptr, BTOK, D_MODEL, HIDE);
    if (l < 3)
      addrms_k<<<BTOK / 4, 256, 0, stream>>>(h, y, anw + bo + D_MODEL, xn);
    else
      addout_k<<<BTOK / 4, 256, 0, stream>>>(h, y, (float*)d_out);
  }
}

// Round 18
// 430.948 us; speedup vs baseline: 1.1218x; 1.0578x over previous
//
#include <hip/hip_runtime.h>
#include <math.h>

// ---------------- types ----------------
typedef unsigned int   uint4v __attribute__((ext_vector_type(4)));
typedef float          f32x4  __attribute__((ext_vector_type(4)));
typedef __bf16         bf16x8 __attribute__((ext_vector_type(8)));
typedef unsigned short u16x8  __attribute__((ext_vector_type(8)));
typedef unsigned short u16x4  __attribute__((ext_vector_type(4)));

#define D_MODEL 512
#define SEQ     2048
#define BTOK    4096   // B * SEQ
#define HIDE    2048
#define NHEAD   8
#define HD      64

static __device__ __forceinline__ unsigned short f2bf(float f) {
  __bf16 b = (__bf16)f;
  return __builtin_bit_cast(unsigned short, b);
}
static __device__ __forceinline__ float bf2f(unsigned short b) {
  union { unsigned u; float f; } v; v.u = ((unsigned)b) << 16;
  return v.f;
}
static __device__ __forceinline__ bf16x8 ldb8(const unsigned short* p) {
  return __builtin_bit_cast(bf16x8, *(const uint4v*)p);
}
static __device__ __forceinline__ f32x4 mfma16(bf16x8 a, bf16x8 b, f32x4 c) {
  return __builtin_amdgcn_mfma_f32_16x16x32_bf16(a, b, c, 0, 0, 0);
}

typedef unsigned int u32_g __attribute__((address_space(1)));
typedef unsigned int u32_l __attribute__((address_space(3)));
static __device__ __forceinline__ void gload16(const unsigned short* g, unsigned short* l) {
  __builtin_amdgcn_global_load_lds((const u32_g*)(const void*)g,
                                   (u32_l*)(void*)l, 16, 0, 0);
}

#define SWZ(r, off) ((off) ^ (((r) & 7) << 4))
#define QSCALE 0.180336880f   // 0.125 * log2(e)

template<int N>
static __device__ __forceinline__ void waitcnt_vm() {
  asm volatile("s_waitcnt vmcnt(%0)" :: "i"(N) : "memory");
}

// ---------------- weight prep: LDS-tiled transpose f32 [K][N] -> bf16 [N][K] ----
__global__ __launch_bounds__(64) void prep_t(
    const float* __restrict__ qw, const float* __restrict__ kw,
    const float* __restrict__ vw, const float* __restrict__ ow,
    const float* __restrict__ w0, const float* __restrict__ w1,
    const float* __restrict__ w2,
    unsigned short* __restrict__ Wq, unsigned short* __restrict__ Wo,
    unsigned short* __restrict__ W01, unsigned short* __restrict__ W2)
{
  int bid = blockIdx.x;
  int l = bid >> 10;
  int r = bid & 1023;
  const float* src; unsigned short* dst;
  int tr, tc, srcN, dstK;
  if (r < 192) {
    int sel = r >> 6, tt = r & 63;
    tr = tt >> 3; tc = tt & 7;
    src = (sel == 0 ? qw : sel == 1 ? kw : vw) + (size_t)l * 262144;
    srcN = 512; dstK = 512;
    dst = Wq + (size_t)l * 786432 + (size_t)(sel * 512 + tc * 64) * 512 + tr * 64;
  } else if (r < 256) {
    int tt = r - 192; tr = tt >> 3; tc = tt & 7;
    src = ow + (size_t)l * 262144; srcN = 512; dstK = 512;
    dst = Wo + (size_t)l * 262144 + (size_t)(tc * 64) * 512 + tr * 64;
  } else if (r < 768) {
    int idx = r - 256; int sel = idx >> 8; int tt = idx & 255;
    tr = tt >> 5; tc = tt & 31;
    src = (sel ? w1 : w0) + (size_t)l * 1048576; srcN = 2048; dstK = 512;
    dst = W01 + (size_t)l * 2097152 + (size_t)sel * 1048576 + (size_t)(tc * 64) * 512 + tr * 64;
  } else {
    int tt = r - 768; tr = tt >> 3; tc = tt & 7;
    src = w2 + (size_t)l * 1048576; srcN = 512; dstK = 2048;
    dst = W2 + (size_t)l * 1048576 + (size_t)(tc * 64) * 2048 + tr * 64;
  }
  src += (size_t)(tr * 64) * srcN + tc * 64;
  __shared__ unsigned short T[64][68];
  int t = threadIdx.x;
  #pragma unroll
  for (int it = 0; it < 16; ++it) {
    int row = it * 4 + (t >> 4);
    int col = (t & 15) * 4;
    f32x4 v4 = *(const f32x4*)(src + (size_t)row * srcN + col);
    u16x4 o; o[0] = f2bf(v4.x); o[1] = f2bf(v4.y); o[2] = f2bf(v4.z); o[3] = f2bf(v4.w);
    *(u16x4*)&T[row][col] = o;
  }
  __syncthreads();
  unsigned short* orow = dst + (size_t)t * dstK;
  #pragma unroll
  for (int j0 = 0; j0 < 8; ++j0) {
    u16x8 o;
    #pragma unroll
    for (int j = 0; j < 8; ++j) o[j] = T[j0 * 8 + j][t];
    *(u16x8*)(orow + j0 * 8) = o;
  }
}

// ---------------- initrms: h = x; xn = rms(x)*w ----------------
__global__ __launch_bounds__(256) void initrms_k(const float* __restrict__ x,
                                                 const float* __restrict__ w,
                                                 float* __restrict__ h,
                                                 unsigned short* __restrict__ xn) {
  int row  = blockIdx.x * 4 + (threadIdx.x >> 6);
  int lane = threadIdx.x & 63;
  const float* xr = x + (size_t)row * D_MODEL + lane * 8;
  f32x4 v0 = *(const f32x4*)(xr);
  f32x4 v1 = *(const f32x4*)(xr + 4);
  *(f32x4*)(h + (size_t)row * D_MODEL + lane * 8)     = v0;
  *(f32x4*)(h + (size_t)row * D_MODEL + lane * 8 + 4) = v1;
  float ss = v0.x*v0.x + v0.y*v0.y + v0.z*v0.z + v0.w*v0.w
           + v1.x*v1.x + v1.y*v1.y + v1.z*v1.z + v1.w*v1.w;
  #pragma unroll
  for (int m = 1; m < 64; m <<= 1) ss += __shfl_xor(ss, m, 64);
  float inv = 1.0f / (sqrtf(ss * (1.0f / D_MODEL)) + 1e-6f);
  f32x4 w0 = *(const f32x4*)(w + lane * 8);
  f32x4 w1 = *(const f32x4*)(w + lane * 8 + 4);
  u16x8 o;
  o[0] = f2bf(v0.x * w0.x * inv); o[1] = f2bf(v0.y * w0.y * inv);
  o[2] = f2bf(v0.z * w0.z * inv); o[3] = f2bf(v0.w * w0.w * inv);
  o[4] = f2bf(v1.x * w1.x * inv); o[5] = f2bf(v1.y * w1.y * inv);
  o[6] = f2bf(v1.z * w1.z * inv); o[7] = f2bf(v1.w * w1.w * inv);
  *(u16x8*)(xn + (size_t)row * D_MODEL + lane * 8) = o;
}

// ---------------- addrms: h += y(bf16); xn = rms(h)*w ----------------
__global__ __launch_bounds__(256) void addrms_k(float* __restrict__ h,
                                                const unsigned short* __restrict__ y,
                                                const float* __restrict__ w,
                                                unsigned short* __restrict__ xn) {
  int row  = blockIdx.x * 4 + (threadIdx.x >> 6);
  int lane = threadIdx.x & 63;
  float* hr = h + (size_t)row * D_MODEL + lane * 8;
  f32x4 v0 = *(const f32x4*)(hr);
  f32x4 v1 = *(const f32x4*)(hr + 4);
  u16x8 yy = *(const u16x8*)(y + (size_t)row * D_MODEL + lane * 8);
  v0.x += bf2f(yy[0]); v0.y += bf2f(yy[1]); v0.z += bf2f(yy[2]); v0.w += bf2f(yy[3]);
  v1.x += bf2f(yy[4]); v1.y += bf2f(yy[5]); v1.z += bf2f(yy[6]); v1.w += bf2f(yy[7]);
  *(f32x4*)(hr)     = v0;
  *(f32x4*)(hr + 4) = v1;
  float ss = v0.x*v0.x + v0.y*v0.y + v0.z*v0.z + v0.w*v0.w
           + v1.x*v1.x + v1.y*v1.y + v1.z*v1.z + v1.w*v1.w;
  #pragma unroll
  for (int m = 1; m < 64; m <<= 1) ss += __shfl_xor(ss, m, 64);
  float inv = 1.0f / (sqrtf(ss * (1.0f / D_MODEL)) + 1e-6f);
  f32x4 w0 = *(const f32x4*)(w + lane * 8);
  f32x4 w1 = *(const f32x4*)(w + lane * 8 + 4);
  u16x8 o;
  o[0] = f2bf(v0.x * w0.x * inv); o[1] = f2bf(v0.y * w0.y * inv);
  o[2] = f2bf(v0.z * w0.z * inv); o[3] = f2bf(v0.w * w0.w * inv);
  o[4] = f2bf(v1.x * w1.x * inv); o[5] = f2bf(v1.y * w1.y * inv);
  o[6] = f2bf(v1.z * w1.z * inv); o[7] = f2bf(v1.w * w1.w * inv);
  *(u16x8*)(xn + (size_t)row * D_MODEL + lane * 8) = o;
}

// ---------------- addrms2: h += y0+y1 (split-K partials); xn = rms(h)*w ----
__global__ __launch_bounds__(256) void addrms2_k(float* __restrict__ h,
                                                 const unsigned short* __restrict__ y0,
                                                 const unsigned short* __restrict__ y1,
                                                 const float* __restrict__ w,
                                                 unsigned short* __restrict__ xn) {
  int row  = blockIdx.x * 4 + (threadIdx.x >> 6);
  int lane = threadIdx.x & 63;
  float* hr = h + (size_t)row * D_MODEL + lane * 8;
  f32x4 v0 = *(const f32x4*)(hr);
  f32x4 v1 = *(const f32x4*)(hr + 4);
  u16x8 a = *(const u16x8*)(y0 + (size_t)row * D_MODEL + lane * 8);
  u16x8 b = *(const u16x8*)(y1 + (size_t)row * D_MODEL + lane * 8);
  v0.x += bf2f(a[0]) + bf2f(b[0]); v0.y += bf2f(a[1]) + bf2f(b[1]);
  v0.z += bf2f(a[2]) + bf2f(b[2]); v0.w += bf2f(a[3]) + bf2f(b[3]);
  v1.x += bf2f(a[4]) + bf2f(b[4]); v1.y += bf2f(a[5]) + bf2f(b[5]);
  v1.z += bf2f(a[6]) + bf2f(b[6]); v1.w += bf2f(a[7]) + bf2f(b[7]);
  *(f32x4*)(hr)     = v0;
  *(f32x4*)(hr + 4) = v1;
  float ss = v0.x*v0.x + v0.y*v0.y + v0.z*v0.z + v0.w*v0.w
           + v1.x*v1.x + v1.y*v1.y + v1.z*v1.z + v1.w*v1.w;
  #pragma unroll
  for (int m = 1; m < 64; m <<= 1) ss += __shfl_xor(ss, m, 64);
  float inv = 1.0f / (sqrtf(ss * (1.0f / D_MODEL)) + 1e-6f);
  f32x4 w0 = *(const f32x4*)(w + lane * 8);
  f32x4 w1 = *(const f32x4*)(w + lane * 8 + 4);
  u16x8 o;
  o[0] = f2bf(v0.x * w0.x * inv); o[1] = f2bf(v0.y * w0.y * inv);
  o[2] = f2bf(v0.z * w0.z * inv); o[3] = f2bf(v0.w * w0.w * inv);
  o[4] = f2bf(v1.x * w1.x * inv); o[5] = f2bf(v1.y * w1.y * inv);
  o[6] = f2bf(v1.z * w1.z * inv); o[7] = f2bf(v1.w * w1.w * inv);
  *(u16x8*)(xn + (size_t)row * D_MODEL + lane * 8) = o;
}

// ---------------- addout2: out = h + y0 + y1 (final layer, f32 out) -------
__global__ __launch_bounds__(256) void addout2_k(const float* __restrict__ h,
                                                 const unsigned short* __restrict__ y0,
                                                 const unsigned short* __restrict__ y1,
                                                 float* __restrict__ out) {
  int row  = blockIdx.x * 4 + (threadIdx.x >> 6);
  int lane = threadIdx.x & 63;
  const float* hr = h + (size_t)row * D_MODEL + lane * 8;
  f32x4 v0 = *(const f32x4*)(hr);
  f32x4 v1 = *(const f32x4*)(hr + 4);
  u16x8 a = *(const u16x8*)(y0 + (size_t)row * D_MODEL + lane * 8);
  u16x8 b = *(const u16x8*)(y1 + (size_t)row * D_MODEL + lane * 8);
  v0.x += bf2f(a[0]) + bf2f(b[0]); v0.y += bf2f(a[1]) + bf2f(b[1]);
  v0.z += bf2f(a[2]) + bf2f(b[2]); v0.w += bf2f(a[3]) + bf2f(b[3]);
  v1.x += bf2f(a[4]) + bf2f(b[4]); v1.y += bf2f(a[5]) + bf2f(b[5]);
  v1.z += bf2f(a[6]) + bf2f(b[6]); v1.w += bf2f(a[7]) + bf2f(b[7]);
  *(f32x4*)(out + (size_t)row * D_MODEL + lane * 8)     = v0;
  *(f32x4*)(out + (size_t)row * D_MODEL + lane * 8 + 4) = v1;
}

// ---------------- GEMM v7: counted-vmcnt pipeline + T2 swizzle ------------
#define EPI_QKV   0
#define EPI_PLAIN 1

template<int EPI, int BM, int BN>
__global__ __launch_bounds__(256) void gemm7_k(
    const unsigned short* __restrict__ A,
    const unsigned short* __restrict__ Bt,    // [N][K]
    const float* __restrict__ bias0,
    const float* __restrict__ bias1,
    const float* __restrict__ bias2,
    void* __restrict__ out0,
    void* __restrict__ out1,
    void* __restrict__ out2,                  // QKV: vt [bh][d][s]
    int M, int N, int K)
{
  constexpr int MF = BM / 32;
  constexpr int NF = BN / 32;
  constexpr int ALOADS = BM / 32;
  constexpr int BLOADS = BN / 32;
  constexpr int NL = ALOADS + BLOADS;

  __shared__ __attribute__((aligned(16))) unsigned short Al[2][BM * 64];
  __shared__ __attribute__((aligned(16))) unsigned short Bl[2][BN * 64];

  int nblk = gridDim.x;
  int orig = blockIdx.x;
  int qq = nblk >> 3, rr = nblk & 7, xcd = orig & 7, pos = orig >> 3;
  int lid = (xcd < rr ? xcd * (qq + 1) : rr * (qq + 1) + (xcd - rr) * qq) + pos;
  int numN = N / BN;
  int mt = lid / numN, nt = lid % numN;
  int m0 = mt * BM, n0 = nt * BN;

  int tid = threadIdx.x, lane = tid & 63, w = tid >> 6;
  int wm = w >> 1, wn = w & 1;
  int g = lane >> 4, c = lane & 15;
  int srow = lane >> 3, sslot = lane & 7;
  int sgc = (sslot ^ srow) * 8;

  const unsigned short* aG = A  + (size_t)(m0 + w * (BM / 4) + srow) * K + sgc;
  const unsigned short* bG = Bt + (size_t)(n0 + w * (BN / 4) + srow) * K + sgc;
  int aOff = (w * (BM / 4) + srow) * 64 + sslot * 8;
  int bOff = (w * (BN / 4) + srow) * 64 + sslot * 8;

  f32x4 acc[MF][NF] = {};
  int KT = K >> 6;
  int rk = c & 7;

  #pragma unroll
  for (int t = 0; t < ALOADS; ++t)
    gload16(aG + (size_t)(t * 8) * K, &Al[0][aOff + t * 8 * 64]);
  #pragma unroll
  for (int t = 0; t < BLOADS; ++t)
    gload16(bG + (size_t)(t * 8) * K, &Bl[0][bOff + t * 8 * 64]);

  for (int kt = 0; kt < KT; ++kt) {
    int cur = kt & 1;
    if (kt + 1 < KT) {
      int nb = cur ^ 1;
      const unsigned short* aGk = aG + (kt + 1) * 64;
      const unsigned short* bGk = bG + (kt + 1) * 64;
      #pragma unroll
      for (int t = 0; t < ALOADS; ++t)
        gload16(aGk + (size_t)(t * 8) * K, &Al[nb][aOff + t * 8 * 64]);
      #pragma unroll
      for (int t = 0; t < BLOADS; ++t)
        gload16(bGk + (size_t)(t * 8) * K, &Bl[nb][bOff + t * 8 * 64]);
      waitcnt_vm<NL>();
    } else {
      waitcnt_vm<0>();
    }
    __builtin_amdgcn_s_barrier();
    __builtin_amdgcn_sched_barrier(0);
    #pragma unroll
    for (int ks = 0; ks < 2; ++ks) {
      int slot = (ks * 4 + g) ^ rk;
      bf16x8 af[MF], bfr[NF];
      #pragma unroll
      for (int i = 0; i < MF; ++i)
        af[i] = ldb8(&Al[cur][(wm * (MF * 16) + i * 16 + c) * 64 + slot * 8]);
      #pragma unroll
      for (int j = 0; j < NF; ++j)
        bfr[j] = ldb8(&Bl[cur][(wn * (NF * 16) + j * 16 + c) * 64 + slot * 8]);
      #pragma unroll
      for (int i = 0; i < MF; ++i)
        #pragma unroll
        for (int j = 0; j < NF; ++j)
          acc[i][j] = mfma16(af[i], bfr[j], acc[i][j]);
    }
    __builtin_amdgcn_sched_barrier(0);
    __builtin_amdgcn_s_barrier();
  }

  if (EPI == EPI_QKV) {
    int sel  = n0 >> 9;
    if (sel < 2) {
      #pragma unroll
      for (int i = 0; i < MF; ++i) {
        int mrow = m0 + wm * (MF * 16) + i * 16 + g * 4;
        #pragma unroll
        for (int j = 0; j < NF; ++j) {
          int nloc = (n0 & 511) + wn * (NF * 16) + j * 16 + c;
          const float* bp = sel == 0 ? bias0 : bias1;
          unsigned short* o = (unsigned short*)(sel == 0 ? out0 : out1);
          float sc = (sel == 0) ? QSCALE : 1.0f;
          float bn = bp[nloc];
          #pragma unroll
          for (int ii = 0; ii < 4; ++ii)
            o[(size_t)(mrow + ii) * D_MODEL + nloc] = f2bf((acc[i][j][ii] + bn) * sc);
        }
      }
    } else {
      unsigned short* T = &Al[0][0];            // 64 x 136
      #pragma unroll
      for (int i = 0; i < MF; ++i) {
        int ml0 = wm * (MF * 16) + i * 16 + g * 4;
        #pragma unroll
        for (int j = 0; j < NF; ++j) {
          int nl = wn * (NF * 16) + j * 16 + c;
          float bn = bias2[(n0 & 511) + nl];
          u16x4 pk;
          #pragma unroll
          for (int ii = 0; ii < 4; ++ii) pk[ii] = f2bf(acc[i][j][ii] + bn);
          *(u16x4*)&T[nl * 136 + ml0] = pk;
        }
      }
      __syncthreads();
      int b  = m0 >> 11, s0 = m0 & 2047;
      int hh = (n0 & 511) >> 6;
      int r  = tid >> 2, c0 = (tid & 3) * 32;
      unsigned short* dst = (unsigned short*)out2 +
          ((size_t)(b * NHEAD + hh) * HD + r) * SEQ + s0 + c0;
      #pragma unroll
      for (int u = 0; u < 4; ++u)
        *(u16x8*)(dst + u * 8) = *(u16x8*)&T[r * 136 + c0 + u * 8];
    }
  } else {  // EPI_PLAIN
    #pragma unroll
    for (int i = 0; i < MF; ++i) {
      int mrow = m0 + wm * (MF * 16) + i * 16 + g * 4;
      #pragma unroll
      for (int j = 0; j < NF; ++j) {
        int n = n0 + wn * (NF * 16) + j * 16 + c;
        float bn = bias0[n];
        unsigned short* o = (unsigned short*)out0;
        #pragma unroll
        for (int ii = 0; ii < 4; ++ii)
          o[(size_t)(mrow + ii) * N + n] = f2bf(acc[i][j][ii] + bn);
      }
    }
  }
}

// ---------------- GEMM v12s: split-K (S=2) plain GEMM for w2 --------------
// grid (512, 2): x = (mt,nt) swizzled, y = K-half. Each half writes its own
// bf16 partial buffer (no RMW); bias folded into half 0. addrms2 combines.
template<int BM, int BN>
__global__ __launch_bounds__(256) void gemm12s_k(
    const unsigned short* __restrict__ A,     // [M][KFULL]
    const unsigned short* __restrict__ Bt,    // [N][KFULL]
    const float* __restrict__ bias0,
    unsigned short* __restrict__ out,         // [2][M][N]
    int M, int N, int KFULL, int KLEN)
{
  constexpr int MF = BM / 32;
  constexpr int NF = BN / 32;
  constexpr int ALOADS = BM / 32;
  constexpr int BLOADS = BN / 32;
  constexpr int NL = ALOADS + BLOADS;

  __shared__ __attribute__((aligned(16))) unsigned short Al[2][BM * 64];
  __shared__ __attribute__((aligned(16))) unsigned short Bl[2][BN * 64];

  int kh = blockIdx.y;
  int nblk = gridDim.x;
  int orig = blockIdx.x;
  int qq = nblk >> 3, rr = nblk & 7, xcd = orig & 7, pos = orig >> 3;
  int lid = (xcd < rr ? xcd * (qq + 1) : rr * (qq + 1) + (xcd - rr) * qq) + pos;
  int numN = N / BN;
  int mt = lid / numN, nt = lid % numN;
  int m0 = mt * BM, n0 = nt * BN;

  int tid = threadIdx.x, lane = tid & 63, w = tid >> 6;
  int wm = w >> 1, wn = w & 1;
  int g = lane >> 4, c = lane & 15;
  int srow = lane >> 3, sslot = lane & 7;
  int sgc = (sslot ^ srow) * 8;

  const unsigned short* aG = A  + (size_t)(m0 + w * (BM / 4) + srow) * KFULL + kh * KLEN + sgc;
  const unsigned short* bG = Bt + (size_t)(n0 + w * (BN / 4) + srow) * KFULL + kh * KLEN + sgc;
  int aOff = (w * (BM / 4) + srow) * 64 + sslot * 8;
  int bOff = (w * (BN / 4) + srow) * 64 + sslot * 8;

  f32x4 acc[MF][NF] = {};
  int KT = KLEN >> 6;
  int rk = c & 7;

  #pragma unroll
  for (int t = 0; t < ALOADS; ++t)
    gload16(aG + (size_t)(t * 8) * KFULL, &Al[0][aOff + t * 8 * 64]);
  #pragma unroll
  for (int t = 0; t < BLOADS; ++t)
    gload16(bG + (size_t)(t * 8) * KFULL, &Bl[0][bOff + t * 8 * 64]);

  for (int kt = 0; kt < KT; ++kt) {
    int cur = kt & 1;
    if (kt + 1 < KT) {
      int nb = cur ^ 1;
      const unsigned short* aGk = aG + (kt + 1) * 64;
      const unsigned short* bGk = bG + (kt + 1) * 64;
      #pragma unroll
      for (int t = 0; t < ALOADS; ++t)
        gload16(aGk + (size_t)(t * 8) * KFULL, &Al[nb][aOff + t * 8 * 64]);
      #pragma unroll
      for (int t = 0; t < BLOADS; ++t)
        gload16(bGk + (size_t)(t * 8) * KFULL, &Bl[nb][bOff + t * 8 * 64]);
      waitcnt_vm<NL>();
    } else {
      waitcnt_vm<0>();
    }
    __builtin_amdgcn_s_barrier();
    __builtin_amdgcn_sched_barrier(0);
    #pragma unroll
    for (int ks = 0; ks < 2; ++ks) {
      int slot = (ks * 4 + g) ^ rk;
      bf16x8 af[MF], bfr[NF];
      #pragma unroll
      for (int i = 0; i < MF; ++i)
        af[i] = ldb8(&Al[cur][(wm * (MF * 16) + i * 16 + c) * 64 + slot * 8]);
      #pragma unroll
      for (int j = 0; j < NF; ++j)
        bfr[j] = ldb8(&Bl[cur][(wn * (NF * 16) + j * 16 + c) * 64 + slot * 8]);
      #pragma unroll
      for (int i = 0; i < MF; ++i)
        #pragma unroll
        for (int j = 0; j < NF; ++j)
          acc[i][j] = mfma16(af[i], bfr[j], acc[i][j]);
    }
    __builtin_amdgcn_sched_barrier(0);
    __builtin_amdgcn_s_barrier();
  }

  unsigned short* o = out + (size_t)kh * M * N;
  #pragma unroll
  for (int i = 0; i < MF; ++i) {
    int mrow = m0 + wm * (MF * 16) + i * 16 + g * 4;
    #pragma unroll
    for (int j = 0; j < NF; ++j) {
      int n = n0 + wn * (NF * 16) + j * 16 + c;
      float bn = (kh == 0) ? bias0[n] : 0.0f;
      #pragma unroll
      for (int ii = 0; ii < 4; ++ii)
        o[(size_t)(mrow + ii) * N + n] = f2bf(acc[i][j][ii] + bn);
    }
  }
}

// ---------------- GEMM v11d: fused dual-B gated FFN-up (single buffer,
// m-major XCD chunking -> hbuf output is XCD-local for the w2 consumer) ----
template<int BM, int BN>
__global__ __launch_bounds__(256) void gemm11d_k(
    const unsigned short* __restrict__ A,
    const unsigned short* __restrict__ B0t,   // [N][K]
    const unsigned short* __restrict__ B1t,   // [N][K]
    const float* __restrict__ bias0,
    const float* __restrict__ bias1,
    unsigned short* __restrict__ out,
    int M, int N, int K)
{
  constexpr int MF = BM / 32;
  constexpr int NF = BN / 32;
  constexpr int ALOADS = BM / 32;
  constexpr int BLOADS = BN / 32;

  __shared__ __attribute__((aligned(16))) unsigned short Al[BM * 64];
  __shared__ __attribute__((aligned(16))) unsigned short B0l[BN * 64];
  __shared__ __attribute__((aligned(16))) unsigned short B1l[BN * 64];

  int nblk = gridDim.x;
  int orig = blockIdx.x;
  int qq = nblk >> 3, rr = nblk & 7, xcd = orig & 7, pos = orig >> 3;
  int lid = (xcd < rr ? xcd * (qq + 1) : rr * (qq + 1) + (xcd - rr) * qq) + pos;
  int numN = N / BN;
  int mt = lid / numN, nt = lid % numN;   // m-major: XCD chunk = contiguous m slab
  int m0 = mt * BM, n0 = nt * BN;

  int tid = threadIdx.x, lane = tid & 63, w = tid >> 6;
  int wm = w >> 1, wn = w & 1;
  int g = lane >> 4, c = lane & 15;
  int srow = lane >> 3, sslot = lane & 7;
  int sgc = (sslot ^ srow) * 8;

  const unsigned short* aG  = A   + (size_t)(m0 + w * (BM / 4) + srow) * K + sgc;
  const unsigned short* b0G = B0t + (size_t)(n0 + w * (BN / 4) + srow) * K + sgc;
  const unsigned short* b1G = B1t + (size_t)(n0 + w * (BN / 4) + srow) * K + sgc;
  unsigned short* aL  = &Al [(w * (BM / 4) + srow) * 64 + sslot * 8];
  unsigned short* b0L = &B0l[(w * (BN / 4) + srow) * 64 + sslot * 8];
  unsigned short* b1L = &B1l[(w * (BN / 4) + srow) * 64 + sslot * 8];

  f32x4 acc0[MF][NF] = {};
  f32x4 acc1[MF][NF] = {};
  int KT = K >> 6;
  int rk = c & 7;

  for (int kt = 0; kt < KT; ++kt) {
    if (kt) __syncthreads();
    #pragma unroll
    for (int t = 0; t < ALOADS; ++t)
      gload16(aG + (size_t)(t * 8) * K + kt * 64, aL + t * 8 * 64);
    #pragma unroll
    for (int t = 0; t < BLOADS; ++t) {
      gload16(b0G + (size_t)(t * 8) * K + kt * 64, b0L + t * 8 * 64);
      gload16(b1G + (size_t)(t * 8) * K + kt * 64, b1L + t * 8 * 64);
    }
    __syncthreads();
    #pragma unroll
    for (int ks = 0; ks < 2; ++ks) {
      int slot = (ks * 4 + g) ^ rk;
      bf16x8 af[MF], b0f[NF], b1f[NF];
      #pragma unroll
      for (int i = 0; i < MF; ++i)
        af[i] = ldb8(&Al[(wm * (MF * 16) + i * 16 + c) * 64 + slot * 8]);
      #pragma unroll
      for (int j = 0; j < NF; ++j) {
        b0f[j] = ldb8(&B0l[(wn * (NF * 16) + j * 16 + c) * 64 + slot * 8]);
        b1f[j] = ldb8(&B1l[(wn * (NF * 16) + j * 16 + c) * 64 + slot * 8]);
      }
      #pragma unroll
      for (int i = 0; i < MF; ++i)
        #pragma unroll
        for (int j = 0; j < NF; ++j) {
          acc0[i][j] = mfma16(af[i], b0f[j], acc0[i][j]);
          acc1[i][j] = mfma16(af[i], b1f[j], acc1[i][j]);
        }
    }
  }

  #pragma unroll
  for (int i = 0; i < MF; ++i) {
    int mrow = m0 + wm * (MF * 16) + i * 16 + g * 4;
    #pragma unroll
    for (int j = 0; j < NF; ++j) {
      int n = n0 + wn * (NF * 16) + j * 16 + c;
      float b0n = bias0[n], b1n = bias1[n];
      #pragma unroll
      for (int ii = 0; ii < 4; ++ii) {
        float a  = acc0[i][j][ii] + b0n;
        float gv = acc1[i][j][ii] + b1n;
        float s  = gv / (1.0f + __expf(-gv));
        out[(size_t)(mrow + ii) * N + n] = f2bf(a * s);
      }
    }
  }
}

// ---------------- attention v5: split-K flash, no-max softmax ------------
struct Stg { uint4v k0, k1, v0, v1; };

static __device__ __forceinline__ Stg stage_load(const unsigned short* Kp,
                                                 const unsigned short* Vp,
                                                 int kbase, int srow, int sslot) {
  Stg s;
  const unsigned short* kr = Kp + (size_t)(kbase + srow) * D_MODEL + sslot * 8;
  s.k0 = *(const uint4v*)kr;
  s.k1 = *(const uint4v*)(kr + 32);
  const unsigned short* vr = Vp + (size_t)srow * SEQ + kbase + sslot * 8;
  s.v0 = *(const uint4v*)vr;
  s.v1 = *(const uint4v*)(vr + 32);
  return s;
}
static __device__ __forceinline__ void stage_write(unsigned short* Klb, unsigned short* Vlb,
                                                   const Stg& s, int srow, int sslot) {
  char* kb = (char*)Klb;
  *(uint4v*)(kb + SWZ(srow, srow * 128 + sslot * 16))       = s.k0;
  *(uint4v*)(kb + SWZ(srow, srow * 128 + (sslot + 4) * 16)) = s.k1;
  char* vb = (char*)Vlb;
  *(uint4v*)(vb + SWZ(srow, srow * 128 + sslot * 16))       = s.v0;
  *(uint4v*)(vb + SWZ(srow, srow * 128 + (sslot + 4) * 16)) = s.v1;
}

template<bool MASKED>
static __device__ __forceinline__ void attn_tile(
    const unsigned short* Klb, const unsigned short* Vlb,
    bf16x8 qf0, bf16x8 qf1, f32x4* oacc, float& ps,
    int g, int c, int kbase, int qrow)
{
  f32x4 z[4];
  #pragma unroll
  for (int hh = 0; hh < 4; ++hh) {
    int r = hh * 16 + c;
    const char* base = (const char*)Klb;
    bf16x8 k0 = ldb8((const unsigned short*)(base + SWZ(r, r * 128 + g * 16)));
    bf16x8 k1 = ldb8((const unsigned short*)(base + SWZ(r, r * 128 + 64 + g * 16)));
    f32x4 t = {};
    t = mfma16(k0, qf0, t);
    t = mfma16(k1, qf1, t);
    z[hh] = t;
  }
  u16x8 pa0, pa1;
  #pragma unroll
  for (int hh = 0; hh < 4; ++hh) {
    #pragma unroll
    for (int i = 0; i < 4; ++i) {
      float p = exp2f(z[hh][i]);
      if (MASKED && (kbase + hh * 16 + g * 4 + i > qrow)) p = 0.0f;
      ps += p;
      unsigned short pb = f2bf(p);
      if (hh < 2) pa0[hh * 4 + i] = pb;
      else        pa1[(hh - 2) * 4 + i] = pb;
    }
  }
  bf16x8 af0 = __builtin_bit_cast(bf16x8, pa0);
  bf16x8 af1 = __builtin_bit_cast(bf16x8, pa1);
  #pragma unroll
  for (int db = 0; db < 4; ++db) {
    int r = db * 16 + c;
    const char* base = (const char*)Vlb;
    u16x4 v00 = *(const u16x4*)(base + SWZ(r, r * 128 + g * 8));
    u16x4 v01 = *(const u16x4*)(base + SWZ(r, r * 128 + 32 + g * 8));
    u16x4 v10 = *(const u16x4*)(base + SWZ(r, r * 128 + 64 + g * 8));
    u16x4 v11 = *(const u16x4*)(base + SWZ(r, r * 128 + 96 + g * 8));
    u16x8 vb0, vb1;
    #pragma unroll
    for (int j = 0; j < 4; ++j) {
      vb0[j] = v00[j]; vb0[4 + j] = v01[j];
      vb1[j] = v10[j]; vb1[4 + j] = v11[j];
    }
    oacc[db] = mfma16(af0, __builtin_bit_cast(bf16x8, vb0), oacc[db]);
    oacc[db] = mfma16(af1, __builtin_bit_cast(bf16x8, vb1), oacc[db]);
  }
}

static __device__ __forceinline__ int slot_base(int c) {
  if (c < 16) return (c - 8) * 2;
  if (c < 24) return 16 + (c - 16) * 3;
  return 40 + (c - 24) * 4;
}

__global__ __launch_bounds__(256) void attn5_k(const unsigned short* __restrict__ Q,
                                               const unsigned short* __restrict__ K,
                                               const unsigned short* __restrict__ VT,
                                               unsigned short* __restrict__ O,
                                               float* __restrict__ Oparts,
                                               float* __restrict__ Sparts)
{
  __shared__ __attribute__((aligned(16))) unsigned short Kl[2][64 * 64];
  __shared__ __attribute__((aligned(16))) unsigned short Vl[2][64 * 64];
  int tid = threadIdx.x, lane = tid & 63, w = tid >> 6;
  int g = lane >> 4, cl = lane & 15;

  int z = 79 - (int)blockIdx.x;
  int c, sp;
  if (z < 8)        { c = z;                    sp = 0; }
  else if (z < 24)  { int t2 = z - 8;  c = 8  + (t2 >> 1); sp = t2 & 1; }
  else if (z < 48)  { int t2 = z - 24; c = 16 + t2 / 3;    sp = t2 % 3; }
  else              { int t2 = z - 48; c = 24 + (t2 >> 2); sp = t2 & 3; }
  int kt0 = sp * 8;
  int kt1 = min(c + 1, kt0 + 8);
  bool lastsplit = (kt1 == c + 1);

  int bh = blockIdx.y, b = bh >> 3, h = bh & 7;
  int q0 = c * 64;
  const unsigned short* Qp = Q + (size_t)(b * SEQ) * D_MODEL + h * HD;
  const unsigned short* Kp = K + (size_t)(b * SEQ) * D_MODEL + h * HD;
  const unsigned short* Vp = VT + (size_t)bh * HD * SEQ;

  int qrow = q0 + w * 16 + cl;
  bf16x8 qf0 = ldb8(Qp + (size_t)qrow * D_MODEL + g * 8);
  bf16x8 qf1 = ldb8(Qp + (size_t)qrow * D_MODEL + 32 + g * 8);

  f32x4 oacc[4] = {};
  float ps = 0.0f;
  int srow = tid >> 2, sslot = tid & 3;

  Stg s0 = stage_load(Kp, Vp, kt0 * 64, srow, sslot);
  stage_write(&Kl[0][0], &Vl[0][0], s0, srow, sslot);
  __syncthreads();

  int buf = 0;
  for (int kt = kt0; kt < kt1 - 1; ++kt) {
    Stg sn = stage_load(Kp, Vp, (kt + 1) * 64, srow, sslot);
    attn_tile<false>(&Kl[buf][0], &Vl[buf][0], qf0, qf1, oacc, ps, g, cl, 0, 0);
    stage_write(&Kl[buf ^ 1][0], &Vl[buf ^ 1][0], sn, srow, sslot);
    __syncthreads();
    buf ^= 1;
  }
  if (lastsplit)
    attn_tile<true>(&Kl[buf][0], &Vl[buf][0], qf0, qf1, oacc, ps, g, cl,
                    (kt1 - 1) * 64, qrow);
  else
    attn_tile<false>(&Kl[buf][0], &Vl[buf][0], qf0, qf1, oacc, ps, g, cl, 0, 0);

  ps += __shfl_xor(ps, 16, 64);
  ps += __shfl_xor(ps, 32, 64);

  if (c < 8) {
    f32x4 inv;
    #pragma unroll
    for (int i = 0; i < 4; ++i) inv[i] = 1.0f / __shfl(ps, g * 4 + i, 64);
    #pragma unroll
    for (int db = 0; db < 4; ++db)
      #pragma unroll
      for (int i = 0; i < 4; ++i)
        O[(size_t)(b * SEQ + q0 + w * 16 + g * 4 + i) * D_MODEL + h * HD + db * 16 + cl] =
            f2bf(oacc[db][i] * inv[i]);
  } else {
    size_t slot = (size_t)bh * 72 + slot_base(c) + sp;
    float* Op = Oparts + slot * 4096;
    float* Sp = Sparts + slot * 64;
    #pragma unroll
    for (int db = 0; db < 4; ++db)
      #pragma unroll
      for (int i = 0; i < 4; ++i)
        Op[(w * 16 + g * 4 + i) * 64 + db * 16 + cl] = oacc[db][i];
    if (g == 0) Sp[w * 16 + cl] = ps;
  }
}

__global__ __launch_bounds__(256) void attn_comb_k(const float* __restrict__ Oparts,
                                                   const float* __restrict__ Sparts,
                                                   unsigned short* __restrict__ O) {
  int t  = threadIdx.x;
  int c  = 8 + (int)(blockIdx.x % 24);
  int bh = (int)(blockIdx.x / 24);
  int b = bh >> 3, h = bh & 7;
  int ns = (c + 8) >> 3;
  size_t slot = (size_t)bh * 72 + slot_base(c);
  const float* O0 = Oparts + slot * 4096;
  const float* S0 = Sparts + slot * 64;
  int r = t >> 2, d0 = (t & 3) * 16;
  f32x4 a0 = {}, a1 = {}, a2 = {}, a3 = {};
  float s = 0.0f;
  for (int si = 0; si < ns; ++si) {
    const float* o = O0 + si * 4096 + r * 64 + d0;
    a0 += *(const f32x4*)(o);
    a1 += *(const f32x4*)(o + 4);
    a2 += *(const f32x4*)(o + 8);
    a3 += *(const f32x4*)(o + 12);
    s  += S0[si * 64 + r];
  }
  float inv = 1.0f / s;
  u16x8 w0, w1;
  #pragma unroll
  for (int j = 0; j < 4; ++j) {
    w0[j]     = f2bf(a0[j] * inv); w0[4 + j] = f2bf(a1[j] * inv);
    w1[j]     = f2bf(a2[j] * inv); w1[4 + j] = f2bf(a3[j] * inv);
  }
  unsigned short* dst = O + (size_t)(b * SEQ + c * 64 + r) * D_MODEL + h * HD + d0;
  *(u16x8*)(dst)     = w0;
  *(u16x8*)(dst + 8) = w1;
}

// ---------------- launch ----------------
extern "C" void kernel_launch(void* const* d_in, const int* in_sizes, int n_in,
                              void* d_out, int out_size, void* d_ws, size_t ws_size,
                              hipStream_t stream) {
  (void)in_sizes; (void)n_in; (void)out_size; (void)ws_size;
  const float* x   = (const float*)d_in[0];
  const float* qw  = (const float*)d_in[1];
  const float* qb  = (const float*)d_in[2];
  const float* kw  = (const float*)d_in[3];
  const float* kbi = (const float*)d_in[4];
  const float* vw  = (const float*)d_in[5];
  const float* vb  = (const float*)d_in[6];
  const float* ow  = (const float*)d_in[7];
  const float* ob  = (const float*)d_in[8];
  const float* w0  = (const float*)d_in[9];
  const float* b0  = (const float*)d_in[10];
  const float* w1  = (const float*)d_in[11];
  const float* b1  = (const float*)d_in[12];
  const float* w2  = (const float*)d_in[13];
  const float* b2  = (const float*)d_in[14];
  const float* anw = (const float*)d_in[15];
  const float* fnw = (const float*)d_in[16];

  char* ws = (char*)d_ws;
  float*          h    = (float*)ws;                              // 0-8MB fp32 residual
  unsigned short* xn   = (unsigned short*)(ws + (8u  << 20));     // 8-12
  unsigned short* q    = (unsigned short*)(ws + (12u << 20));     // 12-16
  unsigned short* k    = (unsigned short*)(ws + (16u << 20));     // 16-20
  unsigned short* vt   = (unsigned short*)(ws + (24u << 20));     // 24-28
  unsigned short* ao   = (unsigned short*)(ws + (28u << 20));     // 28-32
  unsigned short* y0   = (unsigned short*)(ws + (32u << 20));     // 32-36
  unsigned short* hbuf = (unsigned short*)(ws + (12u << 20));     // 12-28 (aliases q,k,vt)
  unsigned short* Wq   = (unsigned short*)(ws + (36u << 20));     // 36-42
  unsigned short* Wo   = (unsigned short*)(ws + (42u << 20));     // 42-44
  unsigned short* W01  = (unsigned short*)(ws + (44u << 20));     // 44-60
  unsigned short* W2   = (unsigned short*)(ws + (60u << 20));     // 60-68
  float*          Opar = (float*)(ws + (68u << 20));              // 68-86 (18MB)
  float*          Spar = (float*)(ws + (86u << 20));              // 86-86.3
  unsigned short* ysp  = (unsigned short*)(ws + (88u << 20));     // 88-96 (split-K partials, 2x4MB)

  prep_t<<<4096, 64, 0, stream>>>(qw, kw, vw, ow, w0, w1, w2, Wq, Wo, W01, W2);
  initrms_k<<<BTOK / 4, 256, 0, stream>>>(x, anw, h, xn);

  for (int l = 0; l < 4; ++l) {
    size_t bo  = (size_t)l * D_MODEL;
    size_t bho = (size_t)l * HIDE;

    gemm7_k<EPI_QKV, 128, 64><<<768, 256, 0, stream>>>(
        xn, Wq + (size_t)l * 786432, qb + bo, kbi + bo, vb + bo,
        q, k, vt, BTOK, 3 * D_MODEL, D_MODEL);
    attn5_k<<<dim3(80, 16), 256, 0, stream>>>(q, k, vt, ao, Opar, Spar);
    attn_comb_k<<<384, 256, 0, stream>>>(Opar, Spar, ao);
    gemm7_k<EPI_PLAIN, 64, 64><<<512, 256, 0, stream>>>(
        ao, Wo + (size_t)l * 262144, ob + bo, nullptr, nullptr,
        y0, nullptr, nullptr, BTOK, D_MODEL, D_MODEL);
    addrms_k<<<BTOK / 4, 256, 0, stream>>>(h, y0, fnw + bo, xn);

    gemm11d_k<128, 64><<<1024, 256, 0, stream>>>(
        xn, W01 + (size_t)l * 2097152, W01 + (size_t)l * 2097152 + 1048576,
        b0 + bho, b1 + bho, hbuf, BTOK, HIDE, D_MODEL);
    gemm12s_k<64, 64><<<dim3(512, 2), 256, 0, stream>>>(
        hbuf, W2 + (size_t)l * 1048576, b2 + bo, ysp,
        BTOK, D_MODEL, HIDE, HIDE / 2);
    if (l < 3)
      addrms2_k<<<BTOK / 4, 256, 0, stream>>>(
          h, ysp, ysp + (size_t)BTOK * D_MODEL, anw + bo + D_MODEL, xn);
    else
      addout2_k<<<BTOK / 4, 256, 0, stream>>>(
          h, ysp, ysp + (size_t)BTOK * D_MODEL, (float*)d_out);
  }
}

// Round 19
// 429.502 us; speedup vs baseline: 1.1255x; 1.0034x over previous
//
#include <hip/hip_runtime.h>
#include <math.h>

// ---------------- types ----------------
typedef unsigned int   uint4v __attribute__((ext_vector_type(4)));
typedef float          f32x4  __attribute__((ext_vector_type(4)));
typedef __bf16         bf16x8 __attribute__((ext_vector_type(8)));
typedef unsigned short u16x8  __attribute__((ext_vector_type(8)));
typedef unsigned short u16x4  __attribute__((ext_vector_type(4)));

#define D_MODEL 512
#define SEQ     2048
#define BTOK    4096   // B * SEQ
#define HIDE    2048
#define NHEAD   8
#define HD      64

static __device__ __forceinline__ unsigned short f2bf(float f) {
  __bf16 b = (__bf16)f;
  return __builtin_bit_cast(unsigned short, b);
}
static __device__ __forceinline__ float bf2f(unsigned short b) {
  union { unsigned u; float f; } v; v.u = ((unsigned)b) << 16;
  return v.f;
}
static __device__ __forceinline__ bf16x8 ldb8(const unsigned short* p) {
  return __builtin_bit_cast(bf16x8, *(const uint4v*)p);
}
static __device__ __forceinline__ f32x4 mfma16(bf16x8 a, bf16x8 b, f32x4 c) {
  return __builtin_amdgcn_mfma_f32_16x16x32_bf16(a, b, c, 0, 0, 0);
}

typedef unsigned int u32_g __attribute__((address_space(1)));
typedef unsigned int u32_l __attribute__((address_space(3)));
static __device__ __forceinline__ void gload16(const unsigned short* g, unsigned short* l) {
  __builtin_amdgcn_global_load_lds((const u32_g*)(const void*)g,
                                   (u32_l*)(void*)l, 16, 0, 0);
}

#define SWZ(r, off) ((off) ^ (((r) & 7) << 4))
#define QSCALE 0.180336880f   // 0.125 * log2(e)

template<int N>
static __device__ __forceinline__ void waitcnt_vm() {
  asm volatile("s_waitcnt vmcnt(%0)" :: "i"(N) : "memory");
}

// ---------------- weight prep: LDS-tiled transpose f32 [K][N] -> bf16 [N][K] ----
__global__ __launch_bounds__(64) void prep_t(
    const float* __restrict__ qw, const float* __restrict__ kw,
    const float* __restrict__ vw, const float* __restrict__ ow,
    const float* __restrict__ w0, const float* __restrict__ w1,
    const float* __restrict__ w2,
    unsigned short* __restrict__ Wq, unsigned short* __restrict__ Wo,
    unsigned short* __restrict__ W01, unsigned short* __restrict__ W2)
{
  int bid = blockIdx.x;
  int l = bid >> 10;
  int r = bid & 1023;
  const float* src; unsigned short* dst;
  int tr, tc, srcN, dstK;
  if (r < 192) {
    int sel = r >> 6, tt = r & 63;
    tr = tt >> 3; tc = tt & 7;
    src = (sel == 0 ? qw : sel == 1 ? kw : vw) + (size_t)l * 262144;
    srcN = 512; dstK = 512;
    dst = Wq + (size_t)l * 786432 + (size_t)(sel * 512 + tc * 64) * 512 + tr * 64;
  } else if (r < 256) {
    int tt = r - 192; tr = tt >> 3; tc = tt & 7;
    src = ow + (size_t)l * 262144; srcN = 512; dstK = 512;
    dst = Wo + (size_t)l * 262144 + (size_t)(tc * 64) * 512 + tr * 64;
  } else if (r < 768) {
    int idx = r - 256; int sel = idx >> 8; int tt = idx & 255;
    tr = tt >> 5; tc = tt & 31;
    src = (sel ? w1 : w0) + (size_t)l * 1048576; srcN = 2048; dstK = 512;
    dst = W01 + (size_t)l * 2097152 + (size_t)sel * 1048576 + (size_t)(tc * 64) * 512 + tr * 64;
  } else {
    int tt = r - 768; tr = tt >> 3; tc = tt & 7;
    src = w2 + (size_t)l * 1048576; srcN = 512; dstK = 2048;
    dst = W2 + (size_t)l * 1048576 + (size_t)(tc * 64) * 2048 + tr * 64;
  }
  src += (size_t)(tr * 64) * srcN + tc * 64;
  __shared__ unsigned short T[64][68];
  int t = threadIdx.x;
  #pragma unroll
  for (int it = 0; it < 16; ++it) {
    int row = it * 4 + (t >> 4);
    int col = (t & 15) * 4;
    f32x4 v4 = *(const f32x4*)(src + (size_t)row * srcN + col);
    u16x4 o; o[0] = f2bf(v4.x); o[1] = f2bf(v4.y); o[2] = f2bf(v4.z); o[3] = f2bf(v4.w);
    *(u16x4*)&T[row][col] = o;
  }
  __syncthreads();
  unsigned short* orow = dst + (size_t)t * dstK;
  #pragma unroll
  for (int j0 = 0; j0 < 8; ++j0) {
    u16x8 o;
    #pragma unroll
    for (int j = 0; j < 8; ++j) o[j] = T[j0 * 8 + j][t];
    *(u16x8*)(orow + j0 * 8) = o;
  }
}

// ---------------- initrms: h = x; xn = rms(x)*w ----------------
__global__ __launch_bounds__(256) void initrms_k(const float* __restrict__ x,
                                                 const float* __restrict__ w,
                                                 float* __restrict__ h,
                                                 unsigned short* __restrict__ xn) {
  int row  = blockIdx.x * 4 + (threadIdx.x >> 6);
  int lane = threadIdx.x & 63;
  const float* xr = x + (size_t)row * D_MODEL + lane * 8;
  f32x4 v0 = *(const f32x4*)(xr);
  f32x4 v1 = *(const f32x4*)(xr + 4);
  *(f32x4*)(h + (size_t)row * D_MODEL + lane * 8)     = v0;
  *(f32x4*)(h + (size_t)row * D_MODEL + lane * 8 + 4) = v1;
  float ss = v0.x*v0.x + v0.y*v0.y + v0.z*v0.z + v0.w*v0.w
           + v1.x*v1.x + v1.y*v1.y + v1.z*v1.z + v1.w*v1.w;
  #pragma unroll
  for (int m = 1; m < 64; m <<= 1) ss += __shfl_xor(ss, m, 64);
  float inv = 1.0f / (sqrtf(ss * (1.0f / D_MODEL)) + 1e-6f);
  f32x4 w0 = *(const f32x4*)(w + lane * 8);
  f32x4 w1 = *(const f32x4*)(w + lane * 8 + 4);
  u16x8 o;
  o[0] = f2bf(v0.x * w0.x * inv); o[1] = f2bf(v0.y * w0.y * inv);
  o[2] = f2bf(v0.z * w0.z * inv); o[3] = f2bf(v0.w * w0.w * inv);
  o[4] = f2bf(v1.x * w1.x * inv); o[5] = f2bf(v1.y * w1.y * inv);
  o[6] = f2bf(v1.z * w1.z * inv); o[7] = f2bf(v1.w * w1.w * inv);
  *(u16x8*)(xn + (size_t)row * D_MODEL + lane * 8) = o;
}

// ---------------- addrms2: h += y0+y1 (split-K partials); xn = rms(h)*w ----
__global__ __launch_bounds__(256) void addrms2_k(float* __restrict__ h,
                                                 const unsigned short* __restrict__ y0,
                                                 const unsigned short* __restrict__ y1,
                                                 const float* __restrict__ w,
                                                 unsigned short* __restrict__ xn) {
  int row  = blockIdx.x * 4 + (threadIdx.x >> 6);
  int lane = threadIdx.x & 63;
  float* hr = h + (size_t)row * D_MODEL + lane * 8;
  f32x4 v0 = *(const f32x4*)(hr);
  f32x4 v1 = *(const f32x4*)(hr + 4);
  u16x8 a = *(const u16x8*)(y0 + (size_t)row * D_MODEL + lane * 8);
  u16x8 b = *(const u16x8*)(y1 + (size_t)row * D_MODEL + lane * 8);
  v0.x += bf2f(a[0]) + bf2f(b[0]); v0.y += bf2f(a[1]) + bf2f(b[1]);
  v0.z += bf2f(a[2]) + bf2f(b[2]); v0.w += bf2f(a[3]) + bf2f(b[3]);
  v1.x += bf2f(a[4]) + bf2f(b[4]); v1.y += bf2f(a[5]) + bf2f(b[5]);
  v1.z += bf2f(a[6]) + bf2f(b[6]); v1.w += bf2f(a[7]) + bf2f(b[7]);
  *(f32x4*)(hr)     = v0;
  *(f32x4*)(hr + 4) = v1;
  float ss = v0.x*v0.x + v0.y*v0.y + v0.z*v0.z + v0.w*v0.w
           + v1.x*v1.x + v1.y*v1.y + v1.z*v1.z + v1.w*v1.w;
  #pragma unroll
  for (int m = 1; m < 64; m <<= 1) ss += __shfl_xor(ss, m, 64);
  float inv = 1.0f / (sqrtf(ss * (1.0f / D_MODEL)) + 1e-6f);
  f32x4 w0 = *(const f32x4*)(w + lane * 8);
  f32x4 w1 = *(const f32x4*)(w + lane * 8 + 4);
  u16x8 o;
  o[0] = f2bf(v0.x * w0.x * inv); o[1] = f2bf(v0.y * w0.y * inv);
  o[2] = f2bf(v0.z * w0.z * inv); o[3] = f2bf(v0.w * w0.w * inv);
  o[4] = f2bf(v1.x * w1.x * inv); o[5] = f2bf(v1.y * w1.y * inv);
  o[6] = f2bf(v1.z * w1.z * inv); o[7] = f2bf(v1.w * w1.w * inv);
  *(u16x8*)(xn + (size_t)row * D_MODEL + lane * 8) = o;
}

// ---------------- addout2: out = h + y0 + y1 (final layer, f32 out) -------
__global__ __launch_bounds__(256) void addout2_k(const float* __restrict__ h,
                                                 const unsigned short* __restrict__ y0,
                                                 const unsigned short* __restrict__ y1,
                                                 float* __restrict__ out) {
  int row  = blockIdx.x * 4 + (threadIdx.x >> 6);
  int lane = threadIdx.x & 63;
  const float* hr = h + (size_t)row * D_MODEL + lane * 8;
  f32x4 v0 = *(const f32x4*)(hr);
  f32x4 v1 = *(const f32x4*)(hr + 4);
  u16x8 a = *(const u16x8*)(y0 + (size_t)row * D_MODEL + lane * 8);
  u16x8 b = *(const u16x8*)(y1 + (size_t)row * D_MODEL + lane * 8);
  v0.x += bf2f(a[0]) + bf2f(b[0]); v0.y += bf2f(a[1]) + bf2f(b[1]);
  v0.z += bf2f(a[2]) + bf2f(b[2]); v0.w += bf2f(a[3]) + bf2f(b[3]);
  v1.x += bf2f(a[4]) + bf2f(b[4]); v1.y += bf2f(a[5]) + bf2f(b[5]);
  v1.z += bf2f(a[6]) + bf2f(b[6]); v1.w += bf2f(a[7]) + bf2f(b[7]);
  *(f32x4*)(out + (size_t)row * D_MODEL + lane * 8)     = v0;
  *(f32x4*)(out + (size_t)row * D_MODEL + lane * 8 + 4) = v1;
}

// ---------------- GEMM v7: counted-vmcnt pipeline + T2 swizzle ------------
#define EPI_QKV   0
#define EPI_PLAIN 1

template<int EPI, int BM, int BN>
__global__ __launch_bounds__(256) void gemm7_k(
    const unsigned short* __restrict__ A,
    const unsigned short* __restrict__ Bt,    // [N][K]
    const float* __restrict__ bias0,
    const float* __restrict__ bias1,
    const float* __restrict__ bias2,
    void* __restrict__ out0,
    void* __restrict__ out1,
    void* __restrict__ out2,                  // QKV: vt [bh][d][s]
    int M, int N, int K)
{
  constexpr int MF = BM / 32;
  constexpr int NF = BN / 32;
  constexpr int ALOADS = BM / 32;
  constexpr int BLOADS = BN / 32;
  constexpr int NL = ALOADS + BLOADS;

  __shared__ __attribute__((aligned(16))) unsigned short Al[2][BM * 64];
  __shared__ __attribute__((aligned(16))) unsigned short Bl[2][BN * 64];

  int nblk = gridDim.x;
  int orig = blockIdx.x;
  int qq = nblk >> 3, rr = nblk & 7, xcd = orig & 7, pos = orig >> 3;
  int lid = (xcd < rr ? xcd * (qq + 1) : rr * (qq + 1) + (xcd - rr) * qq) + pos;
  int numN = N / BN;
  int mt = lid / numN, nt = lid % numN;
  int m0 = mt * BM, n0 = nt * BN;

  int tid = threadIdx.x, lane = tid & 63, w = tid >> 6;
  int wm = w >> 1, wn = w & 1;
  int g = lane >> 4, c = lane & 15;
  int srow = lane >> 3, sslot = lane & 7;
  int sgc = (sslot ^ srow) * 8;

  const unsigned short* aG = A  + (size_t)(m0 + w * (BM / 4) + srow) * K + sgc;
  const unsigned short* bG = Bt + (size_t)(n0 + w * (BN / 4) + srow) * K + sgc;
  int aOff = (w * (BM / 4) + srow) * 64 + sslot * 8;
  int bOff = (w * (BN / 4) + srow) * 64 + sslot * 8;

  f32x4 acc[MF][NF] = {};
  int KT = K >> 6;
  int rk = c & 7;

  #pragma unroll
  for (int t = 0; t < ALOADS; ++t)
    gload16(aG + (size_t)(t * 8) * K, &Al[0][aOff + t * 8 * 64]);
  #pragma unroll
  for (int t = 0; t < BLOADS; ++t)
    gload16(bG + (size_t)(t * 8) * K, &Bl[0][bOff + t * 8 * 64]);

  for (int kt = 0; kt < KT; ++kt) {
    int cur = kt & 1;
    if (kt + 1 < KT) {
      int nb = cur ^ 1;
      const unsigned short* aGk = aG + (kt + 1) * 64;
      const unsigned short* bGk = bG + (kt + 1) * 64;
      #pragma unroll
      for (int t = 0; t < ALOADS; ++t)
        gload16(aGk + (size_t)(t * 8) * K, &Al[nb][aOff + t * 8 * 64]);
      #pragma unroll
      for (int t = 0; t < BLOADS; ++t)
        gload16(bGk + (size_t)(t * 8) * K, &Bl[nb][bOff + t * 8 * 64]);
      waitcnt_vm<NL>();
    } else {
      waitcnt_vm<0>();
    }
    __builtin_amdgcn_s_barrier();
    __builtin_amdgcn_sched_barrier(0);
    #pragma unroll
    for (int ks = 0; ks < 2; ++ks) {
      int slot = (ks * 4 + g) ^ rk;
      bf16x8 af[MF], bfr[NF];
      #pragma unroll
      for (int i = 0; i < MF; ++i)
        af[i] = ldb8(&Al[cur][(wm * (MF * 16) + i * 16 + c) * 64 + slot * 8]);
      #pragma unroll
      for (int j = 0; j < NF; ++j)
        bfr[j] = ldb8(&Bl[cur][(wn * (NF * 16) + j * 16 + c) * 64 + slot * 8]);
      #pragma unroll
      for (int i = 0; i < MF; ++i)
        #pragma unroll
        for (int j = 0; j < NF; ++j)
          acc[i][j] = mfma16(af[i], bfr[j], acc[i][j]);
    }
    __builtin_amdgcn_sched_barrier(0);
    __builtin_amdgcn_s_barrier();
  }

  if (EPI == EPI_QKV) {
    int sel  = n0 >> 9;
    if (sel < 2) {
      #pragma unroll
      for (int i = 0; i < MF; ++i) {
        int mrow = m0 + wm * (MF * 16) + i * 16 + g * 4;
        #pragma unroll
        for (int j = 0; j < NF; ++j) {
          int nloc = (n0 & 511) + wn * (NF * 16) + j * 16 + c;
          const float* bp = sel == 0 ? bias0 : bias1;
          unsigned short* o = (unsigned short*)(sel == 0 ? out0 : out1);
          float sc = (sel == 0) ? QSCALE : 1.0f;
          float bn = bp[nloc];
          #pragma unroll
          for (int ii = 0; ii < 4; ++ii)
            o[(size_t)(mrow + ii) * D_MODEL + nloc] = f2bf((acc[i][j][ii] + bn) * sc);
        }
      }
    } else {
      unsigned short* T = &Al[0][0];            // 64 x 136
      #pragma unroll
      for (int i = 0; i < MF; ++i) {
        int ml0 = wm * (MF * 16) + i * 16 + g * 4;
        #pragma unroll
        for (int j = 0; j < NF; ++j) {
          int nl = wn * (NF * 16) + j * 16 + c;
          float bn = bias2[(n0 & 511) + nl];
          u16x4 pk;
          #pragma unroll
          for (int ii = 0; ii < 4; ++ii) pk[ii] = f2bf(acc[i][j][ii] + bn);
          *(u16x4*)&T[nl * 136 + ml0] = pk;
        }
      }
      __syncthreads();
      int b  = m0 >> 11, s0 = m0 & 2047;
      int hh = (n0 & 511) >> 6;
      int r  = tid >> 2, c0 = (tid & 3) * 32;
      unsigned short* dst = (unsigned short*)out2 +
          ((size_t)(b * NHEAD + hh) * HD + r) * SEQ + s0 + c0;
      #pragma unroll
      for (int u = 0; u < 4; ++u)
        *(u16x8*)(dst + u * 8) = *(u16x8*)&T[r * 136 + c0 + u * 8];
    }
  } else {  // EPI_PLAIN
    #pragma unroll
    for (int i = 0; i < MF; ++i) {
      int mrow = m0 + wm * (MF * 16) + i * 16 + g * 4;
      #pragma unroll
      for (int j = 0; j < NF; ++j) {
        int n = n0 + wn * (NF * 16) + j * 16 + c;
        float bn = bias0[n];
        unsigned short* o = (unsigned short*)out0;
        #pragma unroll
        for (int ii = 0; ii < 4; ++ii)
          o[(size_t)(mrow + ii) * N + n] = f2bf(acc[i][j][ii] + bn);
      }
    }
  }
}

// ---------------- GEMM v12s: split-K (S=2) plain GEMM --------------------
// grid (512, 2): x = (mt,nt) swizzled, y = K-half. Each half writes its own
// bf16 partial buffer (no RMW); bias folded into half 0. addrms2 combines.
template<int BM, int BN>
__global__ __launch_bounds__(256) void gemm12s_k(
    const unsigned short* __restrict__ A,     // [M][KFULL]
    const unsigned short* __restrict__ Bt,    // [N][KFULL]
    const float* __restrict__ bias0,
    unsigned short* __restrict__ out,         // [2][M][N]
    int M, int N, int KFULL, int KLEN)
{
  constexpr int MF = BM / 32;
  constexpr int NF = BN / 32;
  constexpr int ALOADS = BM / 32;
  constexpr int BLOADS = BN / 32;
  constexpr int NL = ALOADS + BLOADS;

  __shared__ __attribute__((aligned(16))) unsigned short Al[2][BM * 64];
  __shared__ __attribute__((aligned(16))) unsigned short Bl[2][BN * 64];

  int kh = blockIdx.y;
  int nblk = gridDim.x;
  int orig = blockIdx.x;
  int qq = nblk >> 3, rr = nblk & 7, xcd = orig & 7, pos = orig >> 3;
  int lid = (xcd < rr ? xcd * (qq + 1) : rr * (qq + 1) + (xcd - rr) * qq) + pos;
  int numN = N / BN;
  int mt = lid / numN, nt = lid % numN;
  int m0 = mt * BM, n0 = nt * BN;

  int tid = threadIdx.x, lane = tid & 63, w = tid >> 6;
  int wm = w >> 1, wn = w & 1;
  int g = lane >> 4, c = lane & 15;
  int srow = lane >> 3, sslot = lane & 7;
  int sgc = (sslot ^ srow) * 8;

  const unsigned short* aG = A  + (size_t)(m0 + w * (BM / 4) + srow) * KFULL + kh * KLEN + sgc;
  const unsigned short* bG = Bt + (size_t)(n0 + w * (BN / 4) + srow) * KFULL + kh * KLEN + sgc;
  int aOff = (w * (BM / 4) + srow) * 64 + sslot * 8;
  int bOff = (w * (BN / 4) + srow) * 64 + sslot * 8;

  f32x4 acc[MF][NF] = {};
  int KT = KLEN >> 6;
  int rk = c & 7;

  #pragma unroll
  for (int t = 0; t < ALOADS; ++t)
    gload16(aG + (size_t)(t * 8) * KFULL, &Al[0][aOff + t * 8 * 64]);
  #pragma unroll
  for (int t = 0; t < BLOADS; ++t)
    gload16(bG + (size_t)(t * 8) * KFULL, &Bl[0][bOff + t * 8 * 64]);

  for (int kt = 0; kt < KT; ++kt) {
    int cur = kt & 1;
    if (kt + 1 < KT) {
      int nb = cur ^ 1;
      const unsigned short* aGk = aG + (kt + 1) * 64;
      const unsigned short* bGk = bG + (kt + 1) * 64;
      #pragma unroll
      for (int t = 0; t < ALOADS; ++t)
        gload16(aGk + (size_t)(t * 8) * KFULL, &Al[nb][aOff + t * 8 * 64]);
      #pragma unroll
      for (int t = 0; t < BLOADS; ++t)
        gload16(bGk + (size_t)(t * 8) * KFULL, &Bl[nb][bOff + t * 8 * 64]);
      waitcnt_vm<NL>();
    } else {
      waitcnt_vm<0>();
    }
    __builtin_amdgcn_s_barrier();
    __builtin_amdgcn_sched_barrier(0);
    #pragma unroll
    for (int ks = 0; ks < 2; ++ks) {
      int slot = (ks * 4 + g) ^ rk;
      bf16x8 af[MF], bfr[NF];
      #pragma unroll
      for (int i = 0; i < MF; ++i)
        af[i] = ldb8(&Al[cur][(wm * (MF * 16) + i * 16 + c) * 64 + slot * 8]);
      #pragma unroll
      for (int j = 0; j < NF; ++j)
        bfr[j] = ldb8(&Bl[cur][(wn * (NF * 16) + j * 16 + c) * 64 + slot * 8]);
      #pragma unroll
      for (int i = 0; i < MF; ++i)
        #pragma unroll
        for (int j = 0; j < NF; ++j)
          acc[i][j] = mfma16(af[i], bfr[j], acc[i][j]);
    }
    __builtin_amdgcn_sched_barrier(0);
    __builtin_amdgcn_s_barrier();
  }

  unsigned short* o = out + (size_t)kh * M * N;
  #pragma unroll
  for (int i = 0; i < MF; ++i) {
    int mrow = m0 + wm * (MF * 16) + i * 16 + g * 4;
    #pragma unroll
    for (int j = 0; j < NF; ++j) {
      int n = n0 + wn * (NF * 16) + j * 16 + c;
      float bn = (kh == 0) ? bias0[n] : 0.0f;
      #pragma unroll
      for (int ii = 0; ii < 4; ++ii)
        o[(size_t)(mrow + ii) * N + n] = f2bf(acc[i][j][ii] + bn);
    }
  }
}

// ---------------- GEMM v11d: fused dual-B gated FFN-up (single buffer,
// m-major XCD chunking -> hbuf output is XCD-local for the w2 consumer) ----
template<int BM, int BN>
__global__ __launch_bounds__(256) void gemm11d_k(
    const unsigned short* __restrict__ A,
    const unsigned short* __restrict__ B0t,   // [N][K]
    const unsigned short* __restrict__ B1t,   // [N][K]
    const float* __restrict__ bias0,
    const float* __restrict__ bias1,
    unsigned short* __restrict__ out,
    int M, int N, int K)
{
  constexpr int MF = BM / 32;
  constexpr int NF = BN / 32;
  constexpr int ALOADS = BM / 32;
  constexpr int BLOADS = BN / 32;

  __shared__ __attribute__((aligned(16))) unsigned short Al[BM * 64];
  __shared__ __attribute__((aligned(16))) unsigned short B0l[BN * 64];
  __shared__ __attribute__((aligned(16))) unsigned short B1l[BN * 64];

  int nblk = gridDim.x;
  int orig = blockIdx.x;
  int qq = nblk >> 3, rr = nblk & 7, xcd = orig & 7, pos = orig >> 3;
  int lid = (xcd < rr ? xcd * (qq + 1) : rr * (qq + 1) + (xcd - rr) * qq) + pos;
  int numN = N / BN;
  int mt = lid / numN, nt = lid % numN;   // m-major: XCD chunk = contiguous m slab
  int m0 = mt * BM, n0 = nt * BN;

  int tid = threadIdx.x, lane = tid & 63, w = tid >> 6;
  int wm = w >> 1, wn = w & 1;
  int g = lane >> 4, c = lane & 15;
  int srow = lane >> 3, sslot = lane & 7;
  int sgc = (sslot ^ srow) * 8;

  const unsigned short* aG  = A   + (size_t)(m0 + w * (BM / 4) + srow) * K + sgc;
  const unsigned short* b0G = B0t + (size_t)(n0 + w * (BN / 4) + srow) * K + sgc;
  const unsigned short* b1G = B1t + (size_t)(n0 + w * (BN / 4) + srow) * K + sgc;
  unsigned short* aL  = &Al [(w * (BM / 4) + srow) * 64 + sslot * 8];
  unsigned short* b0L = &B0l[(w * (BN / 4) + srow) * 64 + sslot * 8];
  unsigned short* b1L = &B1l[(w * (BN / 4) + srow) * 64 + sslot * 8];

  f32x4 acc0[MF][NF] = {};
  f32x4 acc1[MF][NF] = {};
  int KT = K >> 6;
  int rk = c & 7;

  for (int kt = 0; kt < KT; ++kt) {
    if (kt) __syncthreads();
    #pragma unroll
    for (int t = 0; t < ALOADS; ++t)
      gload16(aG + (size_t)(t * 8) * K + kt * 64, aL + t * 8 * 64);
    #pragma unroll
    for (int t = 0; t < BLOADS; ++t) {
      gload16(b0G + (size_t)(t * 8) * K + kt * 64, b0L + t * 8 * 64);
      gload16(b1G + (size_t)(t * 8) * K + kt * 64, b1L + t * 8 * 64);
    }
    __syncthreads();
    #pragma unroll
    for (int ks = 0; ks < 2; ++ks) {
      int slot = (ks * 4 + g) ^ rk;
      bf16x8 af[MF], b0f[NF], b1f[NF];
      #pragma unroll
      for (int i = 0; i < MF; ++i)
        af[i] = ldb8(&Al[(wm * (MF * 16) + i * 16 + c) * 64 + slot * 8]);
      #pragma unroll
      for (int j = 0; j < NF; ++j) {
        b0f[j] = ldb8(&B0l[(wn * (NF * 16) + j * 16 + c) * 64 + slot * 8]);
        b1f[j] = ldb8(&B1l[(wn * (NF * 16) + j * 16 + c) * 64 + slot * 8]);
      }
      #pragma unroll
      for (int i = 0; i < MF; ++i)
        #pragma unroll
        for (int j = 0; j < NF; ++j) {
          acc0[i][j] = mfma16(af[i], b0f[j], acc0[i][j]);
          acc1[i][j] = mfma16(af[i], b1f[j], acc1[i][j]);
        }
    }
  }

  #pragma unroll
  for (int i = 0; i < MF; ++i) {
    int mrow = m0 + wm * (MF * 16) + i * 16 + g * 4;
    #pragma unroll
    for (int j = 0; j < NF; ++j) {
      int n = n0 + wn * (NF * 16) + j * 16 + c;
      float b0n = bias0[n], b1n = bias1[n];
      #pragma unroll
      for (int ii = 0; ii < 4; ++ii) {
        float a  = acc0[i][j][ii] + b0n;
        float gv = acc1[i][j][ii] + b1n;
        float s  = gv / (1.0f + __expf(-gv));
        out[(size_t)(mrow + ii) * N + n] = f2bf(a * s);
      }
    }
  }
}

// ---------------- attention v5: split-K flash, no-max softmax ------------
struct Stg { uint4v k0, k1, v0, v1; };

static __device__ __forceinline__ Stg stage_load(const unsigned short* Kp,
                                                 const unsigned short* Vp,
                                                 int kbase, int srow, int sslot) {
  Stg s;
  const unsigned short* kr = Kp + (size_t)(kbase + srow) * D_MODEL + sslot * 8;
  s.k0 = *(const uint4v*)kr;
  s.k1 = *(const uint4v*)(kr + 32);
  const unsigned short* vr = Vp + (size_t)srow * SEQ + kbase + sslot * 8;
  s.v0 = *(const uint4v*)vr;
  s.v1 = *(const uint4v*)(vr + 32);
  return s;
}
static __device__ __forceinline__ void stage_write(unsigned short* Klb, unsigned short* Vlb,
                                                   const Stg& s, int srow, int sslot) {
  char* kb = (char*)Klb;
  *(uint4v*)(kb + SWZ(srow, srow * 128 + sslot * 16))       = s.k0;
  *(uint4v*)(kb + SWZ(srow, srow * 128 + (sslot + 4) * 16)) = s.k1;
  char* vb = (char*)Vlb;
  *(uint4v*)(vb + SWZ(srow, srow * 128 + sslot * 16))       = s.v0;
  *(uint4v*)(vb + SWZ(srow, srow * 128 + (sslot + 4) * 16)) = s.v1;
}

template<bool MASKED>
static __device__ __forceinline__ void attn_tile(
    const unsigned short* Klb, const unsigned short* Vlb,
    bf16x8 qf0, bf16x8 qf1, f32x4* oacc, float& ps,
    int g, int c, int kbase, int qrow)
{
  f32x4 z[4];
  #pragma unroll
  for (int hh = 0; hh < 4; ++hh) {
    int r = hh * 16 + c;
    const char* base = (const char*)Klb;
    bf16x8 k0 = ldb8((const unsigned short*)(base + SWZ(r, r * 128 + g * 16)));
    bf16x8 k1 = ldb8((const unsigned short*)(base + SWZ(r, r * 128 + 64 + g * 16)));
    f32x4 t = {};
    t = mfma16(k0, qf0, t);
    t = mfma16(k1, qf1, t);
    z[hh] = t;
  }
  u16x8 pa0, pa1;
  #pragma unroll
  for (int hh = 0; hh < 4; ++hh) {
    #pragma unroll
    for (int i = 0; i < 4; ++i) {
      float p = exp2f(z[hh][i]);
      if (MASKED && (kbase + hh * 16 + g * 4 + i > qrow)) p = 0.0f;
      ps += p;
      unsigned short pb = f2bf(p);
      if (hh < 2) pa0[hh * 4 + i] = pb;
      else        pa1[(hh - 2) * 4 + i] = pb;
    }
  }
  bf16x8 af0 = __builtin_bit_cast(bf16x8, pa0);
  bf16x8 af1 = __builtin_bit_cast(bf16x8, pa1);
  #pragma unroll
  for (int db = 0; db < 4; ++db) {
    int r = db * 16 + c;
    const char* base = (const char*)Vlb;
    u16x4 v00 = *(const u16x4*)(base + SWZ(r, r * 128 + g * 8));
    u16x4 v01 = *(const u16x4*)(base + SWZ(r, r * 128 + 32 + g * 8));
    u16x4 v10 = *(const u16x4*)(base + SWZ(r, r * 128 + 64 + g * 8));
    u16x4 v11 = *(const u16x4*)(base + SWZ(r, r * 128 + 96 + g * 8));
    u16x8 vb0, vb1;
    #pragma unroll
    for (int j = 0; j < 4; ++j) {
      vb0[j] = v00[j]; vb0[4 + j] = v01[j];
      vb1[j] = v10[j]; vb1[4 + j] = v11[j];
    }
    oacc[db] = mfma16(af0, __builtin_bit_cast(bf16x8, vb0), oacc[db]);
    oacc[db] = mfma16(af1, __builtin_bit_cast(bf16x8, vb1), oacc[db]);
  }
}

static __device__ __forceinline__ int slot_base(int c) {
  if (c < 16) return (c - 8) * 2;
  if (c < 24) return 16 + (c - 16) * 3;
  return 40 + (c - 24) * 4;
}

__global__ __launch_bounds__(256) void attn5_k(const unsigned short* __restrict__ Q,
                                               const unsigned short* __restrict__ K,
                                               const unsigned short* __restrict__ VT,
                                               unsigned short* __restrict__ O,
                                               float* __restrict__ Oparts,
                                               float* __restrict__ Sparts)
{
  __shared__ __attribute__((aligned(16))) unsigned short Kl[2][64 * 64];
  __shared__ __attribute__((aligned(16))) unsigned short Vl[2][64 * 64];
  int tid = threadIdx.x, lane = tid & 63, w = tid >> 6;
  int g = lane >> 4, cl = lane & 15;

  int z = 79 - (int)blockIdx.x;
  int c, sp;
  if (z < 8)        { c = z;                    sp = 0; }
  else if (z < 24)  { int t2 = z - 8;  c = 8  + (t2 >> 1); sp = t2 & 1; }
  else if (z < 48)  { int t2 = z - 24; c = 16 + t2 / 3;    sp = t2 % 3; }
  else              { int t2 = z - 48; c = 24 + (t2 >> 2); sp = t2 & 3; }
  int kt0 = sp * 8;
  int kt1 = min(c + 1, kt0 + 8);
  bool lastsplit = (kt1 == c + 1);

  int bh = blockIdx.y, b = bh >> 3, h = bh & 7;
  int q0 = c * 64;
  const unsigned short* Qp = Q + (size_t)(b * SEQ) * D_MODEL + h * HD;
  const unsigned short* Kp = K + (size_t)(b * SEQ) * D_MODEL + h * HD;
  const unsigned short* Vp = VT + (size_t)bh * HD * SEQ;

  int qrow = q0 + w * 16 + cl;
  bf16x8 qf0 = ldb8(Qp + (size_t)qrow * D_MODEL + g * 8);
  bf16x8 qf1 = ldb8(Qp + (size_t)qrow * D_MODEL + 32 + g * 8);

  f32x4 oacc[4] = {};
  float ps = 0.0f;
  int srow = tid >> 2, sslot = tid & 3;

  Stg s0 = stage_load(Kp, Vp, kt0 * 64, srow, sslot);
  stage_write(&Kl[0][0], &Vl[0][0], s0, srow, sslot);
  __syncthreads();

  int buf = 0;
  for (int kt = kt0; kt < kt1 - 1; ++kt) {
    Stg sn = stage_load(Kp, Vp, (kt + 1) * 64, srow, sslot);
    attn_tile<false>(&Kl[buf][0], &Vl[buf][0], qf0, qf1, oacc, ps, g, cl, 0, 0);
    stage_write(&Kl[buf ^ 1][0], &Vl[buf ^ 1][0], sn, srow, sslot);
    __syncthreads();
    buf ^= 1;
  }
  if (lastsplit)
    attn_tile<true>(&Kl[buf][0], &Vl[buf][0], qf0, qf1, oacc, ps, g, cl,
                    (kt1 - 1) * 64, qrow);
  else
    attn_tile<false>(&Kl[buf][0], &Vl[buf][0], qf0, qf1, oacc, ps, g, cl, 0, 0);

  ps += __shfl_xor(ps, 16, 64);
  ps += __shfl_xor(ps, 32, 64);

  if (c < 8) {
    f32x4 inv;
    #pragma unroll
    for (int i = 0; i < 4; ++i) inv[i] = 1.0f / __shfl(ps, g * 4 + i, 64);
    #pragma unroll
    for (int db = 0; db < 4; ++db)
      #pragma unroll
      for (int i = 0; i < 4; ++i)
        O[(size_t)(b * SEQ + q0 + w * 16 + g * 4 + i) * D_MODEL + h * HD + db * 16 + cl] =
            f2bf(oacc[db][i] * inv[i]);
  } else {
    size_t slot = (size_t)bh * 72 + slot_base(c) + sp;
    float* Op = Oparts + slot * 4096;
    float* Sp = Sparts + slot * 64;
    #pragma unroll
    for (int db = 0; db < 4; ++db)
      #pragma unroll
      for (int i = 0; i < 4; ++i)
        Op[(w * 16 + g * 4 + i) * 64 + db * 16 + cl] = oacc[db][i];
    if (g == 0) Sp[w * 16 + cl] = ps;
  }
}

__global__ __launch_bounds__(256) void attn_comb_k(const float* __restrict__ Oparts,
                                                   const float* __restrict__ Sparts,
                                                   unsigned short* __restrict__ O) {
  int t  = threadIdx.x;
  int c  = 8 + (int)(blockIdx.x % 24);
  int bh = (int)(blockIdx.x / 24);
  int b = bh >> 3, h = bh & 7;
  int ns = (c + 8) >> 3;
  size_t slot = (size_t)bh * 72 + slot_base(c);
  const float* O0 = Oparts + slot * 4096;
  const float* S0 = Sparts + slot * 64;
  int r = t >> 2, d0 = (t & 3) * 16;
  f32x4 a0 = {}, a1 = {}, a2 = {}, a3 = {};
  float s = 0.0f;
  for (int si = 0; si < ns; ++si) {
    const float* o = O0 + si * 4096 + r * 64 + d0;
    a0 += *(const f32x4*)(o);
    a1 += *(const f32x4*)(o + 4);
    a2 += *(const f32x4*)(o + 8);
    a3 += *(const f32x4*)(o + 12);
    s  += S0[si * 64 + r];
  }
  float inv = 1.0f / s;
  u16x8 w0, w1;
  #pragma unroll
  for (int j = 0; j < 4; ++j) {
    w0[j]     = f2bf(a0[j] * inv); w0[4 + j] = f2bf(a1[j] * inv);
    w1[j]     = f2bf(a2[j] * inv); w1[4 + j] = f2bf(a3[j] * inv);
  }
  unsigned short* dst = O + (size_t)(b * SEQ + c * 64 + r) * D_MODEL + h * HD + d0;
  *(u16x8*)(dst)     = w0;
  *(u16x8*)(dst + 8) = w1;
}

// ---------------- launch ----------------
extern "C" void kernel_launch(void* const* d_in, const int* in_sizes, int n_in,
                              void* d_out, int out_size, void* d_ws, size_t ws_size,
                              hipStream_t stream) {
  (void)in_sizes; (void)n_in; (void)out_size; (void)ws_size;
  const float* x   = (const float*)d_in[0];
  const float* qw  = (const float*)d_in[1];
  const float* qb  = (const float*)d_in[2];
  const float* kw  = (const float*)d_in[3];
  const float* kbi = (const float*)d_in[4];
  const float* vw  = (const float*)d_in[5];
  const float* vb  = (const float*)d_in[6];
  const float* ow  = (const float*)d_in[7];
  const float* ob  = (const float*)d_in[8];
  const float* w0  = (const float*)d_in[9];
  const float* b0  = (const float*)d_in[10];
  const float* w1  = (const float*)d_in[11];
  const float* b1  = (const float*)d_in[12];
  const float* w2  = (const float*)d_in[13];
  const float* b2  = (const float*)d_in[14];
  const float* anw = (const float*)d_in[15];
  const float* fnw = (const float*)d_in[16];

  char* ws = (char*)d_ws;
  float*          h    = (float*)ws;                              // 0-8MB fp32 residual
  unsigned short* xn   = (unsigned short*)(ws + (8u  << 20));     // 8-12
  unsigned short* q    = (unsigned short*)(ws + (12u << 20));     // 12-16
  unsigned short* k    = (unsigned short*)(ws + (16u << 20));     // 16-20
  unsigned short* vt   = (unsigned short*)(ws + (24u << 20));     // 24-28
  unsigned short* ao   = (unsigned short*)(ws + (28u << 20));     // 28-32
  unsigned short* hbuf = (unsigned short*)(ws + (12u << 20));     // 12-28 (aliases q,k,vt)
  unsigned short* Wq   = (unsigned short*)(ws + (36u << 20));     // 36-42
  unsigned short* Wo   = (unsigned short*)(ws + (42u << 20));     // 42-44
  unsigned short* W01  = (unsigned short*)(ws + (44u << 20));     // 44-60
  unsigned short* W2   = (unsigned short*)(ws + (60u << 20));     // 60-68
  float*          Opar = (float*)(ws + (68u << 20));              // 68-86 (18MB)
  float*          Spar = (float*)(ws + (86u << 20));              // 86-86.3
  unsigned short* ysp  = (unsigned short*)(ws + (88u << 20));     // 88-96 (split-K partials, 2x4MB)

  prep_t<<<4096, 64, 0, stream>>>(qw, kw, vw, ow, w0, w1, w2, Wq, Wo, W01, W2);
  initrms_k<<<BTOK / 4, 256, 0, stream>>>(x, anw, h, xn);

  for (int l = 0; l < 4; ++l) {
    size_t bo  = (size_t)l * D_MODEL;
    size_t bho = (size_t)l * HIDE;

    gemm7_k<EPI_QKV, 128, 64><<<768, 256, 0, stream>>>(
        xn, Wq + (size_t)l * 786432, qb + bo, kbi + bo, vb + bo,
        q, k, vt, BTOK, 3 * D_MODEL, D_MODEL);
    attn5_k<<<dim3(80, 16), 256, 0, stream>>>(q, k, vt, ao, Opar, Spar);
    attn_comb_k<<<384, 256, 0, stream>>>(Opar, Spar, ao);
    gemm12s_k<64, 64><<<dim3(512, 2), 256, 0, stream>>>(
        ao, Wo + (size_t)l * 262144, ob + bo, ysp,
        BTOK, D_MODEL, D_MODEL, D_MODEL / 2);
    addrms2_k<<<BTOK / 4, 256, 0, stream>>>(
        h, ysp, ysp + (size_t)BTOK * D_MODEL, fnw + bo, xn);

    gemm11d_k<128, 64><<<1024, 256, 0, stream>>>(
        xn, W01 + (size_t)l * 2097152, W01 + (size_t)l * 2097152 + 1048576,
        b0 + bho, b1 + bho, hbuf, BTOK, HIDE, D_MODEL);
    gemm12s_k<64, 64><<<dim3(512, 2), 256, 0, stream>>>(
        hbuf, W2 + (size_t)l * 1048576, b2 + bo, ysp,
        BTOK, D_MODEL, HIDE, HIDE / 2);
    if (l < 3)
      addrms2_k<<<BTOK / 4, 256, 0, stream>>>(
          h, ysp, ysp + (size_t)BTOK * D_MODEL, anw + bo + D_MODEL, xn);
    else
      addout2_k<<<BTOK / 4, 256, 0, stream>>>(
          h, ysp, ysp + (size_t)BTOK * D_MODEL, (float*)d_out);
  }
}

// Round 20
// 427.144 us; speedup vs baseline: 1.1317x; 1.0055x over previous
//
#include <hip/hip_runtime.h>
#include <math.h>

// ---------------- types ----------------
typedef unsigned int   uint4v __attribute__((ext_vector_type(4)));
typedef float          f32x4  __attribute__((ext_vector_type(4)));
typedef __bf16         bf16x8 __attribute__((ext_vector_type(8)));
typedef unsigned short u16x8  __attribute__((ext_vector_type(8)));
typedef unsigned short u16x4  __attribute__((ext_vector_type(4)));

#define D_MODEL 512
#define SEQ     2048
#define BTOK    4096   // B * SEQ
#define HIDE    2048
#define NHEAD   8
#define HD      64

static __device__ __forceinline__ unsigned short f2bf(float f) {
  __bf16 b = (__bf16)f;
  return __builtin_bit_cast(unsigned short, b);
}
static __device__ __forceinline__ float bf2f(unsigned short b) {
  union { unsigned u; float f; } v; v.u = ((unsigned)b) << 16;
  return v.f;
}
static __device__ __forceinline__ bf16x8 ldb8(const unsigned short* p) {
  return __builtin_bit_cast(bf16x8, *(const uint4v*)p);
}
static __device__ __forceinline__ f32x4 mfma16(bf16x8 a, bf16x8 b, f32x4 c) {
  return __builtin_amdgcn_mfma_f32_16x16x32_bf16(a, b, c, 0, 0, 0);
}

typedef unsigned int u32_g __attribute__((address_space(1)));
typedef unsigned int u32_l __attribute__((address_space(3)));
static __device__ __forceinline__ void gload16(const unsigned short* g, unsigned short* l) {
  __builtin_amdgcn_global_load_lds((const u32_g*)(const void*)g,
                                   (u32_l*)(void*)l, 16, 0, 0);
}

#define SWZ(r, off) ((off) ^ (((r) & 7) << 4))
#define QSCALE 0.180336880f   // 0.125 * log2(e)

template<int N>
static __device__ __forceinline__ void waitcnt_vm() {
  asm volatile("s_waitcnt vmcnt(%0)" :: "i"(N) : "memory");
}

// ---------------- weight prep: LDS-tiled transpose f32 [K][N] -> bf16 [N][K] ----
__global__ __launch_bounds__(64) void prep_t(
    const float* __restrict__ qw, const float* __restrict__ kw,
    const float* __restrict__ vw, const float* __restrict__ ow,
    const float* __restrict__ w0, const float* __restrict__ w1,
    const float* __restrict__ w2,
    unsigned short* __restrict__ Wq, unsigned short* __restrict__ Wo,
    unsigned short* __restrict__ W01, unsigned short* __restrict__ W2)
{
  int bid = blockIdx.x;
  int l = bid >> 10;
  int r = bid & 1023;
  const float* src; unsigned short* dst;
  int tr, tc, srcN, dstK;
  if (r < 192) {
    int sel = r >> 6, tt = r & 63;
    tr = tt >> 3; tc = tt & 7;
    src = (sel == 0 ? qw : sel == 1 ? kw : vw) + (size_t)l * 262144;
    srcN = 512; dstK = 512;
    dst = Wq + (size_t)l * 786432 + (size_t)(sel * 512 + tc * 64) * 512 + tr * 64;
  } else if (r < 256) {
    int tt = r - 192; tr = tt >> 3; tc = tt & 7;
    src = ow + (size_t)l * 262144; srcN = 512; dstK = 512;
    dst = Wo + (size_t)l * 262144 + (size_t)(tc * 64) * 512 + tr * 64;
  } else if (r < 768) {
    int idx = r - 256; int sel = idx >> 8; int tt = idx & 255;
    tr = tt >> 5; tc = tt & 31;
    src = (sel ? w1 : w0) + (size_t)l * 1048576; srcN = 2048; dstK = 512;
    dst = W01 + (size_t)l * 2097152 + (size_t)sel * 1048576 + (size_t)(tc * 64) * 512 + tr * 64;
  } else {
    int tt = r - 768; tr = tt >> 3; tc = tt & 7;
    src = w2 + (size_t)l * 1048576; srcN = 512; dstK = 2048;
    dst = W2 + (size_t)l * 1048576 + (size_t)(tc * 64) * 2048 + tr * 64;
  }
  src += (size_t)(tr * 64) * srcN + tc * 64;
  __shared__ unsigned short T[64][68];
  int t = threadIdx.x;
  #pragma unroll
  for (int it = 0; it < 16; ++it) {
    int row = it * 4 + (t >> 4);
    int col = (t & 15) * 4;
    f32x4 v4 = *(const f32x4*)(src + (size_t)row * srcN + col);
    u16x4 o; o[0] = f2bf(v4.x); o[1] = f2bf(v4.y); o[2] = f2bf(v4.z); o[3] = f2bf(v4.w);
    *(u16x4*)&T[row][col] = o;
  }
  __syncthreads();
  unsigned short* orow = dst + (size_t)t * dstK;
  #pragma unroll
  for (int j0 = 0; j0 < 8; ++j0) {
    u16x8 o;
    #pragma unroll
    for (int j = 0; j < 8; ++j) o[j] = T[j0 * 8 + j][t];
    *(u16x8*)(orow + j0 * 8) = o;
  }
}

// ---------------- initrms: h = x; xn = rms(x)*w ----------------
__global__ __launch_bounds__(256) void initrms_k(const float* __restrict__ x,
                                                 const float* __restrict__ w,
                                                 float* __restrict__ h,
                                                 unsigned short* __restrict__ xn) {
  int row  = blockIdx.x * 4 + (threadIdx.x >> 6);
  int lane = threadIdx.x & 63;
  const float* xr = x + (size_t)row * D_MODEL + lane * 8;
  f32x4 v0 = *(const f32x4*)(xr);
  f32x4 v1 = *(const f32x4*)(xr + 4);
  *(f32x4*)(h + (size_t)row * D_MODEL + lane * 8)     = v0;
  *(f32x4*)(h + (size_t)row * D_MODEL + lane * 8 + 4) = v1;
  float ss = v0.x*v0.x + v0.y*v0.y + v0.z*v0.z + v0.w*v0.w
           + v1.x*v1.x + v1.y*v1.y + v1.z*v1.z + v1.w*v1.w;
  #pragma unroll
  for (int m = 1; m < 64; m <<= 1) ss += __shfl_xor(ss, m, 64);
  float inv = 1.0f / (sqrtf(ss * (1.0f / D_MODEL)) + 1e-6f);
  f32x4 w0 = *(const f32x4*)(w + lane * 8);
  f32x4 w1 = *(const f32x4*)(w + lane * 8 + 4);
  u16x8 o;
  o[0] = f2bf(v0.x * w0.x * inv); o[1] = f2bf(v0.y * w0.y * inv);
  o[2] = f2bf(v0.z * w0.z * inv); o[3] = f2bf(v0.w * w0.w * inv);
  o[4] = f2bf(v1.x * w1.x * inv); o[5] = f2bf(v1.y * w1.y * inv);
  o[6] = f2bf(v1.z * w1.z * inv); o[7] = f2bf(v1.w * w1.w * inv);
  *(u16x8*)(xn + (size_t)row * D_MODEL + lane * 8) = o;
}

// ---------------- addrms2: h += y0+y1 (split-K partials); xn = rms(h)*w ----
__global__ __launch_bounds__(256) void addrms2_k(float* __restrict__ h,
                                                 const unsigned short* __restrict__ y0,
                                                 const unsigned short* __restrict__ y1,
                                                 const float* __restrict__ w,
                                                 unsigned short* __restrict__ xn) {
  int row  = blockIdx.x * 4 + (threadIdx.x >> 6);
  int lane = threadIdx.x & 63;
  float* hr = h + (size_t)row * D_MODEL + lane * 8;
  f32x4 v0 = *(const f32x4*)(hr);
  f32x4 v1 = *(const f32x4*)(hr + 4);
  u16x8 a = *(const u16x8*)(y0 + (size_t)row * D_MODEL + lane * 8);
  u16x8 b = *(const u16x8*)(y1 + (size_t)row * D_MODEL + lane * 8);
  v0.x += bf2f(a[0]) + bf2f(b[0]); v0.y += bf2f(a[1]) + bf2f(b[1]);
  v0.z += bf2f(a[2]) + bf2f(b[2]); v0.w += bf2f(a[3]) + bf2f(b[3]);
  v1.x += bf2f(a[4]) + bf2f(b[4]); v1.y += bf2f(a[5]) + bf2f(b[5]);
  v1.z += bf2f(a[6]) + bf2f(b[6]); v1.w += bf2f(a[7]) + bf2f(b[7]);
  *(f32x4*)(hr)     = v0;
  *(f32x4*)(hr + 4) = v1;
  float ss = v0.x*v0.x + v0.y*v0.y + v0.z*v0.z + v0.w*v0.w
           + v1.x*v1.x + v1.y*v1.y + v1.z*v1.z + v1.w*v1.w;
  #pragma unroll
  for (int m = 1; m < 64; m <<= 1) ss += __shfl_xor(ss, m, 64);
  float inv = 1.0f / (sqrtf(ss * (1.0f / D_MODEL)) + 1e-6f);
  f32x4 w0 = *(const f32x4*)(w + lane * 8);
  f32x4 w1 = *(const f32x4*)(w + lane * 8 + 4);
  u16x8 o;
  o[0] = f2bf(v0.x * w0.x * inv); o[1] = f2bf(v0.y * w0.y * inv);
  o[2] = f2bf(v0.z * w0.z * inv); o[3] = f2bf(v0.w * w0.w * inv);
  o[4] = f2bf(v1.x * w1.x * inv); o[5] = f2bf(v1.y * w1.y * inv);
  o[6] = f2bf(v1.z * w1.z * inv); o[7] = f2bf(v1.w * w1.w * inv);
  *(u16x8*)(xn + (size_t)row * D_MODEL + lane * 8) = o;
}

// ---------------- addout2: out = h + y0 + y1 (final layer, f32 out) -------
__global__ __launch_bounds__(256) void addout2_k(const float* __restrict__ h,
                                                 const unsigned short* __restrict__ y0,
                                                 const unsigned short* __restrict__ y1,
                                                 float* __restrict__ out) {
  int row  = blockIdx.x * 4 + (threadIdx.x >> 6);
  int lane = threadIdx.x & 63;
  const float* hr = h + (size_t)row * D_MODEL + lane * 8;
  f32x4 v0 = *(const f32x4*)(hr);
  f32x4 v1 = *(const f32x4*)(hr + 4);
  u16x8 a = *(const u16x8*)(y0 + (size_t)row * D_MODEL + lane * 8);
  u16x8 b = *(const u16x8*)(y1 + (size_t)row * D_MODEL + lane * 8);
  v0.x += bf2f(a[0]) + bf2f(b[0]); v0.y += bf2f(a[1]) + bf2f(b[1]);
  v0.z += bf2f(a[2]) + bf2f(b[2]); v0.w += bf2f(a[3]) + bf2f(b[3]);
  v1.x += bf2f(a[4]) + bf2f(b[4]); v1.y += bf2f(a[5]) + bf2f(b[5]);
  v1.z += bf2f(a[6]) + bf2f(b[6]); v1.w += bf2f(a[7]) + bf2f(b[7]);
  *(f32x4*)(out + (size_t)row * D_MODEL + lane * 8)     = v0;
  *(f32x4*)(out + (size_t)row * D_MODEL + lane * 8 + 4) = v1;
}

// ---------------- GEMM v7: counted-vmcnt pipeline + T2 swizzle ------------
#define EPI_QKV   0
#define EPI_PLAIN 1

template<int EPI, int BM, int BN>
__global__ __launch_bounds__(256) void gemm7_k(
    const unsigned short* __restrict__ A,
    const unsigned short* __restrict__ Bt,    // [N][K]
    const float* __restrict__ bias0,
    const float* __restrict__ bias1,
    const float* __restrict__ bias2,
    void* __restrict__ out0,
    void* __restrict__ out1,
    void* __restrict__ out2,                  // QKV: vt [bh][d][s]
    int M, int N, int K)
{
  constexpr int MF = BM / 32;
  constexpr int NF = BN / 32;
  constexpr int ALOADS = BM / 32;
  constexpr int BLOADS = BN / 32;
  constexpr int NL = ALOADS + BLOADS;

  __shared__ __attribute__((aligned(16))) unsigned short Al[2][BM * 64];
  __shared__ __attribute__((aligned(16))) unsigned short Bl[2][BN * 64];

  int nblk = gridDim.x;
  int orig = blockIdx.x;
  int qq = nblk >> 3, rr = nblk & 7, xcd = orig & 7, pos = orig >> 3;
  int lid = (xcd < rr ? xcd * (qq + 1) : rr * (qq + 1) + (xcd - rr) * qq) + pos;
  int numN = N / BN;
  int mt = lid / numN, nt = lid % numN;
  int m0 = mt * BM, n0 = nt * BN;

  int tid = threadIdx.x, lane = tid & 63, w = tid >> 6;
  int wm = w >> 1, wn = w & 1;
  int g = lane >> 4, c = lane & 15;
  int srow = lane >> 3, sslot = lane & 7;
  int sgc = (sslot ^ srow) * 8;

  const unsigned short* aG = A  + (size_t)(m0 + w * (BM / 4) + srow) * K + sgc;
  const unsigned short* bG = Bt + (size_t)(n0 + w * (BN / 4) + srow) * K + sgc;
  int aOff = (w * (BM / 4) + srow) * 64 + sslot * 8;
  int bOff = (w * (BN / 4) + srow) * 64 + sslot * 8;

  f32x4 acc[MF][NF] = {};
  int KT = K >> 6;
  int rk = c & 7;

  #pragma unroll
  for (int t = 0; t < ALOADS; ++t)
    gload16(aG + (size_t)(t * 8) * K, &Al[0][aOff + t * 8 * 64]);
  #pragma unroll
  for (int t = 0; t < BLOADS; ++t)
    gload16(bG + (size_t)(t * 8) * K, &Bl[0][bOff + t * 8 * 64]);

  for (int kt = 0; kt < KT; ++kt) {
    int cur = kt & 1;
    if (kt + 1 < KT) {
      int nb = cur ^ 1;
      const unsigned short* aGk = aG + (kt + 1) * 64;
      const unsigned short* bGk = bG + (kt + 1) * 64;
      #pragma unroll
      for (int t = 0; t < ALOADS; ++t)
        gload16(aGk + (size_t)(t * 8) * K, &Al[nb][aOff + t * 8 * 64]);
      #pragma unroll
      for (int t = 0; t < BLOADS; ++t)
        gload16(bGk + (size_t)(t * 8) * K, &Bl[nb][bOff + t * 8 * 64]);
      waitcnt_vm<NL>();
    } else {
      waitcnt_vm<0>();
    }
    __builtin_amdgcn_s_barrier();
    __builtin_amdgcn_sched_barrier(0);
    #pragma unroll
    for (int ks = 0; ks < 2; ++ks) {
      int slot = (ks * 4 + g) ^ rk;
      bf16x8 af[MF], bfr[NF];
      #pragma unroll
      for (int i = 0; i < MF; ++i)
        af[i] = ldb8(&Al[cur][(wm * (MF * 16) + i * 16 + c) * 64 + slot * 8]);
      #pragma unroll
      for (int j = 0; j < NF; ++j)
        bfr[j] = ldb8(&Bl[cur][(wn * (NF * 16) + j * 16 + c) * 64 + slot * 8]);
      #pragma unroll
      for (int i = 0; i < MF; ++i)
        #pragma unroll
        for (int j = 0; j < NF; ++j)
          acc[i][j] = mfma16(af[i], bfr[j], acc[i][j]);
    }
    __builtin_amdgcn_sched_barrier(0);
    __builtin_amdgcn_s_barrier();
  }

  if (EPI == EPI_QKV) {
    int sel  = n0 >> 9;
    if (sel < 2) {
      #pragma unroll
      for (int i = 0; i < MF; ++i) {
        int mrow = m0 + wm * (MF * 16) + i * 16 + g * 4;
        #pragma unroll
        for (int j = 0; j < NF; ++j) {
          int nloc = (n0 & 511) + wn * (NF * 16) + j * 16 + c;
          const float* bp = sel == 0 ? bias0 : bias1;
          unsigned short* o = (unsigned short*)(sel == 0 ? out0 : out1);
          float sc = (sel == 0) ? QSCALE : 1.0f;
          float bn = bp[nloc];
          #pragma unroll
          for (int ii = 0; ii < 4; ++ii)
            o[(size_t)(mrow + ii) * D_MODEL + nloc] = f2bf((acc[i][j][ii] + bn) * sc);
        }
      }
    } else {
      unsigned short* T = &Al[0][0];            // 64 x 136
      #pragma unroll
      for (int i = 0; i < MF; ++i) {
        int ml0 = wm * (MF * 16) + i * 16 + g * 4;
        #pragma unroll
        for (int j = 0; j < NF; ++j) {
          int nl = wn * (NF * 16) + j * 16 + c;
          float bn = bias2[(n0 & 511) + nl];
          u16x4 pk;
          #pragma unroll
          for (int ii = 0; ii < 4; ++ii) pk[ii] = f2bf(acc[i][j][ii] + bn);
          *(u16x4*)&T[nl * 136 + ml0] = pk;
        }
      }
      __syncthreads();
      int b  = m0 >> 11, s0 = m0 & 2047;
      int hh = (n0 & 511) >> 6;
      int r  = tid >> 2, c0 = (tid & 3) * 32;
      unsigned short* dst = (unsigned short*)out2 +
          ((size_t)(b * NHEAD + hh) * HD + r) * SEQ + s0 + c0;
      #pragma unroll
      for (int u = 0; u < 4; ++u)
        *(u16x8*)(dst + u * 8) = *(u16x8*)&T[r * 136 + c0 + u * 8];
    }
  } else {  // EPI_PLAIN
    #pragma unroll
    for (int i = 0; i < MF; ++i) {
      int mrow = m0 + wm * (MF * 16) + i * 16 + g * 4;
      #pragma unroll
      for (int j = 0; j < NF; ++j) {
        int n = n0 + wn * (NF * 16) + j * 16 + c;
        float bn = bias0[n];
        unsigned short* o = (unsigned short*)out0;
        #pragma unroll
        for (int ii = 0; ii < 4; ++ii)
          o[(size_t)(mrow + ii) * N + n] = f2bf(acc[i][j][ii] + bn);
      }
    }
  }
}

// ---------------- GEMM v12s: split-K (S=2) plain GEMM --------------------
template<int BM, int BN>
__global__ __launch_bounds__(256) void gemm12s_k(
    const unsigned short* __restrict__ A,     // [M][KFULL]
    const unsigned short* __restrict__ Bt,    // [N][KFULL]
    const float* __restrict__ bias0,
    unsigned short* __restrict__ out,         // [2][M][N]
    int M, int N, int KFULL, int KLEN)
{
  constexpr int MF = BM / 32;
  constexpr int NF = BN / 32;
  constexpr int ALOADS = BM / 32;
  constexpr int BLOADS = BN / 32;
  constexpr int NL = ALOADS + BLOADS;

  __shared__ __attribute__((aligned(16))) unsigned short Al[2][BM * 64];
  __shared__ __attribute__((aligned(16))) unsigned short Bl[2][BN * 64];

  int kh = blockIdx.y;
  int nblk = gridDim.x;
  int orig = blockIdx.x;
  int qq = nblk >> 3, rr = nblk & 7, xcd = orig & 7, pos = orig >> 3;
  int lid = (xcd < rr ? xcd * (qq + 1) : rr * (qq + 1) + (xcd - rr) * qq) + pos;
  int numN = N / BN;
  int mt = lid / numN, nt = lid % numN;
  int m0 = mt * BM, n0 = nt * BN;

  int tid = threadIdx.x, lane = tid & 63, w = tid >> 6;
  int wm = w >> 1, wn = w & 1;
  int g = lane >> 4, c = lane & 15;
  int srow = lane >> 3, sslot = lane & 7;
  int sgc = (sslot ^ srow) * 8;

  const unsigned short* aG = A  + (size_t)(m0 + w * (BM / 4) + srow) * KFULL + kh * KLEN + sgc;
  const unsigned short* bG = Bt + (size_t)(n0 + w * (BN / 4) + srow) * KFULL + kh * KLEN + sgc;
  int aOff = (w * (BM / 4) + srow) * 64 + sslot * 8;
  int bOff = (w * (BN / 4) + srow) * 64 + sslot * 8;

  f32x4 acc[MF][NF] = {};
  int KT = KLEN >> 6;
  int rk = c & 7;

  #pragma unroll
  for (int t = 0; t < ALOADS; ++t)
    gload16(aG + (size_t)(t * 8) * KFULL, &Al[0][aOff + t * 8 * 64]);
  #pragma unroll
  for (int t = 0; t < BLOADS; ++t)
    gload16(bG + (size_t)(t * 8) * KFULL, &Bl[0][bOff + t * 8 * 64]);

  for (int kt = 0; kt < KT; ++kt) {
    int cur = kt & 1;
    if (kt + 1 < KT) {
      int nb = cur ^ 1;
      const unsigned short* aGk = aG + (kt + 1) * 64;
      const unsigned short* bGk = bG + (kt + 1) * 64;
      #pragma unroll
      for (int t = 0; t < ALOADS; ++t)
        gload16(aGk + (size_t)(t * 8) * KFULL, &Al[nb][aOff + t * 8 * 64]);
      #pragma unroll
      for (int t = 0; t < BLOADS; ++t)
        gload16(bGk + (size_t)(t * 8) * KFULL, &Bl[nb][bOff + t * 8 * 64]);
      waitcnt_vm<NL>();
    } else {
      waitcnt_vm<0>();
    }
    __builtin_amdgcn_s_barrier();
    __builtin_amdgcn_sched_barrier(0);
    #pragma unroll
    for (int ks = 0; ks < 2; ++ks) {
      int slot = (ks * 4 + g) ^ rk;
      bf16x8 af[MF], bfr[NF];
      #pragma unroll
      for (int i = 0; i < MF; ++i)
        af[i] = ldb8(&Al[cur][(wm * (MF * 16) + i * 16 + c) * 64 + slot * 8]);
      #pragma unroll
      for (int j = 0; j < NF; ++j)
        bfr[j] = ldb8(&Bl[cur][(wn * (NF * 16) + j * 16 + c) * 64 + slot * 8]);
      #pragma unroll
      for (int i = 0; i < MF; ++i)
        #pragma unroll
        for (int j = 0; j < NF; ++j)
          acc[i][j] = mfma16(af[i], bfr[j], acc[i][j]);
    }
    __builtin_amdgcn_sched_barrier(0);
    __builtin_amdgcn_s_barrier();
  }

  unsigned short* o = out + (size_t)kh * M * N;
  #pragma unroll
  for (int i = 0; i < MF; ++i) {
    int mrow = m0 + wm * (MF * 16) + i * 16 + g * 4;
    #pragma unroll
    for (int j = 0; j < NF; ++j) {
      int n = n0 + wn * (NF * 16) + j * 16 + c;
      float bn = (kh == 0) ? bias0[n] : 0.0f;
      #pragma unroll
      for (int ii = 0; ii < 4; ++ii)
        o[(size_t)(mrow + ii) * N + n] = f2bf(acc[i][j][ii] + bn);
    }
  }
}

// ---------------- GEMM v11d: fused dual-B gated FFN-up (single buffer,
// m-major XCD chunking; templated tile -- this round: 64x64, grid 2048) ----
template<int BM, int BN>
__global__ __launch_bounds__(256) void gemm11d_k(
    const unsigned short* __restrict__ A,
    const unsigned short* __restrict__ B0t,   // [N][K]
    const unsigned short* __restrict__ B1t,   // [N][K]
    const float* __restrict__ bias0,
    const float* __restrict__ bias1,
    unsigned short* __restrict__ out,
    int M, int N, int K)
{
  constexpr int MF = BM / 32;
  constexpr int NF = BN / 32;
  constexpr int ALOADS = BM / 32;
  constexpr int BLOADS = BN / 32;

  __shared__ __attribute__((aligned(16))) unsigned short Al[BM * 64];
  __shared__ __attribute__((aligned(16))) unsigned short B0l[BN * 64];
  __shared__ __attribute__((aligned(16))) unsigned short B1l[BN * 64];

  int nblk = gridDim.x;
  int orig = blockIdx.x;
  int qq = nblk >> 3, rr = nblk & 7, xcd = orig & 7, pos = orig >> 3;
  int lid = (xcd < rr ? xcd * (qq + 1) : rr * (qq + 1) + (xcd - rr) * qq) + pos;
  int numN = N / BN;
  int mt = lid / numN, nt = lid % numN;   // m-major: XCD chunk = contiguous m slab
  int m0 = mt * BM, n0 = nt * BN;

  int tid = threadIdx.x, lane = tid & 63, w = tid >> 6;
  int wm = w >> 1, wn = w & 1;
  int g = lane >> 4, c = lane & 15;
  int srow = lane >> 3, sslot = lane & 7;
  int sgc = (sslot ^ srow) * 8;

  const unsigned short* aG  = A   + (size_t)(m0 + w * (BM / 4) + srow) * K + sgc;
  const unsigned short* b0G = B0t + (size_t)(n0 + w * (BN / 4) + srow) * K + sgc;
  const unsigned short* b1G = B1t + (size_t)(n0 + w * (BN / 4) + srow) * K + sgc;
  unsigned short* aL  = &Al [(w * (BM / 4) + srow) * 64 + sslot * 8];
  unsigned short* b0L = &B0l[(w * (BN / 4) + srow) * 64 + sslot * 8];
  unsigned short* b1L = &B1l[(w * (BN / 4) + srow) * 64 + sslot * 8];

  f32x4 acc0[MF][NF] = {};
  f32x4 acc1[MF][NF] = {};
  int KT = K >> 6;
  int rk = c & 7;

  for (int kt = 0; kt < KT; ++kt) {
    if (kt) __syncthreads();
    #pragma unroll
    for (int t = 0; t < ALOADS; ++t)
      gload16(aG + (size_t)(t * 8) * K + kt * 64, aL + t * 8 * 64);
    #pragma unroll
    for (int t = 0; t < BLOADS; ++t) {
      gload16(b0G + (size_t)(t * 8) * K + kt * 64, b0L + t * 8 * 64);
      gload16(b1G + (size_t)(t * 8) * K + kt * 64, b1L + t * 8 * 64);
    }
    __syncthreads();
    #pragma unroll
    for (int ks = 0; ks < 2; ++ks) {
      int slot = (ks * 4 + g) ^ rk;
      bf16x8 af[MF], b0f[NF], b1f[NF];
      #pragma unroll
      for (int i = 0; i < MF; ++i)
        af[i] = ldb8(&Al[(wm * (MF * 16) + i * 16 + c) * 64 + slot * 8]);
      #pragma unroll
      for (int j = 0; j < NF; ++j) {
        b0f[j] = ldb8(&B0l[(wn * (NF * 16) + j * 16 + c) * 64 + slot * 8]);
        b1f[j] = ldb8(&B1l[(wn * (NF * 16) + j * 16 + c) * 64 + slot * 8]);
      }
      #pragma unroll
      for (int i = 0; i < MF; ++i)
        #pragma unroll
        for (int j = 0; j < NF; ++j) {
          acc0[i][j] = mfma16(af[i], b0f[j], acc0[i][j]);
          acc1[i][j] = mfma16(af[i], b1f[j], acc1[i][j]);
        }
    }
  }

  #pragma unroll
  for (int i = 0; i < MF; ++i) {
    int mrow = m0 + wm * (MF * 16) + i * 16 + g * 4;
    #pragma unroll
    for (int j = 0; j < NF; ++j) {
      int n = n0 + wn * (NF * 16) + j * 16 + c;
      float b0n = bias0[n], b1n = bias1[n];
      #pragma unroll
      for (int ii = 0; ii < 4; ++ii) {
        float a  = acc0[i][j][ii] + b0n;
        float gv = acc1[i][j][ii] + b1n;
        float s  = gv / (1.0f + __expf(-gv));
        out[(size_t)(mrow + ii) * N + n] = f2bf(a * s);
      }
    }
  }
}

// ---------------- attention v5: split-K flash, no-max softmax ------------
struct Stg { uint4v k0, k1, v0, v1; };

static __device__ __forceinline__ Stg stage_load(const unsigned short* Kp,
                                                 const unsigned short* Vp,
                                                 int kbase, int srow, int sslot) {
  Stg s;
  const unsigned short* kr = Kp + (size_t)(kbase + srow) * D_MODEL + sslot * 8;
  s.k0 = *(const uint4v*)kr;
  s.k1 = *(const uint4v*)(kr + 32);
  const unsigned short* vr = Vp + (size_t)srow * SEQ + kbase + sslot * 8;
  s.v0 = *(const uint4v*)vr;
  s.v1 = *(const uint4v*)(vr + 32);
  return s;
}
static __device__ __forceinline__ void stage_write(unsigned short* Klb, unsigned short* Vlb,
                                                   const Stg& s, int srow, int sslot) {
  char* kb = (char*)Klb;
  *(uint4v*)(kb + SWZ(srow, srow * 128 + sslot * 16))       = s.k0;
  *(uint4v*)(kb + SWZ(srow, srow * 128 + (sslot + 4) * 16)) = s.k1;
  char* vb = (char*)Vlb;
  *(uint4v*)(vb + SWZ(srow, srow * 128 + sslot * 16))       = s.v0;
  *(uint4v*)(vb + SWZ(srow, srow * 128 + (sslot + 4) * 16)) = s.v1;
}

template<bool MASKED>
static __device__ __forceinline__ void attn_tile(
    const unsigned short* Klb, const unsigned short* Vlb,
    bf16x8 qf0, bf16x8 qf1, f32x4* oacc, float& ps,
    int g, int c, int kbase, int qrow)
{
  f32x4 z[4];
  #pragma unroll
  for (int hh = 0; hh < 4; ++hh) {
    int r = hh * 16 + c;
    const char* base = (const char*)Klb;
    bf16x8 k0 = ldb8((const unsigned short*)(base + SWZ(r, r * 128 + g * 16)));
    bf16x8 k1 = ldb8((const unsigned short*)(base + SWZ(r, r * 128 + 64 + g * 16)));
    f32x4 t = {};
    t = mfma16(k0, qf0, t);
    t = mfma16(k1, qf1, t);
    z[hh] = t;
  }
  u16x8 pa0, pa1;
  #pragma unroll
  for (int hh = 0; hh < 4; ++hh) {
    #pragma unroll
    for (int i = 0; i < 4; ++i) {
      float p = exp2f(z[hh][i]);
      if (MASKED && (kbase + hh * 16 + g * 4 + i > qrow)) p = 0.0f;
      ps += p;
      unsigned short pb = f2bf(p);
      if (hh < 2) pa0[hh * 4 + i] = pb;
      else        pa1[(hh - 2) * 4 + i] = pb;
    }
  }
  bf16x8 af0 = __builtin_bit_cast(bf16x8, pa0);
  bf16x8 af1 = __builtin_bit_cast(bf16x8, pa1);
  #pragma unroll
  for (int db = 0; db < 4; ++db) {
    int r = db * 16 + c;
    const char* base = (const char*)Vlb;
    u16x4 v00 = *(const u16x4*)(base + SWZ(r, r * 128 + g * 8));
    u16x4 v01 = *(const u16x4*)(base + SWZ(r, r * 128 + 32 + g * 8));
    u16x4 v10 = *(const u16x4*)(base + SWZ(r, r * 128 + 64 + g * 8));
    u16x4 v11 = *(const u16x4*)(base + SWZ(r, r * 128 + 96 + g * 8));
    u16x8 vb0, vb1;
    #pragma unroll
    for (int j = 0; j < 4; ++j) {
      vb0[j] = v00[j]; vb0[4 + j] = v01[j];
      vb1[j] = v10[j]; vb1[4 + j] = v11[j];
    }
    oacc[db] = mfma16(af0, __builtin_bit_cast(bf16x8, vb0), oacc[db]);
    oacc[db] = mfma16(af1, __builtin_bit_cast(bf16x8, vb1), oacc[db]);
  }
}

static __device__ __forceinline__ int slot_base(int c) {
  if (c < 16) return (c - 8) * 2;
  if (c < 24) return 16 + (c - 16) * 3;
  return 40 + (c - 24) * 4;
}

__global__ __launch_bounds__(256) void attn5_k(const unsigned short* __restrict__ Q,
                                               const unsigned short* __restrict__ K,
                                               const unsigned short* __restrict__ VT,
                                               unsigned short* __restrict__ O,
                                               float* __restrict__ Oparts,
                                               float* __restrict__ Sparts)
{
  __shared__ __attribute__((aligned(16))) unsigned short Kl[2][64 * 64];
  __shared__ __attribute__((aligned(16))) unsigned short Vl[2][64 * 64];
  int tid = threadIdx.x, lane = tid & 63, w = tid >> 6;
  int g = lane >> 4, cl = lane & 15;

  int z = 79 - (int)blockIdx.x;
  int c, sp;
  if (z < 8)        { c = z;                    sp = 0; }
  else if (z < 24)  { int t2 = z - 8;  c = 8  + (t2 >> 1); sp = t2 & 1; }
  else if (z < 48)  { int t2 = z - 24; c = 16 + t2 / 3;    sp = t2 % 3; }
  else              { int t2 = z - 48; c = 24 + (t2 >> 2); sp = t2 & 3; }
  int kt0 = sp * 8;
  int kt1 = min(c + 1, kt0 + 8);
  bool lastsplit = (kt1 == c + 1);

  int bh = blockIdx.y, b = bh >> 3, h = bh & 7;
  int q0 = c * 64;
  const unsigned short* Qp = Q + (size_t)(b * SEQ) * D_MODEL + h * HD;
  const unsigned short* Kp = K + (size_t)(b * SEQ) * D_MODEL + h * HD;
  const unsigned short* Vp = VT + (size_t)bh * HD * SEQ;

  int qrow = q0 + w * 16 + cl;
  bf16x8 qf0 = ldb8(Qp + (size_t)qrow * D_MODEL + g * 8);
  bf16x8 qf1 = ldb8(Qp + (size_t)qrow * D_MODEL + 32 + g * 8);

  f32x4 oacc[4] = {};
  float ps = 0.0f;
  int srow = tid >> 2, sslot = tid & 3;

  Stg s0 = stage_load(Kp, Vp, kt0 * 64, srow, sslot);
  stage_write(&Kl[0][0], &Vl[0][0], s0, srow, sslot);
  __syncthreads();

  int buf = 0;
  for (int kt = kt0; kt < kt1 - 1; ++kt) {
    Stg sn = stage_load(Kp, Vp, (kt + 1) * 64, srow, sslot);
    attn_tile<false>(&Kl[buf][0], &Vl[buf][0], qf0, qf1, oacc, ps, g, cl, 0, 0);
    stage_write(&Kl[buf ^ 1][0], &Vl[buf ^ 1][0], sn, srow, sslot);
    __syncthreads();
    buf ^= 1;
  }
  if (lastsplit)
    attn_tile<true>(&Kl[buf][0], &Vl[buf][0], qf0, qf1, oacc, ps, g, cl,
                    (kt1 - 1) * 64, qrow);
  else
    attn_tile<false>(&Kl[buf][0], &Vl[buf][0], qf0, qf1, oacc, ps, g, cl, 0, 0);

  ps += __shfl_xor(ps, 16, 64);
  ps += __shfl_xor(ps, 32, 64);

  if (c < 8) {
    f32x4 inv;
    #pragma unroll
    for (int i = 0; i < 4; ++i) inv[i] = 1.0f / __shfl(ps, g * 4 + i, 64);
    #pragma unroll
    for (int db = 0; db < 4; ++db)
      #pragma unroll
      for (int i = 0; i < 4; ++i)
        O[(size_t)(b * SEQ + q0 + w * 16 + g * 4 + i) * D_MODEL + h * HD + db * 16 + cl] =
            f2bf(oacc[db][i] * inv[i]);
  } else {
    size_t slot = (size_t)bh * 72 + slot_base(c) + sp;
    float* Op = Oparts + slot * 4096;
    float* Sp = Sparts + slot * 64;
    #pragma unroll
    for (int db = 0; db < 4; ++db)
      #pragma unroll
      for (int i = 0; i < 4; ++i)
        Op[(w * 16 + g * 4 + i) * 64 + db * 16 + cl] = oacc[db][i];
    if (g == 0) Sp[w * 16 + cl] = ps;
  }
}

__global__ __launch_bounds__(256) void attn_comb_k(const float* __restrict__ Oparts,
                                                   const float* __restrict__ Sparts,
                                                   unsigned short* __restrict__ O) {
  int t  = threadIdx.x;
  int c  = 8 + (int)(blockIdx.x % 24);
  int bh = (int)(blockIdx.x / 24);
  int b = bh >> 3, h = bh & 7;
  int ns = (c + 8) >> 3;
  size_t slot = (size_t)bh * 72 + slot_base(c);
  const float* O0 = Oparts + slot * 4096;
  const float* S0 = Sparts + slot * 64;
  int r = t >> 2, d0 = (t & 3) * 16;
  f32x4 a0 = {}, a1 = {}, a2 = {}, a3 = {};
  float s = 0.0f;
  for (int si = 0; si < ns; ++si) {
    const float* o = O0 + si * 4096 + r * 64 + d0;
    a0 += *(const f32x4*)(o);
    a1 += *(const f32x4*)(o + 4);
    a2 += *(const f32x4*)(o + 8);
    a3 += *(const f32x4*)(o + 12);
    s  += S0[si * 64 + r];
  }
  float inv = 1.0f / s;
  u16x8 w0, w1;
  #pragma unroll
  for (int j = 0; j < 4; ++j) {
    w0[j]     = f2bf(a0[j] * inv); w0[4 + j] = f2bf(a1[j] * inv);
    w1[j]     = f2bf(a2[j] * inv); w1[4 + j] = f2bf(a3[j] * inv);
  }
  unsigned short* dst = O + (size_t)(b * SEQ + c * 64 + r) * D_MODEL + h * HD + d0;
  *(u16x8*)(dst)     = w0;
  *(u16x8*)(dst + 8) = w1;
}

// ---------------- launch ----------------
extern "C" void kernel_launch(void* const* d_in, const int* in_sizes, int n_in,
                              void* d_out, int out_size, void* d_ws, size_t ws_size,
                              hipStream_t stream) {
  (void)in_sizes; (void)n_in; (void)out_size; (void)ws_size;
  const float* x   = (const float*)d_in[0];
  const float* qw  = (const float*)d_in[1];
  const float* qb  = (const float*)d_in[2];
  const float* kw  = (const float*)d_in[3];
  const float* kbi = (const float*)d_in[4];
  const float* vw  = (const float*)d_in[5];
  const float* vb  = (const float*)d_in[6];
  const float* ow  = (const float*)d_in[7];
  const float* ob  = (const float*)d_in[8];
  const float* w0  = (const float*)d_in[9];
  const float* b0  = (const float*)d_in[10];
  const float* w1  = (const float*)d_in[11];
  const float* b1  = (const float*)d_in[12];
  const float* w2  = (const float*)d_in[13];
  const float* b2  = (const float*)d_in[14];
  const float* anw = (const float*)d_in[15];
  const float* fnw = (const float*)d_in[16];

  char* ws = (char*)d_ws;
  float*          h    = (float*)ws;                              // 0-8MB fp32 residual
  unsigned short* xn   = (unsigned short*)(ws + (8u  << 20));     // 8-12
  unsigned short* q    = (unsigned short*)(ws + (12u << 20));     // 12-16
  unsigned short* k    = (unsigned short*)(ws + (16u << 20));     // 16-20
  unsigned short* vt   = (unsigned short*)(ws + (24u << 20));     // 24-28
  unsigned short* ao   = (unsigned short*)(ws + (28u << 20));     // 28-32
  unsigned short* hbuf = (unsigned short*)(ws + (12u << 20));     // 12-28 (aliases q,k,vt)
  unsigned short* Wq   = (unsigned short*)(ws + (36u << 20));     // 36-42
  unsigned short* Wo   = (unsigned short*)(ws + (42u << 20));     // 42-44
  unsigned short* W01  = (unsigned short*)(ws + (44u << 20));     // 44-60
  unsigned short* W2   = (unsigned short*)(ws + (60u << 20));     // 60-68
  float*          Opar = (float*)(ws + (68u << 20));              // 68-86 (18MB)
  float*          Spar = (float*)(ws + (86u << 20));              // 86-86.3
  unsigned short* ysp  = (unsigned short*)(ws + (88u << 20));     // 88-96 (split-K partials, 2x4MB)

  prep_t<<<4096, 64, 0, stream>>>(qw, kw, vw, ow, w0, w1, w2, Wq, Wo, W01, W2);
  initrms_k<<<BTOK / 4, 256, 0, stream>>>(x, anw, h, xn);

  for (int l = 0; l < 4; ++l) {
    size_t bo  = (size_t)l * D_MODEL;
    size_t bho = (size_t)l * HIDE;

    gemm7_k<EPI_QKV, 128, 64><<<768, 256, 0, stream>>>(
        xn, Wq + (size_t)l * 786432, qb + bo, kbi + bo, vb + bo,
        q, k, vt, BTOK, 3 * D_MODEL, D_MODEL);
    attn5_k<<<dim3(80, 16), 256, 0, stream>>>(q, k, vt, ao, Opar, Spar);
    attn_comb_k<<<384, 256, 0, stream>>>(Opar, Spar, ao);
    gemm12s_k<64, 64><<<dim3(512, 2), 256, 0, stream>>>(
        ao, Wo + (size_t)l * 262144, ob + bo, ysp,
        BTOK, D_MODEL, D_MODEL, D_MODEL / 2);
    addrms2_k<<<BTOK / 4, 256, 0, stream>>>(
        h, ysp, ysp + (size_t)BTOK * D_MODEL, fnw + bo, xn);

    gemm11d_k<64, 64><<<2048, 256, 0, stream>>>(
        xn, W01 + (size_t)l * 2097152, W01 + (size_t)l * 2097152 + 1048576,
        b0 + bho, b1 + bho, hbuf, BTOK, HIDE, D_MODEL);
    gemm12s_k<64, 64><<<dim3(512, 2), 256, 0, stream>>>(
        hbuf, W2 + (size_t)l * 1048576, b2 + bo, ysp,
        BTOK, D_MODEL, HIDE, HIDE / 2);
    if (l < 3)
      addrms2_k<<<BTOK / 4, 256, 0, stream>>>(
          h, ysp, ysp + (size_t)BTOK * D_MODEL, anw + bo + D_MODEL, xn);
    else
      addout2_k<<<BTOK / 4, 256, 0, stream>>>(
          h, ysp, ysp + (size_t)BTOK * D_MODEL, (float*)d_out);
  }
}